// Round 1
// baseline (14013.821 us; speedup 1.0000x reference)
//
#include <hip/hip_runtime.h>
#include <hip/hip_bf16.h>
#include <float.h>

// ---------------------------------------------------------------------------
// Beam-search seq2seq (2-layer LSTM encoder S=512, greedy-degenerate 4-beam
// decoder MAXLEN=12, V=32000). Fully fp32 math; bf16 only for stored logits
// history (output tolerance is 2% of absmax).
//
// Cross-WG communication inside persistent kernels uses relaxed AGENT-scope
// atomics (sc1 coherent ops -> bypass non-coherent L2, no cache-invalidate
// fences, so weight slices stay L2-resident across steps). Barrier ordering:
// __syncthreads() drains each wave's vmcnt (coherent stores complete at the
// coherence point) before thread 0's arrival add.
// ---------------------------------------------------------------------------

#define SCOPE_AGENT __HIP_MEMORY_SCOPE_AGENT

__device__ __forceinline__ float cLoad(const float* p) {
  return __hip_atomic_load(p, __ATOMIC_RELAXED, SCOPE_AGENT);
}
__device__ __forceinline__ void cStore(float* p, float v) {
  __hip_atomic_store(p, v, __ATOMIC_RELAXED, SCOPE_AGENT);
}
__device__ __forceinline__ int cLoadI(const int* p) {
  return __hip_atomic_load(p, __ATOMIC_RELAXED, SCOPE_AGENT);
}
__device__ __forceinline__ void cStoreI(int* p, int v) {
  __hip_atomic_store(p, v, __ATOMIC_RELAXED, SCOPE_AGENT);
}

// Grid-wide barrier: monotonic counter, one arrival per WG.
__device__ __forceinline__ void gbar(int* ctr, int phase, int nwg) {
  __syncthreads();  // drains all waves' outstanding (coherent) stores
  if (threadIdx.x == 0) {
    __hip_atomic_fetch_add(ctr, 1, __ATOMIC_RELAXED, SCOPE_AGENT);
    const int tgt = (phase + 1) * nwg;
    while (cLoadI(ctr) < tgt) __builtin_amdgcn_s_sleep(1);
  }
  __syncthreads();
}

__device__ __forceinline__ float sig_(float x) { return 1.0f / (1.0f + expf(-x)); }

// top-4 sorted insert; ordering matches lax.top_k (desc value, tie -> lower idx)
__device__ __forceinline__ void ins4(float* v, int* id, float nv, int ni) {
  if (nv > v[3] || (nv == v[3] && ni < id[3])) {
    v[3] = nv; id[3] = ni;
#pragma unroll
    for (int p = 3; p > 0; --p) {
      bool sw = (v[p] > v[p - 1]) || (v[p] == v[p - 1] && id[p] < id[p - 1]);
      if (sw) {
        float t0 = v[p]; v[p] = v[p - 1]; v[p - 1] = t0;
        int t1 = id[p]; id[p] = id[p - 1]; id[p - 1] = t1;
      }
    }
  }
}

// ---------------------------------------------------------------------------
// init: zero h double-buffers + barrier counters
// ---------------------------------------------------------------------------
__global__ __launch_bounds__(256) void init_kernel(float* h0buf, float* h1buf,
                                                   int* ctrE, int* ctrD) {
  int g = blockIdx.x * 256 + threadIdx.x;
  if (g < 8192) { h0buf[g] = 0.0f; h1buf[g] = 0.0f; }
  if (g == 0) { *ctrE = 0; *ctrD = 0; }
}

// ---------------------------------------------------------------------------
// Encoder: 128 WGs x 256 thr. WGs 0..63 = layer0, 64..127 = layer1 (skewed by
// one step). Each WG owns 8 h-columns (32 gate rows). 513 iterations.
// ---------------------------------------------------------------------------
struct EncP {
  const int* text; const float* emb;
  const float* Wih0; const float* Whh0; const float* bih0; const float* bhh0;
  const float* Wih1; const float* Whh1; const float* bih1; const float* bhh1;
  float* h0buf; float* h1buf; float* h0f; float* h1f; float* c1f;
  int* ctr;
};

__global__ __launch_bounds__(256, 1) void enc_kernel(EncP P) {
  __shared__ float hsA[8 * 516];   // recurrent-h stage (pad: 516 % 32 == 4)
  __shared__ float hsB[8 * 516];   // layer1 x stage (h0)
  __shared__ float xs[8 * 260];    // layer0 x stage (emb rows)
  __shared__ float gl[8][4][8];
  __shared__ float cl[8][8];

  const int w = blockIdx.x, tid = threadIdx.x;
  const int L = w >> 6;
  const int c0 = (w & 63) * 8;
  const int col_l = tid >> 5, gate = (tid >> 3) & 3, b = tid & 7;
  const int row = gate * 512 + c0 + col_l;

  if (tid < 64) cl[tid >> 3][tid & 7] = 0.0f;

  const float* Wih = L ? P.Wih1 : P.Wih0;
  const float* Whh = L ? P.Whh1 : P.Whh0;
  const float bias = L ? (P.bih1[row] + P.bhh1[row]) : (P.bih0[row] + P.bhh0[row]);
  const float4* wih4 = (const float4*)(Wih + (size_t)row * (L ? 512 : 256));
  const float4* whh4 = (const float4*)(Whh + (size_t)row * 512);
  float* myH = L ? P.h1buf : P.h0buf;

  for (int i = 0; i <= 512; ++i) {
    const bool act = L ? (i >= 1) : (i < 512);
    if (act) {
      const int t = L ? (i - 1) : i;
      // ---- stage ----
      const float* hprev = L ? (P.h1buf + (i & 1) * 4096)
                             : (P.h0buf + ((i + 1) & 1) * 4096);
      for (int e = tid; e < 4096; e += 256)
        hsA[(e >> 9) * 516 + (e & 511)] = cLoad(hprev + e);
      if (L) {
        const float* x0 = P.h0buf + ((i + 1) & 1) * 4096;  // h0_{i-1}
        for (int e = tid; e < 4096; e += 256)
          hsB[(e >> 9) * 516 + (e & 511)] = cLoad(x0 + e);
      } else {
        for (int e = tid; e < 2048; e += 256) {
          int eb = e >> 8, ek = e & 255;
          int tv2 = P.text[t * 8 + eb];
          xs[eb * 260 + ek] = P.emb[(size_t)tv2 * 256 + ek];
        }
      }
      __syncthreads();
      // ---- gate dot (4-way split accumulators; 1 wave/SIMD => latency-bound) ----
      float s0 = 0.f, s1 = 0.f, s2 = 0.f, s3 = 0.f;
      if (L) {
        const float4* x4 = (const float4*)hsB + b * 129;
#pragma unroll 8
        for (int k = 0; k < 128; ++k) {
          float4 a = wih4[k], x = x4[k];
          s0 = fmaf(a.x, x.x, s0); s1 = fmaf(a.y, x.y, s1);
          s2 = fmaf(a.z, x.z, s2); s3 = fmaf(a.w, x.w, s3);
        }
      } else {
        const float4* x4 = (const float4*)xs + b * 65;
#pragma unroll 8
        for (int k = 0; k < 64; ++k) {
          float4 a = wih4[k], x = x4[k];
          s0 = fmaf(a.x, x.x, s0); s1 = fmaf(a.y, x.y, s1);
          s2 = fmaf(a.z, x.z, s2); s3 = fmaf(a.w, x.w, s3);
        }
      }
      {
        const float4* h4 = (const float4*)hsA + b * 129;
#pragma unroll 8
        for (int k = 0; k < 128; ++k) {
          float4 a = whh4[k], x = h4[k];
          s0 = fmaf(a.x, x.x, s0); s1 = fmaf(a.y, x.y, s1);
          s2 = fmaf(a.z, x.z, s2); s3 = fmaf(a.w, x.w, s3);
        }
      }
      gl[col_l][gate][b] = bias + ((s0 + s1) + (s2 + s3));
      __syncthreads();
      if (tid < 64) {
        const int cc = tid >> 3, bb = tid & 7;
        float gi = gl[cc][0][bb], gf = gl[cc][1][bb];
        float gg = gl[cc][2][bb], go = gl[cc][3][bb];
        float cold = cl[cc][bb];
        float c2 = sig_(gf) * cold + sig_(gi) * tanhf(gg);
        float hv = sig_(go) * tanhf(c2);
        cl[cc][bb] = c2;
        cStore(myH + (t & 1) * 4096 + bb * 512 + c0 + cc, hv);
        if (t == 511) {
          (L ? P.h1f : P.h0f)[bb * 512 + c0 + cc] = hv;
          if (L) P.c1f[bb * 512 + c0 + cc] = c2;
        }
      }
    }
    if (i < 512) gbar(P.ctr, i, 128);
  }
}

// ---------------------------------------------------------------------------
// prep: k_enc/v_enc projections of [h0f;h1f], decoder state init
// ---------------------------------------------------------------------------
__global__ __launch_bounds__(256) void prep_kernel(
    const float* Wk, const float* bk, const float* Wv, const float* bv,
    const float* h0f, const float* h1f, const float* c1f,
    float* kenc, float* venc, float* dech, float* decc, int* tok) {
  const int w = blockIdx.x, tid = threadIdx.x;
  if (w < 64) {
    const int o = w * 256 + tid;                  // [kv][l][b][c]
    const int kv = o >> 13, l = (o >> 12) & 1, b = (o >> 9) & 7, c = o & 511;
    const float4* h4 = (const float4*)((l ? h1f : h0f) + b * 512);
    const float4* w4 = (const float4*)((kv ? Wv : Wk) + (size_t)c * 512);
    float s0 = 0.f, s1 = 0.f, s2 = 0.f, s3 = 0.f;
#pragma unroll 8
    for (int k = 0; k < 128; ++k) {
      float4 a = w4[k], x = h4[k];
      s0 = fmaf(a.x, x.x, s0); s1 = fmaf(a.y, x.y, s1);
      s2 = fmaf(a.z, x.z, s2); s3 = fmaf(a.w, x.w, s3);
    }
    (kv ? venc : kenc)[l * 4096 + b * 512 + c] =
        (kv ? bv : bk)[c] + ((s0 + s1) + (s2 + s3));
  } else {
    const int o = (w - 64) * 256 + tid;           // [n][b][c] broadcast over n
    dech[o] = h1f[o & 4095];
    decc[o] = c1f[o & 4095];
    if (o < 32) tok[o] = 1;                        // SOS
  }
}

// ---------------------------------------------------------------------------
// Decoder: 256 WGs x 256 thr, 12 steps x 6 barrier phases
// ---------------------------------------------------------------------------
struct DecP {
  const float* emb;
  const float* Wih; const float* Whh; const float* bih; const float* bhh;
  const float* Wq; const float* bq; const float* Wk; const float* bk;
  const float* Wv; const float* bv; const float* Wo; const float* bo;
  const float* Wout; const float* bout;
  const float* kenc; const float* venc;
  float* dech; float* decc; float* nh; float* nc;
  float* qkv;    // [3][32][512]
  float* ctx;    // [32][512]
  float* out1;   // [32][512]
  int* tok;      // [32]
  float* pval; int* pidx;  // [256][32][4]
  int* obh;      // [12][4][8]
  int* res0;     // [13][8]
  __hip_bfloat16* hist;    // [12][32][32000]
  int* ctr;
};

// stage [32][512] coherent source into LDS (2 chunks) and dot with one weight
// row; all 256 threads of a WG must call uniformly.
__device__ float stage_dot512(const float* src, const float4* w4row, float* hs,
                              int nb) {
  const int tid = threadIdx.x;
  float s0 = 0.f, s1 = 0.f, s2 = 0.f, s3 = 0.f;
  for (int ck = 0; ck < 2; ++ck) {
    __syncthreads();
    for (int e = tid; e < 8192; e += 256)
      hs[(e >> 8) * 260 + (e & 255)] = cLoad(src + (e >> 8) * 512 + ck * 256 + (e & 255));
    __syncthreads();
    const float4* h4 = (const float4*)hs + nb * 65;
    const float4* w4 = w4row + ck * 64;
#pragma unroll 8
    for (int k = 0; k < 64; ++k) {
      float4 a = w4[k], x = h4[k];
      s0 = fmaf(a.x, x.x, s0); s1 = fmaf(a.y, x.y, s1);
      s2 = fmaf(a.z, x.z, s2); s3 = fmaf(a.w, x.w, s3);
    }
  }
  return (s0 + s1) + (s2 + s3);
}

__global__ __launch_bounds__(256, 1) void dec_kernel(DecP P) {
  __shared__ float hs[32 * 260];
  __shared__ float gl[2][4][32];
  __shared__ float sl[32][3];
  __shared__ float wsm[32][3];
  __shared__ float tv[32][8][4];
  __shared__ int ti_[32][8][4];
  __shared__ float rv[32][4];
  __shared__ int rt[32][4];
  __shared__ int res[4][13][8];
  __shared__ int obl[4][8];
  __shared__ int tkl[4][8];

  const int w = blockIdx.x, tid = threadIdx.x;
  int ph = 0;

  if (tid < 104) {  // res init: all SOS (only WG0's copy is used)
    for (int n = 0; n < 4; ++n) res[n][tid >> 3][tid & 7] = 1;
  }

  for (int t = 0; t < 12; ++t) {
    // ===== A: LSTM gates + cell (WG w owns h-cols [2w, 2w+2)) =====
    {
      const int col_l = tid >> 7, gate = (tid >> 5) & 3, nb = tid & 31;
      const int col = 2 * w + col_l;
      const int row = gate * 512 + col;
      const int tokv = cLoadI(P.tok + nb);
      float s0 = 0.f, s1 = 0.f, s2 = 0.f, s3 = 0.f;
      {
        const float4* a4 = (const float4*)(P.Wih + (size_t)row * 256);
        const float4* x4 = (const float4*)(P.emb + (size_t)tokv * 256);
#pragma unroll 8
        for (int k = 0; k < 64; ++k) {
          float4 a = a4[k], x = x4[k];
          s0 = fmaf(a.x, x.x, s0); s1 = fmaf(a.y, x.y, s1);
          s2 = fmaf(a.z, x.z, s2); s3 = fmaf(a.w, x.w, s3);
        }
      }
      float acc = P.bih[row] + P.bhh[row] + ((s0 + s1) + (s2 + s3));
      acc += stage_dot512(P.dech, (const float4*)(P.Whh + (size_t)row * 512), hs, nb);
      gl[col_l][gate][nb] = acc;
      __syncthreads();
      if (tid < 64) {
        const int cc = tid >> 5, nb2 = tid & 31;
        const int col2 = 2 * w + cc;
        float gi = gl[cc][0][nb2], gf = gl[cc][1][nb2];
        float gg = gl[cc][2][nb2], go = gl[cc][3][nb2];
        float cold = cLoad(P.decc + nb2 * 512 + col2);
        float c2 = sig_(gf) * cold + sig_(gi) * tanhf(gg);
        float hv = sig_(go) * tanhf(c2);
        cStore(P.nh + nb2 * 512 + col2, hv);
        cStore(P.nc + nb2 * 512 + col2, c2);
      }
    }
    gbar(P.ctr, ph++, 256);

    // ===== B: q / kd / vd projections of nh =====
    if (w < 192) {
      const int p = w >> 6, cb = w & 63;
      const int col_l = tid >> 5, nb = tid & 31;
      const int col = cb * 8 + col_l;
      const float* W = (p == 0 ? P.Wq : p == 1 ? P.Wk : P.Wv) + (size_t)col * 512;
      float acc = (p == 0 ? P.bq : p == 1 ? P.bk : P.bv)[col];
      acc += stage_dot512(P.nh, (const float4*)W, hs, nb);
      cStore(P.qkv + p * 16384 + nb * 512 + col, acc);
    }
    gbar(P.ctr, ph++, 256);

    // ===== C: attention scores / softmax(3) / ctx  (WG 0) =====
    if (w == 0) {
      if (tid < 96) {
        const int nb = tid / 3, l = tid % 3, b = nb & 7;
        const float* q = P.qkv + nb * 512;
        const float* kk = (l < 2) ? (P.kenc + l * 4096 + b * 512)
                                  : (P.qkv + 16384 + nb * 512);
        float acc = 0.f;
        for (int k = 0; k < 512; ++k)
          acc = fmaf(cLoad(q + k), (l < 2 ? kk[k] : cLoad(kk + k)), acc);
        sl[nb][l] = acc * (1.0f / sqrtf(512.0f));
      }
      __syncthreads();
      if (tid < 32) {
        float a = sl[tid][0], b2 = sl[tid][1], c3 = sl[tid][2];
        float m = fmaxf(a, fmaxf(b2, c3));
        float e0 = expf(a - m), e1 = expf(b2 - m), e2 = expf(c3 - m);
        float inv = 1.0f / (e0 + e1 + e2);
        wsm[tid][0] = e0 * inv; wsm[tid][1] = e1 * inv; wsm[tid][2] = e2 * inv;
      }
      __syncthreads();
      for (int e = tid; e < 16384; e += 256) {
        const int nb = e >> 9, c = e & 511, b = nb & 7;
        float v0 = P.venc[b * 512 + c];
        float v1 = P.venc[4096 + b * 512 + c];
        float v2 = cLoad(P.qkv + 32768 + nb * 512 + c);
        cStore(P.ctx + e, wsm[nb][0] * v0 + wsm[nb][1] * v1 + wsm[nb][2] * v2);
      }
    }
    gbar(P.ctr, ph++, 256);

    // ===== D: out1 = ctx @ Wo.T + bo =====
    if (w < 64) {
      const int col_l = tid >> 5, nb = tid & 31;
      const int col = w * 8 + col_l;
      float acc = P.bo[col];
      acc += stage_dot512(P.ctx, (const float4*)(P.Wo + (size_t)col * 512), hs, nb);
      cStore(P.out1 + nb * 512 + col, acc);
    }
    gbar(P.ctr, ph++, 256);

    // ===== E: logits (+bout), bf16 history store, per-WG partial top-4 =====
    {
      const int nb = tid >> 3, cg = tid & 7;
      const int cbase = w * 125;
      float acc[16];
#pragma unroll
      for (int j = 0; j < 16; ++j) acc[j] = 0.0f;
      for (int ck = 0; ck < 2; ++ck) {
        __syncthreads();
        for (int e = tid; e < 8192; e += 256)
          hs[(e >> 8) * 260 + (e & 255)] =
              cLoad(P.out1 + (e >> 8) * 512 + ck * 256 + (e & 255));
        __syncthreads();
        const float4* h4 = (const float4*)hs + nb * 65;
#pragma unroll
        for (int j = 0; j < 16; ++j) {
          const int cl2 = cg + 8 * j;
          if (cl2 < 125) {
            const float4* w4 =
                (const float4*)(P.Wout + (size_t)(cbase + cl2) * 512 + ck * 256);
            float p0 = 0.f, p1 = 0.f;
#pragma unroll 4
            for (int k = 0; k < 64; ++k) {
              float4 a = w4[k], x = h4[k];
              p0 = fmaf(a.x, x.x, p0); p0 = fmaf(a.y, x.y, p0);
              p1 = fmaf(a.z, x.z, p1); p1 = fmaf(a.w, x.w, p1);
            }
            acc[j] += p0 + p1;
          }
        }
      }
      float v4[4] = {-FLT_MAX, -FLT_MAX, -FLT_MAX, -FLT_MAX};
      int i4[4] = {0x7fffffff, 0x7fffffff, 0x7fffffff, 0x7fffffff};
#pragma unroll
      for (int j = 0; j < 16; ++j) {
        const int cl2 = cg + 8 * j;
        if (cl2 < 125) {
          const int c = cbase + cl2;
          const float v = acc[j] + P.bout[c];
          P.hist[(size_t)t * 1024000 + (size_t)nb * 32000 + c] = __float2bfloat16(v);
          ins4(v4, i4, v, c);
        }
      }
#pragma unroll
      for (int k = 0; k < 4; ++k) { tv[nb][cg][k] = v4[k]; ti_[nb][cg][k] = i4[k]; }
      __syncthreads();
      if (tid < 32) {
        float m4[4] = {-FLT_MAX, -FLT_MAX, -FLT_MAX, -FLT_MAX};
        int mi[4] = {0x7fffffff, 0x7fffffff, 0x7fffffff, 0x7fffffff};
        for (int g2 = 0; g2 < 8; ++g2)
#pragma unroll
          for (int k = 0; k < 4; ++k) ins4(m4, mi, tv[tid][g2][k], ti_[tid][g2][k]);
#pragma unroll
        for (int k = 0; k < 4; ++k) {
          cStore(P.pval + w * 128 + tid * 4 + k, m4[k]);
          cStoreI(P.pidx + w * 128 + tid * 4 + k, mi[k]);
        }
      }
    }
    gbar(P.ctr, ph++, 256);

    // ===== F: global top-4/row, beam candidate select, state reorder (WG 0) =====
    if (w == 0) {
      {
        const int r = tid >> 3, ch = tid & 7;
        float m4[4] = {-FLT_MAX, -FLT_MAX, -FLT_MAX, -FLT_MAX};
        int mi[4] = {0x7fffffff, 0x7fffffff, 0x7fffffff, 0x7fffffff};
        for (int wg = ch * 32; wg < ch * 32 + 32; ++wg)
#pragma unroll
          for (int k = 0; k < 4; ++k)
            ins4(m4, mi, cLoad(P.pval + wg * 128 + r * 4 + k),
                 cLoadI(P.pidx + wg * 128 + r * 4 + k));
#pragma unroll
        for (int k = 0; k < 4; ++k) { tv[r][ch][k] = m4[k]; ti_[r][ch][k] = mi[k]; }
      }
      __syncthreads();
      if (tid < 32) {
        float m4[4] = {-FLT_MAX, -FLT_MAX, -FLT_MAX, -FLT_MAX};
        int mi[4] = {0x7fffffff, 0x7fffffff, 0x7fffffff, 0x7fffffff};
        for (int g2 = 0; g2 < 8; ++g2)
#pragma unroll
          for (int k = 0; k < 4; ++k) ins4(m4, mi, tv[tid][g2][k], ti_[tid][g2][k]);
#pragma unroll
        for (int k = 0; k < 4; ++k) { rv[tid][k] = m4[k]; rt[tid][k] = mi[k]; }
      }
      __syncthreads();
      if (tid < 8) {
        const int b2 = tid;
        unsigned used = 0;
#pragma unroll
        for (int sel = 0; sel < 4; ++sel) {
          float bestv = -FLT_MAX; int bestj = -1;
          for (int j = 0; j < 16; ++j) {
            if (used & (1u << j)) continue;
            float vv = rv[(j >> 2) * 8 + b2][j & 3];
            if (vv > bestv) { bestv = vv; bestj = j; }  // tie -> lower j
          }
          used |= 1u << bestj;
          const int obn = bestj >> 2;
          const int tkn = rt[obn * 8 + b2][bestj & 3];
          obl[sel][b2] = obn; tkl[sel][b2] = tkn;
          P.obh[t * 32 + sel * 8 + b2] = obn;
          cStoreI(P.tok + sel * 8 + b2, tkn);
        }
        int tmp[4][13];
        for (int n2 = 0; n2 < 4; ++n2)
          for (int s2 = 0; s2 < 13; ++s2) tmp[n2][s2] = res[obl[n2][b2]][s2][b2];
        for (int n2 = 0; n2 < 4; ++n2)
          for (int s2 = 0; s2 < 13; ++s2) res[n2][s2][b2] = tmp[n2][s2];
        for (int n2 = 0; n2 < 4; ++n2) res[n2][t + 1][b2] = tkl[n2][b2];
      }
      __syncthreads();
      if (t < 11) {
        for (int e = tid; e < 16384; e += 256) {
          const int n2 = e >> 12, b3 = (e >> 9) & 7, c3 = e & 511;
          const int obn = obl[n2][b3];
          cStore(P.dech + e, cLoad(P.nh + (size_t)(obn * 8 + b3) * 512 + c3));
          cStore(P.decc + e, cLoad(P.nc + (size_t)(obn * 8 + b3) * 512 + c3));
        }
      } else if (tid < 104) {
        P.res0[tid] = res[0][tid >> 3][tid & 7];  // res0[s][b]
      }
    }
    gbar(P.ctr, ph++, 256);
  }
}

// ---------------------------------------------------------------------------
// Output assembly: backtrace beam-0 path; out = [res(8x13) ; logits(8,V,13)]
// ---------------------------------------------------------------------------
__global__ __launch_bounds__(256) void out_kernel(const __hip_bfloat16* hist,
                                                  const int* obh, const int* res0,
                                                  float* out) {
  const long g = (long)blockIdx.x * 256 + threadIdx.x;
  if (g < 256000) {
    const int b = (int)(g / 32000), v = (int)(g % 32000);
    float* o = out + 104 + (long)(b * 32000 + v) * 13;
    o[0] = (v == 1) ? 1.0f : 0.0f;  // t=0 one-hot at SOS
    int beta = 0;
    for (int t = 11; t >= 0; --t) {
      const int sb = obh[t * 32 + beta * 8 + b];
      o[t + 1] = __bfloat162float(hist[((long)(t * 32 + sb * 8 + b)) * 32000 + v]);
      beta = sb;
    }
  }
  if (blockIdx.x == 0 && threadIdx.x < 104) {
    const int s = threadIdx.x >> 3, b = threadIdx.x & 7;
    out[b * 13 + s] = (float)res0[threadIdx.x];
  }
}

// ---------------------------------------------------------------------------
extern "C" void kernel_launch(void* const* d_in, const int* in_sizes, int n_in,
                              void* d_out, int out_size, void* d_ws, size_t ws_size,
                              hipStream_t stream) {
  const int* text  = (const int*)d_in[0];
  const float* embE = (const float*)d_in[1];
  const float* embD = (const float*)d_in[2];
  const float* Wih0 = (const float*)d_in[3];
  const float* Whh0 = (const float*)d_in[4];
  const float* bih0 = (const float*)d_in[5];
  const float* bhh0 = (const float*)d_in[6];
  const float* Wih1 = (const float*)d_in[7];
  const float* Whh1 = (const float*)d_in[8];
  const float* bih1 = (const float*)d_in[9];
  const float* bhh1 = (const float*)d_in[10];
  const float* dWih = (const float*)d_in[11];
  const float* dWhh = (const float*)d_in[12];
  const float* dbih = (const float*)d_in[13];
  const float* dbhh = (const float*)d_in[14];
  const float* Wq = (const float*)d_in[15];
  const float* bq = (const float*)d_in[16];
  const float* Wk = (const float*)d_in[17];
  const float* bk = (const float*)d_in[18];
  const float* Wv = (const float*)d_in[19];
  const float* bv = (const float*)d_in[20];
  const float* Wo = (const float*)d_in[21];
  const float* bo = (const float*)d_in[22];
  const float* Wout = (const float*)d_in[23];
  const float* bout = (const float*)d_in[24];

  char* ws = (char*)d_ws;
  size_t off = 0;
  auto alloc = [&](size_t bytes) -> char* {
    off = (off + 511) & ~(size_t)511;
    char* p = ws + off;
    off += bytes;
    return p;
  };
  int* ctrE   = (int*)alloc(4);
  int* ctrD   = (int*)alloc(4);
  float* h0buf = (float*)alloc(2 * 4096 * 4);
  float* h1buf = (float*)alloc(2 * 4096 * 4);
  float* h0f  = (float*)alloc(4096 * 4);
  float* h1f  = (float*)alloc(4096 * 4);
  float* c1f  = (float*)alloc(4096 * 4);
  float* kenc = (float*)alloc(8192 * 4);
  float* venc = (float*)alloc(8192 * 4);
  float* dech = (float*)alloc(16384 * 4);
  float* decc = (float*)alloc(16384 * 4);
  float* nh   = (float*)alloc(16384 * 4);
  float* nc   = (float*)alloc(16384 * 4);
  float* qkv  = (float*)alloc(49152 * 4);
  float* ctx  = (float*)alloc(16384 * 4);
  float* out1 = (float*)alloc(16384 * 4);
  int* tok    = (int*)alloc(32 * 4);
  float* pval = (float*)alloc(32768 * 4);
  int* pidx   = (int*)alloc(32768 * 4);
  int* obh    = (int*)alloc(384 * 4);
  int* res0   = (int*)alloc(104 * 4);
  __hip_bfloat16* hist = (__hip_bfloat16*)alloc((size_t)12288000 * 2);
  if (off > ws_size) return;  // ~25.5 MB required

  init_kernel<<<32, 256, 0, stream>>>(h0buf, h1buf, ctrE, ctrD);

  EncP ep{text, embE, Wih0, Whh0, bih0, bhh0, Wih1, Whh1, bih1, bhh1,
          h0buf, h1buf, h0f, h1f, c1f, ctrE};
  enc_kernel<<<128, 256, 0, stream>>>(ep);

  prep_kernel<<<128, 256, 0, stream>>>(Wk, bk, Wv, bv, h0f, h1f, c1f, kenc, venc,
                                       dech, decc, tok);

  DecP dp{embD, dWih, dWhh, dbih, dbhh, Wq, bq, Wk, bk, Wv, bv, Wo, bo,
          Wout, bout, kenc, venc, dech, decc, nh, nc, qkv, ctx, out1, tok,
          pval, pidx, obh, res0, hist, ctrD};
  dec_kernel<<<256, 256, 0, stream>>>(dp);

  out_kernel<<<1000, 256, 0, stream>>>(hist, obh, res0, (float*)d_out);
}

// Round 2
// 11400.844 us; speedup vs baseline: 1.2292x; 1.2292x over previous
//
#include <hip/hip_runtime.h>
#include <hip/hip_bf16.h>
#include <float.h>

// ---------------------------------------------------------------------------
// Beam-search seq2seq (2-layer LSTM encoder S=512, greedy-degenerate 4-beam
// decoder MAXLEN=12, V=32000). Fully fp32 math; bf16 only for stored logits
// history (output tolerance is 2% of absmax).
//
// Cross-WG communication inside persistent kernels uses relaxed AGENT-scope
// atomics (coherent ops bypass the non-coherent per-XCD L2; plain weight
// loads stay L2-resident). Grid barrier = distributed per-WG flag lines
// (1 store/WG + parallel per-thread polling) -- NO contended atomic RMW.
// Ordering: __syncthreads() forces s_waitcnt vmcnt(0) per wave, so all data
// stores complete at the coherence point before the flag store issues.
// ---------------------------------------------------------------------------

#define SCOPE_AGENT __HIP_MEMORY_SCOPE_AGENT

__device__ __forceinline__ float cLoad(const float* p) {
  return __hip_atomic_load(p, __ATOMIC_RELAXED, SCOPE_AGENT);
}
__device__ __forceinline__ void cStore(float* p, float v) {
  __hip_atomic_store(p, v, __ATOMIC_RELAXED, SCOPE_AGENT);
}
__device__ __forceinline__ int cLoadI(const int* p) {
  return __hip_atomic_load(p, __ATOMIC_RELAXED, SCOPE_AGENT);
}
__device__ __forceinline__ void cStoreI(int* p, int v) {
  __hip_atomic_store(p, v, __ATOMIC_RELAXED, SCOPE_AGENT);
}

// Distributed flag barrier for 256 WGs x 256 threads. flags[w*32] holds the
// last phase value WG w reached (monotonic within a launch; init zeroes it).
__device__ __forceinline__ void fbar(int* flags, int target) {
  __syncthreads();  // drains vmcnt -> all data stores at coherence point
  if (threadIdx.x == 0) cStoreI(flags + blockIdx.x * 32, target);
  const int* f = flags + (threadIdx.x & 255) * 32;
  while (cLoadI(f) < target) __builtin_amdgcn_s_sleep(1);
  __syncthreads();
}

__device__ __forceinline__ float sig_(float x) { return 1.0f / (1.0f + expf(-x)); }

// top-4 sorted insert; ordering matches lax.top_k (desc value, tie -> lower idx)
__device__ __forceinline__ void ins4(float* v, int* id, float nv, int ni) {
  if (nv > v[3] || (nv == v[3] && ni < id[3])) {
    v[3] = nv; id[3] = ni;
#pragma unroll
    for (int p = 3; p > 0; --p) {
      bool sw = (v[p] > v[p - 1]) || (v[p] == v[p - 1] && id[p] < id[p - 1]);
      if (sw) {
        float t0 = v[p]; v[p] = v[p - 1]; v[p - 1] = t0;
        int t1 = id[p]; id[p] = id[p - 1]; id[p - 1] = t1;
      }
    }
  }
}

// ---------------------------------------------------------------------------
// init: zero h double-buffers + barrier flags
// ---------------------------------------------------------------------------
__global__ __launch_bounds__(256) void init_kernel(float* h0buf, float* h1buf,
                                                   int* flagE, int* flagD) {
  int g = blockIdx.x * 256 + threadIdx.x;
  if (g < 8192) {
    h0buf[g] = 0.0f; h1buf[g] = 0.0f;
    flagE[g] = 0; flagD[g] = 0;
  }
}

// ---------------------------------------------------------------------------
// Encoder: 256 WGs x 256 thr. WGs 0..127 = layer0, 128..255 = layer1 (skewed
// by one step). Each WG owns 4 h-columns (16 gate rows); threads split as
// 2 k-halves x 16 rows x 8 batch. 513 iterations, 1 flag barrier per step.
// ---------------------------------------------------------------------------
struct EncP {
  const int* text; const float* emb;
  const float* Wih0; const float* Whh0; const float* bih0; const float* bhh0;
  const float* Wih1; const float* Whh1; const float* bih1; const float* bhh1;
  float* h0buf; float* h1buf; float* h0f; float* h1f; float* c1f;
  int* flags;
};

__global__ __launch_bounds__(256, 1) void enc_kernel(EncP P) {
  __shared__ float hsA[8 * 516];   // own-layer recurrent h (pad: 516 % 32 == 4)
  __shared__ float hsB[8 * 516];   // layer1 x stage (h0)
  __shared__ float xs[8 * 260];    // layer0 x stage (emb rows)
  __shared__ float part[2][16][8]; // k-split partial sums
  __shared__ float cl[4][8];       // cell state

  const int w = blockIdx.x, tid = threadIdx.x;
  const int L = w >> 7;
  const int c0 = (w & 127) * 4;
  const int kh = tid >> 7;              // k-half
  const int r = (tid >> 3) & 15;        // row-in-WG: col_l = r>>2, gate = r&3
  const int b = tid & 7;
  const int col_l = r >> 2, gate = r & 3;
  const int row = gate * 512 + c0 + col_l;

  if (tid < 32) cl[tid >> 3][tid & 7] = 0.0f;

  const float* Wih = L ? P.Wih1 : P.Wih0;
  const float* Whh = L ? P.Whh1 : P.Whh0;
  const float bias =
      (kh == 0) ? (L ? (P.bih1[row] + P.bhh1[row]) : (P.bih0[row] + P.bhh0[row]))
                : 0.0f;
  const float4* wih4 = (const float4*)(Wih + (size_t)row * (L ? 512 : 256));
  const float4* whh4 = (const float4*)(Whh + (size_t)row * 512);
  float* myH = L ? P.h1buf : P.h0buf;

  for (int i = 0; i <= 512; ++i) {
    const bool act = L ? (i >= 1) : (i < 512);
    if (act) {
      const int t = L ? (i - 1) : i;
      // ---- stage inputs (coherent loads; data crosses XCDs via L3) ----
      const float* hprev = L ? (P.h1buf + (i & 1) * 4096)
                             : (P.h0buf + ((i + 1) & 1) * 4096);
      for (int e = tid; e < 4096; e += 256)
        hsA[(e >> 9) * 516 + (e & 511)] = cLoad(hprev + e);
      if (L) {
        const float* x0 = P.h0buf + ((i + 1) & 1) * 4096;  // h0_{i-1}
        for (int e = tid; e < 4096; e += 256)
          hsB[(e >> 9) * 516 + (e & 511)] = cLoad(x0 + e);
      } else {
        for (int e = tid; e < 2048; e += 256) {
          int eb = e >> 8, ek = e & 255;
          int tv2 = P.text[t * 8 + eb];
          xs[eb * 260 + ek] = P.emb[(size_t)tv2 * 256 + ek];
        }
      }
      __syncthreads();
      // ---- k-split gate dot (4-way split accumulators per thread) ----
      float s0 = 0.f, s1 = 0.f, s2 = 0.f, s3 = 0.f;
      if (L) {
        const float4* a4 = kh ? whh4 : wih4;
        const float4* x4 = (const float4*)(kh ? hsA : hsB) + b * 129;
#pragma unroll 8
        for (int k = 0; k < 128; ++k) {
          float4 a = a4[k], x = x4[k];
          s0 = fmaf(a.x, x.x, s0); s1 = fmaf(a.y, x.y, s1);
          s2 = fmaf(a.z, x.z, s2); s3 = fmaf(a.w, x.w, s3);
        }
      } else if (kh == 0) {
        const float4* x4 = (const float4*)xs + b * 65;
#pragma unroll 8
        for (int k = 0; k < 64; ++k) {
          float4 a = wih4[k], x = x4[k];
          s0 = fmaf(a.x, x.x, s0); s1 = fmaf(a.y, x.y, s1);
          s2 = fmaf(a.z, x.z, s2); s3 = fmaf(a.w, x.w, s3);
        }
        const float4* h4 = (const float4*)hsA + b * 129;
#pragma unroll 8
        for (int k = 0; k < 32; ++k) {
          float4 a = whh4[k], x = h4[k];
          s0 = fmaf(a.x, x.x, s0); s1 = fmaf(a.y, x.y, s1);
          s2 = fmaf(a.z, x.z, s2); s3 = fmaf(a.w, x.w, s3);
        }
      } else {
        const float4* a4 = whh4 + 32;
        const float4* h4 = (const float4*)hsA + b * 129 + 32;
#pragma unroll 8
        for (int k = 0; k < 96; ++k) {
          float4 a = a4[k], x = h4[k];
          s0 = fmaf(a.x, x.x, s0); s1 = fmaf(a.y, x.y, s1);
          s2 = fmaf(a.z, x.z, s2); s3 = fmaf(a.w, x.w, s3);
        }
      }
      part[kh][r][b] = bias + ((s0 + s1) + (s2 + s3));
      __syncthreads();
      // ---- cell update (one thread per (col, batch)) ----
      if (tid < 32) {
        const int cc = tid >> 3, bb = tid & 7;
        float gi = part[0][cc * 4 + 0][bb] + part[1][cc * 4 + 0][bb];
        float gf = part[0][cc * 4 + 1][bb] + part[1][cc * 4 + 1][bb];
        float gg = part[0][cc * 4 + 2][bb] + part[1][cc * 4 + 2][bb];
        float go = part[0][cc * 4 + 3][bb] + part[1][cc * 4 + 3][bb];
        float cold = cl[cc][bb];
        float c2 = sig_(gf) * cold + sig_(gi) * tanhf(gg);
        float hv = sig_(go) * tanhf(c2);
        cl[cc][bb] = c2;
        cStore(myH + (t & 1) * 4096 + bb * 512 + c0 + cc, hv);
        if (t == 511) {
          (L ? P.h1f : P.h0f)[bb * 512 + c0 + cc] = hv;
          if (L) P.c1f[bb * 512 + c0 + cc] = c2;
        }
      }
    }
    if (i < 512) fbar(P.flags, i + 1);
  }
}

// ---------------------------------------------------------------------------
// prep: k_enc/v_enc projections of [h0f;h1f], decoder state init
// ---------------------------------------------------------------------------
__global__ __launch_bounds__(256) void prep_kernel(
    const float* Wk, const float* bk, const float* Wv, const float* bv,
    const float* h0f, const float* h1f, const float* c1f,
    float* kenc, float* venc, float* dech, float* decc, int* tok) {
  const int w = blockIdx.x, tid = threadIdx.x;
  if (w < 64) {
    const int o = w * 256 + tid;                  // [kv][l][b][c]
    const int kv = o >> 13, l = (o >> 12) & 1, b = (o >> 9) & 7, c = o & 511;
    const float4* h4 = (const float4*)((l ? h1f : h0f) + b * 512);
    const float4* w4 = (const float4*)((kv ? Wv : Wk) + (size_t)c * 512);
    float s0 = 0.f, s1 = 0.f, s2 = 0.f, s3 = 0.f;
#pragma unroll 8
    for (int k = 0; k < 128; ++k) {
      float4 a = w4[k], x = h4[k];
      s0 = fmaf(a.x, x.x, s0); s1 = fmaf(a.y, x.y, s1);
      s2 = fmaf(a.z, x.z, s2); s3 = fmaf(a.w, x.w, s3);
    }
    (kv ? venc : kenc)[l * 4096 + b * 512 + c] =
        (kv ? bv : bk)[c] + ((s0 + s1) + (s2 + s3));
  } else {
    const int o = (w - 64) * 256 + tid;           // [n][b][c] broadcast over n
    dech[o] = h1f[o & 4095];
    decc[o] = c1f[o & 4095];
    if (o < 32) tok[o] = 1;                        // SOS
  }
}

// ---------------------------------------------------------------------------
// Decoder: 256 WGs x 256 thr, 12 steps x 6 barrier phases
// ---------------------------------------------------------------------------
struct DecP {
  const float* emb;
  const float* Wih; const float* Whh; const float* bih; const float* bhh;
  const float* Wq; const float* bq; const float* Wk; const float* bk;
  const float* Wv; const float* bv; const float* Wo; const float* bo;
  const float* Wout; const float* bout;
  const float* kenc; const float* venc;
  float* dech; float* decc; float* nh; float* nc;
  float* qkv;    // [3][32][512]
  float* ctx;    // [32][512]
  float* out1;   // [32][512]
  int* tok;      // [32]
  float* pval; int* pidx;  // [256][32][4]
  int* obh;      // [12][4][8]
  int* res0;     // [13][8]
  __hip_bfloat16* hist;    // [12][32][32000]
  int* flags;
};

// stage [32][512] coherent source into LDS (2 chunks) and dot with one weight
// row; all 256 threads of a WG must call uniformly.
__device__ float stage_dot512(const float* src, const float4* w4row, float* hs,
                              int nb) {
  const int tid = threadIdx.x;
  float s0 = 0.f, s1 = 0.f, s2 = 0.f, s3 = 0.f;
  for (int ck = 0; ck < 2; ++ck) {
    __syncthreads();
    for (int e = tid; e < 8192; e += 256)
      hs[(e >> 8) * 260 + (e & 255)] = cLoad(src + (e >> 8) * 512 + ck * 256 + (e & 255));
    __syncthreads();
    const float4* h4 = (const float4*)hs + nb * 65;
    const float4* w4 = w4row + ck * 64;
#pragma unroll 8
    for (int k = 0; k < 64; ++k) {
      float4 a = w4[k], x = h4[k];
      s0 = fmaf(a.x, x.x, s0); s1 = fmaf(a.y, x.y, s1);
      s2 = fmaf(a.z, x.z, s2); s3 = fmaf(a.w, x.w, s3);
    }
  }
  return (s0 + s1) + (s2 + s3);
}

__global__ __launch_bounds__(256, 1) void dec_kernel(DecP P) {
  __shared__ float hs[32 * 260];
  __shared__ float gl[2][4][32];
  __shared__ float sl[32][3];
  __shared__ float wsm[32][3];
  __shared__ float tv[32][8][4];
  __shared__ int ti_[32][8][4];
  __shared__ float rv[32][4];
  __shared__ int rt[32][4];
  __shared__ int res[4][13][8];
  __shared__ int obl[4][8];
  __shared__ int tkl[4][8];

  const int w = blockIdx.x, tid = threadIdx.x;
  int ph = 0;

  if (tid < 104) {  // res init: all SOS (only WG0's copy is used)
    for (int n = 0; n < 4; ++n) res[n][tid >> 3][tid & 7] = 1;
  }

  for (int t = 0; t < 12; ++t) {
    // ===== A: LSTM gates + cell (WG w owns h-cols [2w, 2w+2)) =====
    {
      const int col_l = tid >> 7, gate = (tid >> 5) & 3, nb = tid & 31;
      const int col = 2 * w + col_l;
      const int row = gate * 512 + col;
      const int tokv = cLoadI(P.tok + nb);
      float s0 = 0.f, s1 = 0.f, s2 = 0.f, s3 = 0.f;
      {
        const float4* a4 = (const float4*)(P.Wih + (size_t)row * 256);
        const float4* x4 = (const float4*)(P.emb + (size_t)tokv * 256);
#pragma unroll 8
        for (int k = 0; k < 64; ++k) {
          float4 a = a4[k], x = x4[k];
          s0 = fmaf(a.x, x.x, s0); s1 = fmaf(a.y, x.y, s1);
          s2 = fmaf(a.z, x.z, s2); s3 = fmaf(a.w, x.w, s3);
        }
      }
      float acc = P.bih[row] + P.bhh[row] + ((s0 + s1) + (s2 + s3));
      acc += stage_dot512(P.dech, (const float4*)(P.Whh + (size_t)row * 512), hs, nb);
      gl[col_l][gate][nb] = acc;
      __syncthreads();
      if (tid < 64) {
        const int cc = tid >> 5, nb2 = tid & 31;
        const int col2 = 2 * w + cc;
        float gi = gl[cc][0][nb2], gf = gl[cc][1][nb2];
        float gg = gl[cc][2][nb2], go = gl[cc][3][nb2];
        float cold = cLoad(P.decc + nb2 * 512 + col2);
        float c2 = sig_(gf) * cold + sig_(gi) * tanhf(gg);
        float hv = sig_(go) * tanhf(c2);
        cStore(P.nh + nb2 * 512 + col2, hv);
        cStore(P.nc + nb2 * 512 + col2, c2);
      }
    }
    fbar(P.flags, ++ph);

    // ===== B: q / kd / vd projections of nh =====
    if (w < 192) {
      const int p = w >> 6, cb = w & 63;
      const int col_l = tid >> 5, nb = tid & 31;
      const int col = cb * 8 + col_l;
      const float* W = (p == 0 ? P.Wq : p == 1 ? P.Wk : P.Wv) + (size_t)col * 512;
      float acc = (p == 0 ? P.bq : p == 1 ? P.bk : P.bv)[col];
      acc += stage_dot512(P.nh, (const float4*)W, hs, nb);
      cStore(P.qkv + p * 16384 + nb * 512 + col, acc);
    }
    fbar(P.flags, ++ph);

    // ===== C: attention scores / softmax(3) / ctx  (WG 0) =====
    if (w == 0) {
      if (tid < 96) {
        const int nb = tid / 3, l = tid % 3, b = nb & 7;
        const float* q = P.qkv + nb * 512;
        const float* kk = (l < 2) ? (P.kenc + l * 4096 + b * 512)
                                  : (P.qkv + 16384 + nb * 512);
        float acc = 0.f;
        for (int k = 0; k < 512; ++k)
          acc = fmaf(cLoad(q + k), (l < 2 ? kk[k] : cLoad(kk + k)), acc);
        sl[nb][l] = acc * (1.0f / sqrtf(512.0f));
      }
      __syncthreads();
      if (tid < 32) {
        float a = sl[tid][0], b2 = sl[tid][1], c3 = sl[tid][2];
        float m = fmaxf(a, fmaxf(b2, c3));
        float e0 = expf(a - m), e1 = expf(b2 - m), e2 = expf(c3 - m);
        float inv = 1.0f / (e0 + e1 + e2);
        wsm[tid][0] = e0 * inv; wsm[tid][1] = e1 * inv; wsm[tid][2] = e2 * inv;
      }
      __syncthreads();
      for (int e = tid; e < 16384; e += 256) {
        const int nb = e >> 9, c = e & 511, b = nb & 7;
        float v0 = P.venc[b * 512 + c];
        float v1 = P.venc[4096 + b * 512 + c];
        float v2 = cLoad(P.qkv + 32768 + nb * 512 + c);
        cStore(P.ctx + e, wsm[nb][0] * v0 + wsm[nb][1] * v1 + wsm[nb][2] * v2);
      }
    }
    fbar(P.flags, ++ph);

    // ===== D: out1 = ctx @ Wo.T + bo =====
    if (w < 64) {
      const int col_l = tid >> 5, nb = tid & 31;
      const int col = w * 8 + col_l;
      float acc = P.bo[col];
      acc += stage_dot512(P.ctx, (const float4*)(P.Wo + (size_t)col * 512), hs, nb);
      cStore(P.out1 + nb * 512 + col, acc);
    }
    fbar(P.flags, ++ph);

    // ===== E: logits (+bout), bf16 history store, per-WG partial top-4 =====
    {
      const int nb = tid >> 3, cg = tid & 7;
      const int cbase = w * 125;
      float acc[16];
#pragma unroll
      for (int j = 0; j < 16; ++j) acc[j] = 0.0f;
      for (int ck = 0; ck < 2; ++ck) {
        __syncthreads();
        for (int e = tid; e < 8192; e += 256)
          hs[(e >> 8) * 260 + (e & 255)] =
              cLoad(P.out1 + (e >> 8) * 512 + ck * 256 + (e & 255));
        __syncthreads();
        const float4* h4 = (const float4*)hs + nb * 65;
#pragma unroll
        for (int j = 0; j < 16; ++j) {
          const int cl2 = cg + 8 * j;
          if (cl2 < 125) {
            const float4* w4 =
                (const float4*)(P.Wout + (size_t)(cbase + cl2) * 512 + ck * 256);
            float p0 = 0.f, p1 = 0.f;
#pragma unroll 4
            for (int k = 0; k < 64; ++k) {
              float4 a = w4[k], x = h4[k];
              p0 = fmaf(a.x, x.x, p0); p0 = fmaf(a.y, x.y, p0);
              p1 = fmaf(a.z, x.z, p1); p1 = fmaf(a.w, x.w, p1);
            }
            acc[j] += p0 + p1;
          }
        }
      }
      float v4[4] = {-FLT_MAX, -FLT_MAX, -FLT_MAX, -FLT_MAX};
      int i4[4] = {0x7fffffff, 0x7fffffff, 0x7fffffff, 0x7fffffff};
#pragma unroll
      for (int j = 0; j < 16; ++j) {
        const int cl2 = cg + 8 * j;
        if (cl2 < 125) {
          const int c = cbase + cl2;
          const float v = acc[j] + P.bout[c];
          P.hist[(size_t)t * 1024000 + (size_t)nb * 32000 + c] = __float2bfloat16(v);
          ins4(v4, i4, v, c);
        }
      }
#pragma unroll
      for (int k = 0; k < 4; ++k) { tv[nb][cg][k] = v4[k]; ti_[nb][cg][k] = i4[k]; }
      __syncthreads();
      if (tid < 32) {
        float m4[4] = {-FLT_MAX, -FLT_MAX, -FLT_MAX, -FLT_MAX};
        int mi[4] = {0x7fffffff, 0x7fffffff, 0x7fffffff, 0x7fffffff};
        for (int g2 = 0; g2 < 8; ++g2)
#pragma unroll
          for (int k = 0; k < 4; ++k) ins4(m4, mi, tv[tid][g2][k], ti_[tid][g2][k]);
#pragma unroll
        for (int k = 0; k < 4; ++k) {
          cStore(P.pval + w * 128 + tid * 4 + k, m4[k]);
          cStoreI(P.pidx + w * 128 + tid * 4 + k, mi[k]);
        }
      }
    }
    fbar(P.flags, ++ph);

    // ===== F: global top-4/row, beam candidate select, state reorder (WG 0) =====
    if (w == 0) {
      {
        const int r = tid >> 3, ch = tid & 7;
        float m4[4] = {-FLT_MAX, -FLT_MAX, -FLT_MAX, -FLT_MAX};
        int mi[4] = {0x7fffffff, 0x7fffffff, 0x7fffffff, 0x7fffffff};
        for (int wg = ch * 32; wg < ch * 32 + 32; ++wg)
#pragma unroll
          for (int k = 0; k < 4; ++k)
            ins4(m4, mi, cLoad(P.pval + wg * 128 + r * 4 + k),
                 cLoadI(P.pidx + wg * 128 + r * 4 + k));
#pragma unroll
        for (int k = 0; k < 4; ++k) { tv[r][ch][k] = m4[k]; ti_[r][ch][k] = mi[k]; }
      }
      __syncthreads();
      if (tid < 32) {
        float m4[4] = {-FLT_MAX, -FLT_MAX, -FLT_MAX, -FLT_MAX};
        int mi[4] = {0x7fffffff, 0x7fffffff, 0x7fffffff, 0x7fffffff};
        for (int g2 = 0; g2 < 8; ++g2)
#pragma unroll
          for (int k = 0; k < 4; ++k) ins4(m4, mi, tv[tid][g2][k], ti_[tid][g2][k]);
#pragma unroll
        for (int k = 0; k < 4; ++k) { rv[tid][k] = m4[k]; rt[tid][k] = mi[k]; }
      }
      __syncthreads();
      if (tid < 8) {
        const int b2 = tid;
        unsigned used = 0;
#pragma unroll
        for (int sel = 0; sel < 4; ++sel) {
          float bestv = -FLT_MAX; int bestj = -1;
          for (int j = 0; j < 16; ++j) {
            if (used & (1u << j)) continue;
            float vv = rv[(j >> 2) * 8 + b2][j & 3];
            if (vv > bestv) { bestv = vv; bestj = j; }  // tie -> lower j
          }
          used |= 1u << bestj;
          const int obn = bestj >> 2;
          const int tkn = rt[obn * 8 + b2][bestj & 3];
          obl[sel][b2] = obn; tkl[sel][b2] = tkn;
          P.obh[t * 32 + sel * 8 + b2] = obn;
          cStoreI(P.tok + sel * 8 + b2, tkn);
        }
        int tmp[4][13];
        for (int n2 = 0; n2 < 4; ++n2)
          for (int s2 = 0; s2 < 13; ++s2) tmp[n2][s2] = res[obl[n2][b2]][s2][b2];
        for (int n2 = 0; n2 < 4; ++n2)
          for (int s2 = 0; s2 < 13; ++s2) res[n2][s2][b2] = tmp[n2][s2];
        for (int n2 = 0; n2 < 4; ++n2) res[n2][t + 1][b2] = tkl[n2][b2];
      }
      __syncthreads();
      if (t < 11) {
        for (int e = tid; e < 16384; e += 256) {
          const int n2 = e >> 12, b3 = (e >> 9) & 7, c3 = e & 511;
          const int obn = obl[n2][b3];
          cStore(P.dech + e, cLoad(P.nh + (size_t)(obn * 8 + b3) * 512 + c3));
          cStore(P.decc + e, cLoad(P.nc + (size_t)(obn * 8 + b3) * 512 + c3));
        }
      } else if (tid < 104) {
        P.res0[tid] = res[0][tid >> 3][tid & 7];  // res0[s][b]
      }
    }
    fbar(P.flags, ++ph);
  }
}

// ---------------------------------------------------------------------------
// Output assembly: backtrace beam-0 path; out = [res(8x13) ; logits(8,V,13)]
// ---------------------------------------------------------------------------
__global__ __launch_bounds__(256) void out_kernel(const __hip_bfloat16* hist,
                                                  const int* obh, const int* res0,
                                                  float* out) {
  const long g = (long)blockIdx.x * 256 + threadIdx.x;
  if (g < 256000) {
    const int b = (int)(g / 32000), v = (int)(g % 32000);
    float* o = out + 104 + (long)(b * 32000 + v) * 13;
    o[0] = (v == 1) ? 1.0f : 0.0f;  // t=0 one-hot at SOS
    int beta = 0;
    for (int t = 11; t >= 0; --t) {
      const int sb = obh[t * 32 + beta * 8 + b];
      o[t + 1] = __bfloat162float(hist[((long)(t * 32 + sb * 8 + b)) * 32000 + v]);
      beta = sb;
    }
  }
  if (blockIdx.x == 0 && threadIdx.x < 104) {
    const int s = threadIdx.x >> 3, b = threadIdx.x & 7;
    out[b * 13 + s] = (float)res0[threadIdx.x];
  }
}

// ---------------------------------------------------------------------------
extern "C" void kernel_launch(void* const* d_in, const int* in_sizes, int n_in,
                              void* d_out, int out_size, void* d_ws, size_t ws_size,
                              hipStream_t stream) {
  const int* text  = (const int*)d_in[0];
  const float* embE = (const float*)d_in[1];
  const float* embD = (const float*)d_in[2];
  const float* Wih0 = (const float*)d_in[3];
  const float* Whh0 = (const float*)d_in[4];
  const float* bih0 = (const float*)d_in[5];
  const float* bhh0 = (const float*)d_in[6];
  const float* Wih1 = (const float*)d_in[7];
  const float* Whh1 = (const float*)d_in[8];
  const float* bih1 = (const float*)d_in[9];
  const float* bhh1 = (const float*)d_in[10];
  const float* dWih = (const float*)d_in[11];
  const float* dWhh = (const float*)d_in[12];
  const float* dbih = (const float*)d_in[13];
  const float* dbhh = (const float*)d_in[14];
  const float* Wq = (const float*)d_in[15];
  const float* bq = (const float*)d_in[16];
  const float* Wk = (const float*)d_in[17];
  const float* bk = (const float*)d_in[18];
  const float* Wv = (const float*)d_in[19];
  const float* bv = (const float*)d_in[20];
  const float* Wo = (const float*)d_in[21];
  const float* bo = (const float*)d_in[22];
  const float* Wout = (const float*)d_in[23];
  const float* bout = (const float*)d_in[24];

  char* ws = (char*)d_ws;
  size_t off = 0;
  auto alloc = [&](size_t bytes) -> char* {
    off = (off + 511) & ~(size_t)511;
    char* p = ws + off;
    off += bytes;
    return p;
  };
  int* flagE  = (int*)alloc(8192 * 4);
  int* flagD  = (int*)alloc(8192 * 4);
  float* h0buf = (float*)alloc(2 * 4096 * 4);
  float* h1buf = (float*)alloc(2 * 4096 * 4);
  float* h0f  = (float*)alloc(4096 * 4);
  float* h1f  = (float*)alloc(4096 * 4);
  float* c1f  = (float*)alloc(4096 * 4);
  float* kenc = (float*)alloc(8192 * 4);
  float* venc = (float*)alloc(8192 * 4);
  float* dech = (float*)alloc(16384 * 4);
  float* decc = (float*)alloc(16384 * 4);
  float* nh   = (float*)alloc(16384 * 4);
  float* nc   = (float*)alloc(16384 * 4);
  float* qkv  = (float*)alloc(49152 * 4);
  float* ctx  = (float*)alloc(16384 * 4);
  float* out1 = (float*)alloc(16384 * 4);
  int* tok    = (int*)alloc(32 * 4);
  float* pval = (float*)alloc(32768 * 4);
  int* pidx   = (int*)alloc(32768 * 4);
  int* obh    = (int*)alloc(384 * 4);
  int* res0   = (int*)alloc(104 * 4);
  __hip_bfloat16* hist = (__hip_bfloat16*)alloc((size_t)12288000 * 2);
  if (off > ws_size) return;  // ~25.6 MB required

  init_kernel<<<32, 256, 0, stream>>>(h0buf, h1buf, flagE, flagD);

  EncP ep{text, embE, Wih0, Whh0, bih0, bhh0, Wih1, Whh1, bih1, bhh1,
          h0buf, h1buf, h0f, h1f, c1f, flagE};
  enc_kernel<<<256, 256, 0, stream>>>(ep);

  prep_kernel<<<128, 256, 0, stream>>>(Wk, bk, Wv, bv, h0f, h1f, c1f, kenc, venc,
                                       dech, decc, tok);

  DecP dp{embD, dWih, dWhh, dbih, dbhh, Wq, bq, Wk, bk, Wv, bv, Wo, bo,
          Wout, bout, kenc, venc, dech, decc, nh, nc, qkv, ctx, out1, tok,
          pval, pidx, obh, res0, hist, flagD};
  dec_kernel<<<256, 256, 0, stream>>>(dp);

  out_kernel<<<1000, 256, 0, stream>>>(hist, obh, res0, (float*)d_out);
}

// Round 3
// 10228.342 us; speedup vs baseline: 1.3701x; 1.1146x over previous
//
#include <hip/hip_runtime.h>
#include <hip/hip_bf16.h>
#include <float.h>

// ---------------------------------------------------------------------------
// Beam-search seq2seq (2-layer LSTM encoder S=512, 4-beam decoder MAXLEN=12,
// V=32000). fp32 math; bf16 only for stored logits history.
//
// Cross-WG data uses relaxed AGENT-scope atomics (coherent path via LLC; the
// per-XCD L2s are not cross-coherent for plain accesses). Grid barrier =
// epoch barrier: per-WG arrival lines, WG0 aggregates (1 thread : 1 WG), then
// one broadcast line that all lanes poll (coalesced single-line reads).
// __syncthreads() before arrival drains vmcnt -> data stores are at the
// coherence point before the flag store issues.
// ---------------------------------------------------------------------------

using ull = unsigned long long;

#define SCOPE_AGENT __HIP_MEMORY_SCOPE_AGENT

__device__ __forceinline__ float cLoad(const float* p) {
  return __hip_atomic_load(p, __ATOMIC_RELAXED, SCOPE_AGENT);
}
__device__ __forceinline__ void cStore(float* p, float v) {
  __hip_atomic_store(p, v, __ATOMIC_RELAXED, SCOPE_AGENT);
}
__device__ __forceinline__ int cLoadI(const int* p) {
  return __hip_atomic_load(p, __ATOMIC_RELAXED, SCOPE_AGENT);
}
__device__ __forceinline__ void cStoreI(int* p, int v) {
  __hip_atomic_store(p, v, __ATOMIC_RELAXED, SCOPE_AGENT);
}
__device__ __forceinline__ ull cLoad64(const ull* p) {
  return __hip_atomic_load(p, __ATOMIC_RELAXED, SCOPE_AGENT);
}

__device__ __forceinline__ float2 u2f2(ull u) {
  union { ull u; float2 f; } c; c.u = u; return c.f;
}

// Epoch barrier for a 256-WG grid. arr = 256 lines (stride 32 ints),
// gf = 1 broadcast line. phase is monotonically increasing from 1.
__device__ __forceinline__ void fbar(int* arr, int* gf, int phase) {
  __syncthreads();  // drain vmcnt: all coherent data stores complete
  if (threadIdx.x == 0) cStoreI(arr + blockIdx.x * 32, phase);
  if (blockIdx.x == 0) {
    const int* f = arr + threadIdx.x * 32;   // thread t waits for WG t
    while (cLoadI(f) < phase) __builtin_amdgcn_s_sleep(1);
    __syncthreads();
    if (threadIdx.x == 0) cStoreI(gf, phase);
  } else {
    while (cLoadI(gf) < phase) __builtin_amdgcn_s_sleep(1);
    __syncthreads();
  }
}

__device__ __forceinline__ float sig_(float x) { return 1.0f / (1.0f + expf(-x)); }

// top-4 sorted insert; ordering matches lax.top_k (desc value, tie -> lower idx)
__device__ __forceinline__ void ins4(float* v, int* id, float nv, int ni) {
  if (nv > v[3] || (nv == v[3] && ni < id[3])) {
    v[3] = nv; id[3] = ni;
#pragma unroll
    for (int p = 3; p > 0; --p) {
      bool sw = (v[p] > v[p - 1]) || (v[p] == v[p - 1] && id[p] < id[p - 1]);
      if (sw) {
        float t0 = v[p]; v[p] = v[p - 1]; v[p - 1] = t0;
        int t1 = id[p]; id[p] = id[p - 1]; id[p - 1] = t1;
      }
    }
  }
}

// ---------------------------------------------------------------------------
// init: zero h double-buffers + barrier arrival/broadcast lines
// ---------------------------------------------------------------------------
__global__ __launch_bounds__(256) void init_kernel(float* h0buf, float* h1buf,
                                                   int* arrE, int* gfE,
                                                   int* arrD, int* gfD) {
  int g = blockIdx.x * 256 + threadIdx.x;
  if (g < 8192) {
    h0buf[g] = 0.0f; h1buf[g] = 0.0f;
    arrE[g] = 0; arrD[g] = 0;
  }
  if (g < 32) { gfE[g] = 0; gfD[g] = 0; }
}

// ---------------------------------------------------------------------------
// Encoder: 256 WGs x 256 thr. WGs 0..127 = layer0, 128..255 = layer1 (skewed
// by one step). WG owns 4 h-cols. thread = (kh8, col4, b8): computes the 4
// gate rows of one col for one batch over a 1/8 k-slice -> x-LDS reads are
// amortized over 4 gate rows (32 ds_read_b128/thread/step, not 128).
// ---------------------------------------------------------------------------
struct EncP {
  const int* text; const float* emb;
  const float* Wih0; const float* Whh0; const float* bih0; const float* bhh0;
  const float* Wih1; const float* Whh1; const float* bih1; const float* bhh1;
  float* h0buf; float* h1buf; float* h0f; float* h1f; float* c1f;
  int* arr; int* gf;
};

template <int KX>
__device__ void enc_run(const EncP& P, float* xcat, int w, int tid) {
  constexpr int KTOT = KX + 512;
  constexpr int ST = KTOT + 4;       // float stride per batch (ST%32==4)
  constexpr int KSL = KTOT / 8;      // k-floats per kh slice (96 / 128)
  constexpr int Q = KSL / 4;         // f4 per slice (24 / 32)
  constexpr int L = (KX == 512) ? 1 : 0;
  __shared__ float part[16 * 8 * 8]; // [r16][b8][kh8]
  __shared__ float gl[128];          // [r16][b8]

  const int c0 = (w & 127) * 4;
  const int kh = tid >> 5, col = (tid >> 3) & 3, b = tid & 7;
  const int kbase = kh * KSL;

  const float* Wih = L ? P.Wih1 : P.Wih0;
  const float* Whh = L ? P.Whh1 : P.Whh0;

  const float4* wih4[4]; const float4* whh4[4];
#pragma unroll
  for (int g = 0; g < 4; ++g) {
    const int row = g * 512 + c0 + col;
    wih4[g] = (const float4*)(Wih + (size_t)row * KX);
    whh4[g] = (const float4*)(Whh + (size_t)row * 512);
  }
  float bsum = 0.f;
  if (tid < 128) {
    const int r = tid >> 3;
    const int row = (r & 3) * 512 + c0 + (r >> 2);
    bsum = (L ? P.bih1[row] + P.bhh1[row] : P.bih0[row] + P.bhh0[row]);
  }
  float creg = 0.f;  // cell state, threads tid<32
  float* myH = L ? P.h1buf : P.h0buf;

  // wih/whh split point of this thread's k-slice
  int qx = (KX - kbase) / 4;
  qx = qx < 0 ? 0 : (qx > Q ? Q : qx);

  for (int i = 0; i <= 512; ++i) {
    const bool act = L ? (i >= 1) : (i < 512);
    if (act) {
      const int t = L ? (i - 1) : i;
      // ---- stage [x ; h] per batch into xcat (8B coherent loads) ----
      if constexpr (KX == 256) {
        for (int e = tid; e < 1024; e += 256) {
          const int b2 = e >> 7, k2 = e & 127;
          const int tokv = P.text[t * 8 + b2];
          float2 v = *(const float2*)(P.emb + (size_t)tokv * 256 + 2 * k2);
          *(float2*)(xcat + b2 * ST + 2 * k2) = v;
        }
      } else {
        const ull* x0 = (const ull*)(P.h0buf + ((i + 1) & 1) * 4096);
        for (int e = tid; e < 2048; e += 256) {
          const int b2 = e >> 8, k2 = e & 255;
          ull u = cLoad64(x0 + b2 * 256 + k2);
          *(ull*)(xcat + b2 * ST + 2 * k2) = u;
        }
      }
      {
        const float* hp = L ? (P.h1buf + (i & 1) * 4096)
                            : (P.h0buf + ((i + 1) & 1) * 4096);
        const ull* hq = (const ull*)hp;
        for (int e = tid; e < 2048; e += 256) {
          const int b2 = e >> 8, k2 = e & 255;
          ull u = cLoad64(hq + b2 * 256 + k2);
          *(ull*)(xcat + b2 * ST + KX + 2 * k2) = u;
        }
      }
      __syncthreads();
      // ---- 4-gate dot over this thread's k-slice ----
      float a0 = 0.f, a1 = 0.f, a2 = 0.f, a3 = 0.f;
      const float4* xq = (const float4*)(xcat + b * ST + kbase);
      const int iw = kbase >> 2, ih = (kbase - KX) >> 2;
#pragma unroll 4
      for (int q = 0; q < qx; ++q) {
        float4 x = xq[q];
        float4 w0 = wih4[0][iw + q], w1 = wih4[1][iw + q];
        float4 w2 = wih4[2][iw + q], w3 = wih4[3][iw + q];
        a0 = fmaf(w0.x, x.x, a0); a0 = fmaf(w0.y, x.y, a0);
        a0 = fmaf(w0.z, x.z, a0); a0 = fmaf(w0.w, x.w, a0);
        a1 = fmaf(w1.x, x.x, a1); a1 = fmaf(w1.y, x.y, a1);
        a1 = fmaf(w1.z, x.z, a1); a1 = fmaf(w1.w, x.w, a1);
        a2 = fmaf(w2.x, x.x, a2); a2 = fmaf(w2.y, x.y, a2);
        a2 = fmaf(w2.z, x.z, a2); a2 = fmaf(w2.w, x.w, a2);
        a3 = fmaf(w3.x, x.x, a3); a3 = fmaf(w3.y, x.y, a3);
        a3 = fmaf(w3.z, x.z, a3); a3 = fmaf(w3.w, x.w, a3);
      }
#pragma unroll 4
      for (int q = qx; q < Q; ++q) {
        float4 x = xq[q];
        float4 w0 = whh4[0][ih + q], w1 = whh4[1][ih + q];
        float4 w2 = whh4[2][ih + q], w3 = whh4[3][ih + q];
        a0 = fmaf(w0.x, x.x, a0); a0 = fmaf(w0.y, x.y, a0);
        a0 = fmaf(w0.z, x.z, a0); a0 = fmaf(w0.w, x.w, a0);
        a1 = fmaf(w1.x, x.x, a1); a1 = fmaf(w1.y, x.y, a1);
        a1 = fmaf(w1.z, x.z, a1); a1 = fmaf(w1.w, x.w, a1);
        a2 = fmaf(w2.x, x.x, a2); a2 = fmaf(w2.y, x.y, a2);
        a2 = fmaf(w2.z, x.z, a2); a2 = fmaf(w2.w, x.w, a2);
        a3 = fmaf(w3.x, x.x, a3); a3 = fmaf(w3.y, x.y, a3);
        a3 = fmaf(w3.z, x.z, a3); a3 = fmaf(w3.w, x.w, a3);
      }
      part[((col * 4 + 0) * 8 + b) * 8 + kh] = a0;
      part[((col * 4 + 1) * 8 + b) * 8 + kh] = a1;
      part[((col * 4 + 2) * 8 + b) * 8 + kh] = a2;
      part[((col * 4 + 3) * 8 + b) * 8 + kh] = a3;
      __syncthreads();
      if (tid < 128) {
        const int r = tid >> 3, b2 = tid & 7;
        const float4* pp = (const float4*)(part + (r * 8 + b2) * 8);
        float4 p0 = pp[0], p1 = pp[1];
        gl[r * 8 + b2] =
            bsum + (((p0.x + p0.y) + (p0.z + p0.w)) + ((p1.x + p1.y) + (p1.z + p1.w)));
      }
      __syncthreads();
      if (tid < 32) {
        const int cc = tid >> 3, b2 = tid & 7;
        float gi = gl[(cc * 4 + 0) * 8 + b2], gf_ = gl[(cc * 4 + 1) * 8 + b2];
        float gg = gl[(cc * 4 + 2) * 8 + b2], go = gl[(cc * 4 + 3) * 8 + b2];
        float c2 = sig_(gf_) * creg + sig_(gi) * tanhf(gg);
        float hv = sig_(go) * tanhf(c2);
        creg = c2;
        cStore(myH + (t & 1) * 4096 + b2 * 512 + c0 + cc, hv);
        if (t == 511) {
          (L ? P.h1f : P.h0f)[b2 * 512 + c0 + cc] = hv;
          if (L) P.c1f[b2 * 512 + c0 + cc] = c2;
        }
      }
    }
    if (i < 512) fbar(P.arr, P.gf, i + 1);
  }
}

__global__ __launch_bounds__(256, 1) void enc_kernel(EncP P) {
  __shared__ float xcat0[8 * 772];
  __shared__ float xcat1[8 * 1028];
  if (blockIdx.x >> 7) enc_run<512>(P, xcat1, blockIdx.x, threadIdx.x);
  else enc_run<256>(P, xcat0, blockIdx.x, threadIdx.x);
}

// ---------------------------------------------------------------------------
// prep: k_enc/v_enc projections of [h0f;h1f], decoder state init
// ---------------------------------------------------------------------------
__global__ __launch_bounds__(256) void prep_kernel(
    const float* Wk, const float* bk, const float* Wv, const float* bv,
    const float* h0f, const float* h1f, const float* c1f,
    float* kenc, float* venc, float* dech, float* decc, int* tok) {
  const int w = blockIdx.x, tid = threadIdx.x;
  if (w < 64) {
    const int o = w * 256 + tid;                  // [kv][l][b][c]
    const int kv = o >> 13, l = (o >> 12) & 1, b = (o >> 9) & 7, c = o & 511;
    const float4* h4 = (const float4*)((l ? h1f : h0f) + b * 512);
    const float4* w4 = (const float4*)((kv ? Wv : Wk) + (size_t)c * 512);
    float s0 = 0.f, s1 = 0.f, s2 = 0.f, s3 = 0.f;
#pragma unroll 8
    for (int k = 0; k < 128; ++k) {
      float4 a = w4[k], x = h4[k];
      s0 = fmaf(a.x, x.x, s0); s1 = fmaf(a.y, x.y, s1);
      s2 = fmaf(a.z, x.z, s2); s3 = fmaf(a.w, x.w, s3);
    }
    (kv ? venc : kenc)[l * 4096 + b * 512 + c] =
        (kv ? bv : bk)[c] + ((s0 + s1) + (s2 + s3));
  } else {
    const int o = (w - 64) * 256 + tid;           // [n][b][c] broadcast over n
    dech[o] = h1f[o & 4095];
    decc[o] = c1f[o & 4095];
    if (o < 32) tok[o] = 1;                        // SOS
  }
}

// ---------------------------------------------------------------------------
// prep2: one-time attention algebra folds.
//   At = Wk.T @ Wq               (s2 quadratic form, row-major [d][c])
//   W2 = Wo @ Wv                 (vd@Wo.T as one projection of nh)
//   u[c] = sum_i Wq[i][c]bk[i] + Wk[i][c]bq[i]     (s2 bias-cross terms)
//   pvec[l][b][c] = sum_i Wq[i][c] kenc[l][b][i]   (enc-key scores)
//   veWo[l][b][j] = sum_c Wo[j][c] venc[l][b][c]
//   bvo[j] = sum_c Wo[j][c] bv[c];  sl0[l][b] = bq.kenc;  sbb = bq.bk
// ---------------------------------------------------------------------------
__global__ __launch_bounds__(256) void prep2_kernel(
    const float* Wq, const float* Wk, const float* Wv, const float* Wo,
    const float* bq, const float* bk, const float* bv,
    const float* kenc, const float* venc,
    float* At, float* W2, float* u, float* pvec, float* veWo, float* bvo,
    float* sl0, float* sbb) {
  const int w = blockIdx.x, tid = threadIdx.x;
#pragma unroll 1
  for (int sub = 0; sub < 2; ++sub) {
    const int d = 2 * w + sub;
    for (int cc = 0; cc < 2; ++cc) {
      const int c = tid + cc * 256;
      float s0 = 0.f, s1 = 0.f, s2 = 0.f, s3 = 0.f;
      for (int i = 0; i < 512; i += 4) {
        s0 = fmaf(Wk[(i + 0) * 512 + d], Wq[(i + 0) * 512 + c], s0);
        s1 = fmaf(Wk[(i + 1) * 512 + d], Wq[(i + 1) * 512 + c], s1);
        s2 = fmaf(Wk[(i + 2) * 512 + d], Wq[(i + 2) * 512 + c], s2);
        s3 = fmaf(Wk[(i + 3) * 512 + d], Wq[(i + 3) * 512 + c], s3);
      }
      At[(size_t)d * 512 + c] = (s0 + s1) + (s2 + s3);
    }
    for (int cc = 0; cc < 2; ++cc) {
      const int dc = tid + cc * 256;
      float s0 = 0.f, s1 = 0.f, s2 = 0.f, s3 = 0.f;
      const float* wor = Wo + (size_t)d * 512;
      for (int c2 = 0; c2 < 512; c2 += 4) {
        s0 = fmaf(wor[c2 + 0], Wv[(size_t)(c2 + 0) * 512 + dc], s0);
        s1 = fmaf(wor[c2 + 1], Wv[(size_t)(c2 + 1) * 512 + dc], s1);
        s2 = fmaf(wor[c2 + 2], Wv[(size_t)(c2 + 2) * 512 + dc], s2);
        s3 = fmaf(wor[c2 + 3], Wv[(size_t)(c2 + 3) * 512 + dc], s3);
      }
      W2[(size_t)d * 512 + dc] = (s0 + s1) + (s2 + s3);
    }
  }
  if (w == 0) {
    for (int cc = 0; cc < 2; ++cc) {
      const int c = tid + cc * 256;
      float a = 0.f;
      for (int i = 0; i < 512; ++i)
        a += Wq[i * 512 + c] * bk[i] + Wk[i * 512 + c] * bq[i];
      u[c] = a;
    }
  } else if (w <= 32) {
    const int idx = (w - 1) * 256 + tid;          // 8192 = [l][b][c]
    const int l = idx >> 12, b = (idx >> 9) & 7, c = idx & 511;
    const float* ke = kenc + l * 4096 + b * 512;
    float a = 0.f;
    for (int i = 0; i < 512; ++i) a = fmaf(Wq[i * 512 + c], ke[i], a);
    pvec[idx] = a;
  } else if (w <= 64) {
    const int idx = (w - 33) * 256 + tid;         // 8192 = [l][b][j]
    const int l = idx >> 12, b = (idx >> 9) & 7, j = idx & 511;
    const float* ve = venc + l * 4096 + b * 512;
    const float* wo = Wo + (size_t)j * 512;
    float a = 0.f;
    for (int c = 0; c < 512; ++c) a = fmaf(wo[c], ve[c], a);
    veWo[idx] = a;
  } else if (w == 65) {
    for (int cc = 0; cc < 2; ++cc) {
      const int j = tid + cc * 256;
      const float* wo = Wo + (size_t)j * 512;
      float a = 0.f;
      for (int c = 0; c < 512; ++c) a = fmaf(wo[c], bv[c], a);
      bvo[j] = a;
    }
  } else if (w == 66) {
    if (tid < 16) {
      const int l = tid >> 3, b = tid & 7;
      const float* ke = kenc + l * 4096 + b * 512;
      float a = 0.f;
      for (int i = 0; i < 512; ++i) a = fmaf(bq[i], ke[i], a);
      sl0[tid] = a;
    } else if (tid == 16) {
      float a = 0.f;
      for (int i = 0; i < 512; ++i) a = fmaf(bq[i], bk[i], a);
      sbb[0] = a;
    }
  }
}

// ---------------------------------------------------------------------------
// Decoder: 256 WGs x 256 thr, 12 steps x 5 barrier phases
// ---------------------------------------------------------------------------
struct DecP {
  const float* emb;
  const float* Wih; const float* Whh; const float* bih; const float* bhh;
  const float* bo; const float* Wout; const float* bout;
  const float* At; const float* W2; const float* u; const float* bvo;
  const float* pvec; const float* sl0; const float* sbb; const float* veWo;
  float* dech; float* decc; float* nh; float* nc;
  float* mbuf;   // [32][512]  nh@At.T + u
  float* vbuf;   // [32][512]  nh@W2.T + bvo
  float* out1;   // [32][512]
  int* tok;      // [32]
  float* pval; int* pidx;  // [256][32][4]
  int* obh;      // [12][4][8]
  int* res0;     // [13][8]
  __hip_bfloat16* hist;    // [12][32][32000]
  int* arr; int* gf;
};

// stage [32][512] coherent source into LDS (2 chunks, 8B loads) and dot with
// one weight row; all 256 threads of a WG must call uniformly.
__device__ float stage_dot512(const float* src, const float4* w4row, float* hs,
                              int nb) {
  const int tid = threadIdx.x;
  float s0 = 0.f, s1 = 0.f, s2 = 0.f, s3 = 0.f;
  for (int ck = 0; ck < 2; ++ck) {
    __syncthreads();
    const ull* s8 = (const ull*)src;
    for (int e = tid; e < 4096; e += 256) {
      const int nb2 = e >> 7, k2 = e & 127;
      ull v = cLoad64(s8 + nb2 * 256 + ck * 128 + k2);
      *(ull*)(hs + nb2 * 260 + 2 * k2) = v;
    }
    __syncthreads();
    const float4* h4 = (const float4*)hs + nb * 65;
    const float4* w4 = w4row + ck * 64;
#pragma unroll 8
    for (int k = 0; k < 64; ++k) {
      float4 a = w4[k], x = h4[k];
      s0 = fmaf(a.x, x.x, s0); s1 = fmaf(a.y, x.y, s1);
      s2 = fmaf(a.z, x.z, s2); s3 = fmaf(a.w, x.w, s3);
    }
  }
  return (s0 + s1) + (s2 + s3);
}

__global__ __launch_bounds__(256, 1) void dec_kernel(DecP P) {
  __shared__ float hs[32 * 260];
  __shared__ float gl[2][4][32];
  __shared__ float sl[32][3];
  __shared__ float wsm[32][3];
  __shared__ float tv[32][8][4];
  __shared__ int ti_[32][8][4];
  __shared__ float rv[32][4];
  __shared__ int rt[32][4];
  __shared__ int res[4][13][8];
  __shared__ int obl[4][8];
  __shared__ int tkl[4][8];

  const int w = blockIdx.x, tid = threadIdx.x;
  int ph = 0;

  if (tid < 104) {  // res init: all SOS (only WG0's copy is used)
    for (int n = 0; n < 4; ++n) res[n][tid >> 3][tid & 7] = 1;
  }

  for (int t = 0; t < 12; ++t) {
    // ===== A: LSTM gates + cell (WG w owns h-cols [2w, 2w+2)) =====
    {
      const int col_l = tid >> 7, gate = (tid >> 5) & 3, nb = tid & 31;
      const int col = 2 * w + col_l;
      const int row = gate * 512 + col;
      const int tokv = cLoadI(P.tok + nb);
      float s0 = 0.f, s1 = 0.f, s2 = 0.f, s3 = 0.f;
      {
        const float4* a4 = (const float4*)(P.Wih + (size_t)row * 256);
        const float4* x4 = (const float4*)(P.emb + (size_t)tokv * 256);
#pragma unroll 8
        for (int k = 0; k < 64; ++k) {
          float4 a = a4[k], x = x4[k];
          s0 = fmaf(a.x, x.x, s0); s1 = fmaf(a.y, x.y, s1);
          s2 = fmaf(a.z, x.z, s2); s3 = fmaf(a.w, x.w, s3);
        }
      }
      float acc = P.bih[row] + P.bhh[row] + ((s0 + s1) + (s2 + s3));
      acc += stage_dot512(P.dech, (const float4*)(P.Whh + (size_t)row * 512), hs, nb);
      gl[col_l][gate][nb] = acc;
      __syncthreads();
      if (tid < 64) {
        const int cc = tid >> 5, nb2 = tid & 31;
        const int col2 = 2 * w + cc;
        float gi = gl[cc][0][nb2], gf_ = gl[cc][1][nb2];
        float gg = gl[cc][2][nb2], go = gl[cc][3][nb2];
        float cold = cLoad(P.decc + nb2 * 512 + col2);
        float c2 = sig_(gf_) * cold + sig_(gi) * tanhf(gg);
        float hv = sig_(go) * tanhf(c2);
        cStore(P.nh + nb2 * 512 + col2, hv);
        cStore(P.nc + nb2 * 512 + col2, c2);
      }
    }
    fbar(P.arr, P.gf, ++ph);

    // ===== B: m' = nh@At.T + u ; vdWo = nh@W2.T + bvo =====
    if (w < 128) {
      const int p = w >> 6, cb = w & 63;
      const int col_l = tid >> 5, nb = tid & 31;
      const int col = cb * 8 + col_l;
      const float* W = (p ? P.W2 : P.At) + (size_t)col * 512;
      float acc = (p ? P.bvo : P.u)[col];
      acc += stage_dot512(P.nh, (const float4*)W, hs, nb);
      cStore((p ? P.vbuf : P.mbuf) + nb * 512 + col, acc);
    }
    fbar(P.arr, P.gf, ++ph);

    // ===== C: scores / softmax(3) / out1 combine  (WG 0) =====
    if (w == 0) {
      if (tid < 192) {
        const int dotid = tid >> 1, kh = tid & 1;
        const int nb = dotid / 3, l = dotid - nb * 3, b = nb & 7;
        const ull* xa = (const ull*)(P.nh) + nb * 256 + kh * 128;
        const ull* ya = (l < 2)
            ? (const ull*)(P.pvec + l * 4096 + b * 512) + kh * 128
            : (const ull*)(P.mbuf + nb * 512) + kh * 128;
        const float sb0 = (l < 2) ? P.sl0[l * 8 + b] : P.sbb[0];
        float a0 = 0.f, a1 = 0.f;
#pragma unroll 4
        for (int k = 0; k < 128; ++k) {
          float2 x = u2f2(cLoad64(xa + k));
          float2 y = u2f2(cLoad64(ya + k));
          a0 = fmaf(x.x, y.x, a0); a1 = fmaf(x.y, y.y, a1);
        }
        float acc = a0 + a1;
        acc += __shfl_xor(acc, 1);
        if (kh == 0) sl[nb][l] = (acc + sb0) * (1.0f / sqrtf(512.0f));
      }
      __syncthreads();
      if (tid < 32) {
        float a = sl[tid][0], b2 = sl[tid][1], c3 = sl[tid][2];
        float m = fmaxf(a, fmaxf(b2, c3));
        float e0 = expf(a - m), e1 = expf(b2 - m), e2 = expf(c3 - m);
        float inv = 1.0f / (e0 + e1 + e2);
        wsm[tid][0] = e0 * inv; wsm[tid][1] = e1 * inv; wsm[tid][2] = e2 * inv;
      }
      __syncthreads();
      for (int e = tid; e < 16384; e += 256) {
        const int nb = e >> 9, c = e & 511, b = nb & 7;
        float v0 = P.veWo[b * 512 + c];
        float v1 = P.veWo[4096 + b * 512 + c];
        float v2 = cLoad(P.vbuf + nb * 512 + c);
        cStore(P.out1 + e,
               wsm[nb][0] * v0 + wsm[nb][1] * v1 + wsm[nb][2] * v2 + P.bo[c]);
      }
    }
    fbar(P.arr, P.gf, ++ph);

    // ===== E: logits (+bout), bf16 history store, per-WG partial top-4 =====
    {
      const int nb = tid >> 3, cg = tid & 7;
      const int cbase = w * 125;
      float acc[16];
#pragma unroll
      for (int j = 0; j < 16; ++j) acc[j] = 0.0f;
      for (int ck = 0; ck < 2; ++ck) {
        __syncthreads();
        {
          const ull* s8 = (const ull*)P.out1;
          for (int e = tid; e < 4096; e += 256) {
            const int nb2 = e >> 7, k2 = e & 127;
            ull v = cLoad64(s8 + nb2 * 256 + ck * 128 + k2);
            *(ull*)(hs + nb2 * 260 + 2 * k2) = v;
          }
        }
        __syncthreads();
        const float4* h4 = (const float4*)hs + nb * 65;
        const float4* wp[16];
#pragma unroll
        for (int j = 0; j < 16; ++j) {
          int cl2 = cg + 8 * j; if (cl2 > 124) cl2 = 124;
          wp[j] = (const float4*)(P.Wout + (size_t)(cbase + cl2) * 512 + ck * 256);
        }
#pragma unroll 2
        for (int kk = 0; kk < 64; ++kk) {
          float4 x = h4[kk];
          float4 wv[16];
#pragma unroll
          for (int j = 0; j < 16; ++j) wv[j] = wp[j][kk];
#pragma unroll
          for (int j = 0; j < 16; ++j) {
            acc[j] = fmaf(wv[j].x, x.x, acc[j]);
            acc[j] = fmaf(wv[j].y, x.y, acc[j]);
            acc[j] = fmaf(wv[j].z, x.z, acc[j]);
            acc[j] = fmaf(wv[j].w, x.w, acc[j]);
          }
        }
      }
      float v4[4] = {-FLT_MAX, -FLT_MAX, -FLT_MAX, -FLT_MAX};
      int i4[4] = {0x7fffffff, 0x7fffffff, 0x7fffffff, 0x7fffffff};
#pragma unroll
      for (int j = 0; j < 16; ++j) {
        const int cl2 = cg + 8 * j;
        if (cl2 < 125) {
          const int c = cbase + cl2;
          const float v = acc[j] + P.bout[c];
          P.hist[(size_t)t * 1024000 + (size_t)nb * 32000 + c] = __float2bfloat16(v);
          ins4(v4, i4, v, c);
        }
      }
#pragma unroll
      for (int k = 0; k < 4; ++k) { tv[nb][cg][k] = v4[k]; ti_[nb][cg][k] = i4[k]; }
      __syncthreads();
      if (tid < 32) {
        float m4[4] = {-FLT_MAX, -FLT_MAX, -FLT_MAX, -FLT_MAX};
        int mi[4] = {0x7fffffff, 0x7fffffff, 0x7fffffff, 0x7fffffff};
        for (int g2 = 0; g2 < 8; ++g2)
#pragma unroll
          for (int k = 0; k < 4; ++k) ins4(m4, mi, tv[tid][g2][k], ti_[tid][g2][k]);
#pragma unroll
        for (int k = 0; k < 4; ++k) {
          cStore(P.pval + w * 128 + tid * 4 + k, m4[k]);
          cStoreI(P.pidx + w * 128 + tid * 4 + k, mi[k]);
        }
      }
    }
    fbar(P.arr, P.gf, ++ph);

    // ===== F: global top-4/row, beam candidate select, state reorder (WG 0) =====
    if (w == 0) {
      {
        const int r = tid >> 3, ch = tid & 7;
        float m4[4] = {-FLT_MAX, -FLT_MAX, -FLT_MAX, -FLT_MAX};
        int mi[4] = {0x7fffffff, 0x7fffffff, 0x7fffffff, 0x7fffffff};
        for (int wg = ch * 32; wg < ch * 32 + 32; ++wg)
#pragma unroll
          for (int k = 0; k < 4; ++k)
            ins4(m4, mi, cLoad(P.pval + wg * 128 + r * 4 + k),
                 cLoadI(P.pidx + wg * 128 + r * 4 + k));
#pragma unroll
        for (int k = 0; k < 4; ++k) { tv[r][ch][k] = m4[k]; ti_[r][ch][k] = mi[k]; }
      }
      __syncthreads();
      if (tid < 32) {
        float m4[4] = {-FLT_MAX, -FLT_MAX, -FLT_MAX, -FLT_MAX};
        int mi[4] = {0x7fffffff, 0x7fffffff, 0x7fffffff, 0x7fffffff};
        for (int g2 = 0; g2 < 8; ++g2)
#pragma unroll
          for (int k = 0; k < 4; ++k) ins4(m4, mi, tv[tid][g2][k], ti_[tid][g2][k]);
#pragma unroll
        for (int k = 0; k < 4; ++k) { rv[tid][k] = m4[k]; rt[tid][k] = mi[k]; }
      }
      __syncthreads();
      if (tid < 8) {
        const int b2 = tid;
        unsigned used = 0;
#pragma unroll
        for (int sel = 0; sel < 4; ++sel) {
          float bestv = -FLT_MAX; int bestj = -1;
          for (int j = 0; j < 16; ++j) {
            if (used & (1u << j)) continue;
            float vv = rv[(j >> 2) * 8 + b2][j & 3];
            if (vv > bestv) { bestv = vv; bestj = j; }  // tie -> lower j
          }
          used |= 1u << bestj;
          const int obn = bestj >> 2;
          const int tkn = rt[obn * 8 + b2][bestj & 3];
          obl[sel][b2] = obn; tkl[sel][b2] = tkn;
          P.obh[t * 32 + sel * 8 + b2] = obn;
          cStoreI(P.tok + sel * 8 + b2, tkn);
        }
        int tmp[4][13];
        for (int n2 = 0; n2 < 4; ++n2)
          for (int s2 = 0; s2 < 13; ++s2) tmp[n2][s2] = res[obl[n2][b2]][s2][b2];
        for (int n2 = 0; n2 < 4; ++n2)
          for (int s2 = 0; s2 < 13; ++s2) res[n2][s2][b2] = tmp[n2][s2];
        for (int n2 = 0; n2 < 4; ++n2) res[n2][t + 1][b2] = tkl[n2][b2];
      }
      __syncthreads();
      if (t < 11) {
        for (int e = tid; e < 16384; e += 256) {
          const int n2 = e >> 12, b3 = (e >> 9) & 7, c3 = e & 511;
          const int obn = obl[n2][b3];
          cStore(P.dech + e, cLoad(P.nh + (size_t)(obn * 8 + b3) * 512 + c3));
          cStore(P.decc + e, cLoad(P.nc + (size_t)(obn * 8 + b3) * 512 + c3));
        }
      } else if (tid < 104) {
        P.res0[tid] = res[0][tid >> 3][tid & 7];  // res0[s][b]
      }
    }
    fbar(P.arr, P.gf, ++ph);
  }
}

// ---------------------------------------------------------------------------
// Output assembly: WG = (b, v-block of 1000). Backtrace beam-0 path, stage
// [13][1000] in LDS, write fully-coalesced 13000-float runs.
// ---------------------------------------------------------------------------
__global__ __launch_bounds__(256) void out_kernel(const __hip_bfloat16* hist,
                                                  const int* obh, const int* res0,
                                                  float* out) {
  __shared__ float sh[13 * 1000];
  __shared__ int sbArr[12];
  const int w = blockIdx.x, tid = threadIdx.x;
  const int b = w >> 5, v0 = (w & 31) * 1000;
  if (tid == 0) {
    int beta = 0;
    for (int t = 11; t >= 0; --t) {
      const int sb = obh[t * 32 + beta * 8 + b];
      sbArr[t] = sb;
      beta = sb;
    }
  }
  __syncthreads();
  for (int e = tid; e < 12000; e += 256) {
    const int t = e / 1000, vv = e - t * 1000;
    sh[(t + 1) * 1000 + vv] = __bfloat162float(
        hist[(size_t)(t * 32 + sbArr[t] * 8 + b) * 32000 + v0 + vv]);
  }
  for (int e = tid; e < 1000; e += 256) sh[e] = (v0 + e == 1) ? 1.0f : 0.0f;
  __syncthreads();
  float* base = out + 104 + (size_t)(b * 32000 + v0) * 13;
  for (int o = tid; o < 13000; o += 256) {
    const int v = o / 13, t = o - v * 13;
    base[o] = sh[t * 1000 + v];
  }
  if (w == 0 && tid < 104) {
    out[(tid & 7) * 13 + (tid >> 3)] = (float)res0[tid];
  }
}

// ---------------------------------------------------------------------------
extern "C" void kernel_launch(void* const* d_in, const int* in_sizes, int n_in,
                              void* d_out, int out_size, void* d_ws, size_t ws_size,
                              hipStream_t stream) {
  const int* text  = (const int*)d_in[0];
  const float* embE = (const float*)d_in[1];
  const float* embD = (const float*)d_in[2];
  const float* Wih0 = (const float*)d_in[3];
  const float* Whh0 = (const float*)d_in[4];
  const float* bih0 = (const float*)d_in[5];
  const float* bhh0 = (const float*)d_in[6];
  const float* Wih1 = (const float*)d_in[7];
  const float* Whh1 = (const float*)d_in[8];
  const float* bih1 = (const float*)d_in[9];
  const float* bhh1 = (const float*)d_in[10];
  const float* dWih = (const float*)d_in[11];
  const float* dWhh = (const float*)d_in[12];
  const float* dbih = (const float*)d_in[13];
  const float* dbhh = (const float*)d_in[14];
  const float* Wq = (const float*)d_in[15];
  const float* bq = (const float*)d_in[16];
  const float* Wk = (const float*)d_in[17];
  const float* bk = (const float*)d_in[18];
  const float* Wv = (const float*)d_in[19];
  const float* bv = (const float*)d_in[20];
  const float* Wo = (const float*)d_in[21];
  const float* bo = (const float*)d_in[22];
  const float* Wout = (const float*)d_in[23];
  const float* bout = (const float*)d_in[24];

  char* ws = (char*)d_ws;
  size_t off = 0;
  auto alloc = [&](size_t bytes) -> char* {
    off = (off + 511) & ~(size_t)511;
    char* p = ws + off;
    off += bytes;
    return p;
  };
  int* arrE  = (int*)alloc(8192 * 4);
  int* gfE   = (int*)alloc(32 * 4);
  int* arrD  = (int*)alloc(8192 * 4);
  int* gfD   = (int*)alloc(32 * 4);
  float* h0buf = (float*)alloc(2 * 4096 * 4);
  float* h1buf = (float*)alloc(2 * 4096 * 4);
  float* h0f  = (float*)alloc(4096 * 4);
  float* h1f  = (float*)alloc(4096 * 4);
  float* c1f  = (float*)alloc(4096 * 4);
  float* kenc = (float*)alloc(8192 * 4);
  float* venc = (float*)alloc(8192 * 4);
  float* At   = (float*)alloc((size_t)262144 * 4);
  float* W2   = (float*)alloc((size_t)262144 * 4);
  float* u    = (float*)alloc(512 * 4);
  float* pvec = (float*)alloc(8192 * 4);
  float* veWo = (float*)alloc(8192 * 4);
  float* bvo  = (float*)alloc(512 * 4);
  float* sl0  = (float*)alloc(16 * 4);
  float* sbb  = (float*)alloc(32 * 4);
  float* dech = (float*)alloc(16384 * 4);
  float* decc = (float*)alloc(16384 * 4);
  float* nh   = (float*)alloc(16384 * 4);
  float* nc   = (float*)alloc(16384 * 4);
  float* mbuf = (float*)alloc(16384 * 4);
  float* vbuf = (float*)alloc(16384 * 4);
  float* out1 = (float*)alloc(16384 * 4);
  int* tok    = (int*)alloc(32 * 4);
  float* pval = (float*)alloc(32768 * 4);
  int* pidx   = (int*)alloc(32768 * 4);
  int* obh    = (int*)alloc(384 * 4);
  int* res0   = (int*)alloc(104 * 4);
  __hip_bfloat16* hist = (__hip_bfloat16*)alloc((size_t)12288000 * 2);
  if (off > ws_size) return;  // ~28 MB required

  init_kernel<<<32, 256, 0, stream>>>(h0buf, h1buf, arrE, gfE, arrD, gfD);

  EncP ep{text, embE, Wih0, Whh0, bih0, bhh0, Wih1, Whh1, bih1, bhh1,
          h0buf, h1buf, h0f, h1f, c1f, arrE, gfE};
  enc_kernel<<<256, 256, 0, stream>>>(ep);

  prep_kernel<<<128, 256, 0, stream>>>(Wk, bk, Wv, bv, h0f, h1f, c1f, kenc, venc,
                                       dech, decc, tok);
  prep2_kernel<<<256, 256, 0, stream>>>(Wq, Wk, Wv, Wo, bq, bk, bv, kenc, venc,
                                        At, W2, u, pvec, veWo, bvo, sl0, sbb);

  DecP dp{embD, dWih, dWhh, dbih, dbhh, bo, Wout, bout,
          At, W2, u, bvo, pvec, sl0, sbb, veWo,
          dech, decc, nh, nc, mbuf, vbuf, out1, tok,
          pval, pidx, obh, res0, hist, arrD, gfD};
  dec_kernel<<<256, 256, 0, stream>>>(dp);

  out_kernel<<<256, 256, 0, stream>>>(hist, obh, res0, (float*)d_out);
}

// Round 4
// 9692.586 us; speedup vs baseline: 1.4458x; 1.0553x over previous
//
#include <hip/hip_runtime.h>
#include <hip/hip_bf16.h>
#include <float.h>

// ---------------------------------------------------------------------------
// Beam-search seq2seq (2-layer LSTM encoder S=512, 4-beam decoder MAXLEN=12,
// V=32000). fp32 math; bf16 only for stored logits history.
//
// Grid barrier = epoch barrier with ONE poller per WG (round-3 post-mortem:
// all-lane polling congests the LLC line and costs ~8-10us/barrier).
// WG0's 256 threads poll the 256 per-WG arrival lines (one each), then
// thread 0 publishes a broadcast line; thread 0 of every other WG polls it.
// __syncthreads() before arrival drains vmcnt -> data stores are at the
// coherence point (LLC) before the flag store issues.
// ---------------------------------------------------------------------------

using ull = unsigned long long;

#define SCOPE_AGENT __HIP_MEMORY_SCOPE_AGENT

__device__ __forceinline__ float cLoad(const float* p) {
  return __hip_atomic_load(p, __ATOMIC_RELAXED, SCOPE_AGENT);
}
__device__ __forceinline__ void cStore(float* p, float v) {
  __hip_atomic_store(p, v, __ATOMIC_RELAXED, SCOPE_AGENT);
}
__device__ __forceinline__ int cLoadI(const int* p) {
  return __hip_atomic_load(p, __ATOMIC_RELAXED, SCOPE_AGENT);
}
__device__ __forceinline__ void cStoreI(int* p, int v) {
  __hip_atomic_store(p, v, __ATOMIC_RELAXED, SCOPE_AGENT);
}
__device__ __forceinline__ ull cLoad64(const ull* p) {
  return __hip_atomic_load(p, __ATOMIC_RELAXED, SCOPE_AGENT);
}

__device__ __forceinline__ float2 u2f2(ull u) {
  union { ull u; float2 f; } c; c.u = u; return c.f;
}

// Epoch barrier, 256 WGs. arr = 256 lines (stride 32 ints), gf = 1 line.
__device__ __forceinline__ void fbar(int* arr, int* gf, int phase) {
  __syncthreads();  // drain vmcnt: all coherent data stores at LLC
  if (threadIdx.x == 0) cStoreI(arr + blockIdx.x * 32, phase);
  if (blockIdx.x == 0) {
    const int* f = arr + threadIdx.x * 32;   // thread t waits for WG t
    while (cLoadI(f) < phase) __builtin_amdgcn_s_sleep(2);
    __syncthreads();
    if (threadIdx.x == 0) cStoreI(gf, phase);
  } else {
    if (threadIdx.x == 0) {
      while (cLoadI(gf) < phase) __builtin_amdgcn_s_sleep(2);
    }
    __syncthreads();
  }
}

__device__ __forceinline__ float sig_(float x) { return 1.0f / (1.0f + expf(-x)); }

// top-4 sorted insert; ordering matches lax.top_k (desc value, tie -> lower idx)
__device__ __forceinline__ void ins4(float* v, int* id, float nv, int ni) {
  if (nv > v[3] || (nv == v[3] && ni < id[3])) {
    v[3] = nv; id[3] = ni;
#pragma unroll
    for (int p = 3; p > 0; --p) {
      bool sw = (v[p] > v[p - 1]) || (v[p] == v[p - 1] && id[p] < id[p - 1]);
      if (sw) {
        float t0 = v[p]; v[p] = v[p - 1]; v[p - 1] = t0;
        int t1 = id[p]; id[p] = id[p - 1]; id[p - 1] = t1;
      }
    }
  }
}

// ---------------------------------------------------------------------------
// init: zero h double-buffers + barrier arrival/broadcast lines
// ---------------------------------------------------------------------------
__global__ __launch_bounds__(256) void init_kernel(float* h0buf, float* h1buf,
                                                   int* arrE, int* gfE,
                                                   int* arrD, int* gfD) {
  int g = blockIdx.x * 256 + threadIdx.x;
  if (g < 8192) {
    h0buf[g] = 0.0f; h1buf[g] = 0.0f;
    arrE[g] = 0; arrD[g] = 0;
  }
  if (g < 32) { gfE[g] = 0; gfD[g] = 0; }
}

// ---------------------------------------------------------------------------
// Encoder: 256 WGs x 256 thr. WGs 0..127 = layer0, 128..255 = layer1 (skewed
// by one step). WG owns 4 h-cols; thread = (kh8, col4, b8).
// ---------------------------------------------------------------------------
struct EncP {
  const int* text; const float* emb;
  const float* Wih0; const float* Whh0; const float* bih0; const float* bhh0;
  const float* Wih1; const float* Whh1; const float* bih1; const float* bhh1;
  float* h0buf; float* h1buf; float* h0f; float* h1f; float* c1f;
  int* arr; int* gf;
};

template <int KX>
__device__ void enc_run(const EncP& P, float* xcat, int w, int tid) {
  constexpr int KTOT = KX + 512;
  constexpr int ST = KTOT + 4;       // float stride per batch (ST%32==4)
  constexpr int KSL = KTOT / 8;      // k-floats per kh slice (96 / 128)
  constexpr int Q = KSL / 4;         // f4 per slice (24 / 32)
  constexpr int L = (KX == 512) ? 1 : 0;
  __shared__ float part[16 * 8 * 8]; // [r16][b8][kh8]
  __shared__ float gl[128];          // [r16][b8]

  const int c0 = (w & 127) * 4;
  const int kh = tid >> 5, col = (tid >> 3) & 3, b = tid & 7;
  const int kbase = kh * KSL;

  const float* Wih = L ? P.Wih1 : P.Wih0;
  const float* Whh = L ? P.Whh1 : P.Whh0;

  const float4* wih4[4]; const float4* whh4[4];
#pragma unroll
  for (int g = 0; g < 4; ++g) {
    const int row = g * 512 + c0 + col;
    wih4[g] = (const float4*)(Wih + (size_t)row * KX);
    whh4[g] = (const float4*)(Whh + (size_t)row * 512);
  }
  float bsum = 0.f;
  if (tid < 128) {
    const int r = tid >> 3;
    const int row = (r & 3) * 512 + c0 + (r >> 2);
    bsum = (L ? P.bih1[row] + P.bhh1[row] : P.bih0[row] + P.bhh0[row]);
  }
  float creg = 0.f;  // cell state, threads tid<32
  float* myH = L ? P.h1buf : P.h0buf;

  int qx = (KX - kbase) / 4;
  qx = qx < 0 ? 0 : (qx > Q ? Q : qx);

  for (int i = 0; i <= 512; ++i) {
    const bool act = L ? (i >= 1) : (i < 512);
    if (act) {
      const int t = L ? (i - 1) : i;
      // ---- stage [x ; h] per batch into xcat ----
      if constexpr (KX == 256) {
        for (int e = tid; e < 1024; e += 256) {
          const int b2 = e >> 7, k2 = e & 127;
          const int tokv = P.text[t * 8 + b2];
          float2 v = *(const float2*)(P.emb + (size_t)tokv * 256 + 2 * k2);
          *(float2*)(xcat + b2 * ST + 2 * k2) = v;
        }
      } else {
        const ull* x0 = (const ull*)(P.h0buf + ((i + 1) & 1) * 4096);
        for (int e = tid; e < 2048; e += 256) {
          const int b2 = e >> 8, k2 = e & 255;
          ull u = cLoad64(x0 + b2 * 256 + k2);
          *(ull*)(xcat + b2 * ST + 2 * k2) = u;
        }
      }
      {
        const float* hp = L ? (P.h1buf + (i & 1) * 4096)
                            : (P.h0buf + ((i + 1) & 1) * 4096);
        const ull* hq = (const ull*)hp;
        for (int e = tid; e < 2048; e += 256) {
          const int b2 = e >> 8, k2 = e & 255;
          ull u = cLoad64(hq + b2 * 256 + k2);
          *(ull*)(xcat + b2 * ST + KX + 2 * k2) = u;
        }
      }
      __syncthreads();
      // ---- 4-gate dot over this thread's k-slice ----
      float a0 = 0.f, a1 = 0.f, a2 = 0.f, a3 = 0.f;
      const float4* xq = (const float4*)(xcat + b * ST + kbase);
      const int iw = kbase >> 2, ih = (kbase - KX) >> 2;
#pragma unroll 4
      for (int q = 0; q < qx; ++q) {
        float4 x = xq[q];
        float4 w0 = wih4[0][iw + q], w1 = wih4[1][iw + q];
        float4 w2 = wih4[2][iw + q], w3 = wih4[3][iw + q];
        a0 = fmaf(w0.x, x.x, a0); a0 = fmaf(w0.y, x.y, a0);
        a0 = fmaf(w0.z, x.z, a0); a0 = fmaf(w0.w, x.w, a0);
        a1 = fmaf(w1.x, x.x, a1); a1 = fmaf(w1.y, x.y, a1);
        a1 = fmaf(w1.z, x.z, a1); a1 = fmaf(w1.w, x.w, a1);
        a2 = fmaf(w2.x, x.x, a2); a2 = fmaf(w2.y, x.y, a2);
        a2 = fmaf(w2.z, x.z, a2); a2 = fmaf(w2.w, x.w, a2);
        a3 = fmaf(w3.x, x.x, a3); a3 = fmaf(w3.y, x.y, a3);
        a3 = fmaf(w3.z, x.z, a3); a3 = fmaf(w3.w, x.w, a3);
      }
#pragma unroll 4
      for (int q = qx; q < Q; ++q) {
        float4 x = xq[q];
        float4 w0 = whh4[0][ih + q], w1 = whh4[1][ih + q];
        float4 w2 = whh4[2][ih + q], w3 = whh4[3][ih + q];
        a0 = fmaf(w0.x, x.x, a0); a0 = fmaf(w0.y, x.y, a0);
        a0 = fmaf(w0.z, x.z, a0); a0 = fmaf(w0.w, x.w, a0);
        a1 = fmaf(w1.x, x.x, a1); a1 = fmaf(w1.y, x.y, a1);
        a1 = fmaf(w1.z, x.z, a1); a1 = fmaf(w1.w, x.w, a1);
        a2 = fmaf(w2.x, x.x, a2); a2 = fmaf(w2.y, x.y, a2);
        a2 = fmaf(w2.z, x.z, a2); a2 = fmaf(w2.w, x.w, a2);
        a3 = fmaf(w3.x, x.x, a3); a3 = fmaf(w3.y, x.y, a3);
        a3 = fmaf(w3.z, x.z, a3); a3 = fmaf(w3.w, x.w, a3);
      }
      part[((col * 4 + 0) * 8 + b) * 8 + kh] = a0;
      part[((col * 4 + 1) * 8 + b) * 8 + kh] = a1;
      part[((col * 4 + 2) * 8 + b) * 8 + kh] = a2;
      part[((col * 4 + 3) * 8 + b) * 8 + kh] = a3;
      __syncthreads();
      if (tid < 128) {
        const int r = tid >> 3, b2 = tid & 7;
        const float4* pp = (const float4*)(part + (r * 8 + b2) * 8);
        float4 p0 = pp[0], p1 = pp[1];
        gl[r * 8 + b2] =
            bsum + (((p0.x + p0.y) + (p0.z + p0.w)) + ((p1.x + p1.y) + (p1.z + p1.w)));
      }
      __syncthreads();
      if (tid < 32) {
        const int cc = tid >> 3, b2 = tid & 7;
        float gi = gl[(cc * 4 + 0) * 8 + b2], gf_ = gl[(cc * 4 + 1) * 8 + b2];
        float gg = gl[(cc * 4 + 2) * 8 + b2], go = gl[(cc * 4 + 3) * 8 + b2];
        float c2 = sig_(gf_) * creg + sig_(gi) * tanhf(gg);
        float hv = sig_(go) * tanhf(c2);
        creg = c2;
        cStore(myH + (t & 1) * 4096 + b2 * 512 + c0 + cc, hv);
        if (t == 511) {
          (L ? P.h1f : P.h0f)[b2 * 512 + c0 + cc] = hv;
          if (L) P.c1f[b2 * 512 + c0 + cc] = c2;
        }
      }
    }
    if (i < 512) fbar(P.arr, P.gf, i + 1);
  }
}

__global__ __launch_bounds__(256, 1) void enc_kernel(EncP P) {
  __shared__ float xcat0[8 * 772];
  __shared__ float xcat1[8 * 1028];
  if (blockIdx.x >> 7) enc_run<512>(P, xcat1, blockIdx.x, threadIdx.x);
  else enc_run<256>(P, xcat0, blockIdx.x, threadIdx.x);
}

// ---------------------------------------------------------------------------
// prep: k_enc/v_enc projections of [h0f;h1f], decoder state init
// ---------------------------------------------------------------------------
__global__ __launch_bounds__(256) void prep_kernel(
    const float* Wk, const float* bk, const float* Wv, const float* bv,
    const float* h0f, const float* h1f, const float* c1f,
    float* kenc, float* venc, float* nhb, float* ncb, int* tok, int* obuf) {
  const int w = blockIdx.x, tid = threadIdx.x;
  if (w < 64) {
    const int o = w * 256 + tid;                  // [kv][l][b][c]
    const int kv = o >> 13, l = (o >> 12) & 1, b = (o >> 9) & 7, c = o & 511;
    const float4* h4 = (const float4*)((l ? h1f : h0f) + b * 512);
    const float4* w4 = (const float4*)((kv ? Wv : Wk) + (size_t)c * 512);
    float s0 = 0.f, s1 = 0.f, s2 = 0.f, s3 = 0.f;
#pragma unroll 8
    for (int k = 0; k < 128; ++k) {
      float4 a = w4[k], x = h4[k];
      s0 = fmaf(a.x, x.x, s0); s1 = fmaf(a.y, x.y, s1);
      s2 = fmaf(a.z, x.z, s2); s3 = fmaf(a.w, x.w, s3);
    }
    (kv ? venc : kenc)[l * 4096 + b * 512 + c] =
        (kv ? bv : bk)[c] + ((s0 + s1) + (s2 + s3));
  } else {
    const int o = (w - 64) * 256 + tid;           // [n][b][c] broadcast over n
    nhb[16384 + o] = h1f[o & 4095];               // slot 1 = "prev" at t=0
    ncb[16384 + o] = c1f[o & 4095];
    if (o < 32) { tok[o] = 1; obuf[o] = o >> 3; } // SOS, identity beams
  }
}

// ---------------------------------------------------------------------------
// prep2: one-time attention algebra folds (unchanged from R3).
// ---------------------------------------------------------------------------
__global__ __launch_bounds__(256) void prep2_kernel(
    const float* Wq, const float* Wk, const float* Wv, const float* Wo,
    const float* bq, const float* bk, const float* bv,
    const float* kenc, const float* venc,
    float* At, float* W2, float* u, float* pvec, float* veWo, float* bvo,
    float* sl0, float* sbb) {
  const int w = blockIdx.x, tid = threadIdx.x;
#pragma unroll 1
  for (int sub = 0; sub < 2; ++sub) {
    const int d = 2 * w + sub;
    for (int cc = 0; cc < 2; ++cc) {
      const int c = tid + cc * 256;
      float s0 = 0.f, s1 = 0.f, s2 = 0.f, s3 = 0.f;
      for (int i = 0; i < 512; i += 4) {
        s0 = fmaf(Wk[(i + 0) * 512 + d], Wq[(i + 0) * 512 + c], s0);
        s1 = fmaf(Wk[(i + 1) * 512 + d], Wq[(i + 1) * 512 + c], s1);
        s2 = fmaf(Wk[(i + 2) * 512 + d], Wq[(i + 2) * 512 + c], s2);
        s3 = fmaf(Wk[(i + 3) * 512 + d], Wq[(i + 3) * 512 + c], s3);
      }
      At[(size_t)d * 512 + c] = (s0 + s1) + (s2 + s3);
    }
    for (int cc = 0; cc < 2; ++cc) {
      const int dc = tid + cc * 256;
      float s0 = 0.f, s1 = 0.f, s2 = 0.f, s3 = 0.f;
      const float* wor = Wo + (size_t)d * 512;
      for (int c2 = 0; c2 < 512; c2 += 4) {
        s0 = fmaf(wor[c2 + 0], Wv[(size_t)(c2 + 0) * 512 + dc], s0);
        s1 = fmaf(wor[c2 + 1], Wv[(size_t)(c2 + 1) * 512 + dc], s1);
        s2 = fmaf(wor[c2 + 2], Wv[(size_t)(c2 + 2) * 512 + dc], s2);
        s3 = fmaf(wor[c2 + 3], Wv[(size_t)(c2 + 3) * 512 + dc], s3);
      }
      W2[(size_t)d * 512 + dc] = (s0 + s1) + (s2 + s3);
    }
  }
  if (w == 0) {
    for (int cc = 0; cc < 2; ++cc) {
      const int c = tid + cc * 256;
      float a = 0.f;
      for (int i = 0; i < 512; ++i)
        a += Wq[i * 512 + c] * bk[i] + Wk[i * 512 + c] * bq[i];
      u[c] = a;
    }
  } else if (w <= 32) {
    const int idx = (w - 1) * 256 + tid;          // 8192 = [l][b][c]
    const int l = idx >> 12, b = (idx >> 9) & 7, c = idx & 511;
    const float* ke = kenc + l * 4096 + b * 512;
    float a = 0.f;
    for (int i = 0; i < 512; ++i) a = fmaf(Wq[i * 512 + c], ke[i], a);
    pvec[idx] = a;
  } else if (w <= 64) {
    const int idx = (w - 33) * 256 + tid;         // 8192 = [l][b][j]
    const int l = idx >> 12, b = (idx >> 9) & 7, j = idx & 511;
    const float* ve = venc + l * 4096 + b * 512;
    const float* wo = Wo + (size_t)j * 512;
    float a = 0.f;
    for (int c = 0; c < 512; ++c) a = fmaf(wo[c], ve[c], a);
    veWo[idx] = a;
  } else if (w == 65) {
    for (int cc = 0; cc < 2; ++cc) {
      const int j = tid + cc * 256;
      const float* wo = Wo + (size_t)j * 512;
      float a = 0.f;
      for (int c = 0; c < 512; ++c) a = fmaf(wo[c], bv[c], a);
      bvo[j] = a;
    }
  } else if (w == 66) {
    if (tid < 16) {
      const int l = tid >> 3, b = tid & 7;
      const float* ke = kenc + l * 4096 + b * 512;
      float a = 0.f;
      for (int i = 0; i < 512; ++i) a = fmaf(bq[i], ke[i], a);
      sl0[tid] = a;
    } else if (tid == 16) {
      float a = 0.f;
      for (int i = 0; i < 512; ++i) a = fmaf(bq[i], bk[i], a);
      sbb[0] = a;
    }
  }
}

// ---------------------------------------------------------------------------
// Decoder: 256 WGs x 256 thr, 12 steps x 5 barrier phases.
// nh/nc double-buffered; beam reorder done by gather in phase A (F publishes
// only obl[32] + tok[32]).
// ---------------------------------------------------------------------------
struct DecP {
  const float* emb;
  const float* Wih; const float* Whh; const float* bih; const float* bhh;
  const float* bo; const float* Wout; const float* bout;
  const float* At; const float* W2; const float* u; const float* bvo;
  const float* pvec; const float* sl0; const float* sbb; const float* veWo;
  float* nhb; float* ncb;  // [2][32][512]
  float* mbuf;   // [32][512]
  float* vbuf;   // [32][512]
  float* out1;   // [32][512]
  int* tok;      // [32]
  int* obuf;     // [32]
  float* pval; int* pidx;  // [256][32][4]
  int* obh;      // [12][4][8]
  int* res0;     // [13][8]
  __hip_bfloat16* hist;    // [12][32][32000]
  int* arr; int* gf;
};

// stage [32][512] coherent source into LDS (2 chunks, 8B loads) and dot with
// one weight row; all 256 threads of a WG must call uniformly.
__device__ float stage_dot512(const float* src, const float4* w4row, float* hs,
                              int nb) {
  const int tid = threadIdx.x;
  float s0 = 0.f, s1 = 0.f, s2 = 0.f, s3 = 0.f;
  for (int ck = 0; ck < 2; ++ck) {
    __syncthreads();
    const ull* s8 = (const ull*)src;
    for (int e = tid; e < 4096; e += 256) {
      const int nb2 = e >> 7, k2 = e & 127;
      ull v = cLoad64(s8 + nb2 * 256 + ck * 128 + k2);
      *(ull*)(hs + nb2 * 260 + 2 * k2) = v;
    }
    __syncthreads();
    const float4* h4 = (const float4*)hs + nb * 65;
    const float4* w4 = w4row + ck * 64;
#pragma unroll 8
    for (int k = 0; k < 64; ++k) {
      float4 a = w4[k], x = h4[k];
      s0 = fmaf(a.x, x.x, s0); s1 = fmaf(a.y, x.y, s1);
      s2 = fmaf(a.z, x.z, s2); s3 = fmaf(a.w, x.w, s3);
    }
  }
  return (s0 + s1) + (s2 + s3);
}

__global__ __launch_bounds__(256, 1) void dec_kernel(DecP P) {
  __shared__ float hs[32 * 260];
  __shared__ float gl[2][4][32];
  __shared__ float sl[32][3];
  __shared__ float wsm[32][3];
  __shared__ float tv[32][8][4];
  __shared__ int ti_[32][8][4];
  __shared__ float rv[32][4];
  __shared__ int rt[32][4];
  __shared__ int res[4][13][8];
  __shared__ int obl[4][8];
  __shared__ int tkl[4][8];
  __shared__ int oblS[32];
  __shared__ int tokS[32];

  const int w = blockIdx.x, tid = threadIdx.x;
  int ph = 0;

  if (tid < 104) {  // res init: all SOS (only WG0's copy is used)
    for (int n = 0; n < 4; ++n) res[n][tid >> 3][tid & 7] = 1;
  }

  for (int t = 0; t < 12; ++t) {
    const int curOff = (t & 1) * 16384, prevOff = ((t + 1) & 1) * 16384;
    // ===== A: LSTM gates + cell; h/c gathered by backpointer =====
    {
      const int col_l = tid >> 7, gate = (tid >> 5) & 3, nb = tid & 31;
      const int col = 2 * w + col_l;
      const int row = gate * 512 + col;
      if (tid < 32) {
        oblS[tid] = cLoadI(P.obuf + tid);
        tokS[tid] = cLoadI(P.tok + tid);
      }
      __syncthreads();
      // stage emb rows [32][256] (f4, pad stride 65 f4)
      for (int e = tid; e < 2048; e += 256) {
        const int nb2 = e >> 6, kf = e & 63;
        float4 v = *((const float4*)(P.emb + (size_t)tokS[nb2] * 256) + kf);
        *((float4*)hs + nb2 * 65 + kf) = v;
      }
      __syncthreads();
      float s0 = 0.f, s1 = 0.f, s2 = 0.f, s3 = 0.f;
      {
        const float4* a4 = (const float4*)(P.Wih + (size_t)row * 256);
        const float4* x4 = (const float4*)hs + nb * 65;
#pragma unroll 8
        for (int k = 0; k < 64; ++k) {
          float4 a = a4[k], x = x4[k];
          s0 = fmaf(a.x, x.x, s0); s1 = fmaf(a.y, x.y, s1);
          s2 = fmaf(a.z, x.z, s2); s3 = fmaf(a.w, x.w, s3);
        }
      }
      float acc = P.bih[row] + P.bhh[row];
      // gathered h, 2 chunks
      const ull* hsrc = (const ull*)(P.nhb + prevOff);
      const float4* w4row = (const float4*)(P.Whh + (size_t)row * 512);
      for (int ck = 0; ck < 2; ++ck) {
        __syncthreads();
        for (int e = tid; e < 4096; e += 256) {
          const int nb2 = e >> 7, k2 = e & 127;
          const int srow = oblS[nb2] * 8 + (nb2 & 7);
          ull v = cLoad64(hsrc + srow * 256 + ck * 128 + k2);
          *(ull*)(hs + nb2 * 260 + 2 * k2) = v;
        }
        __syncthreads();
        const float4* h4 = (const float4*)hs + nb * 65;
        const float4* w4 = w4row + ck * 64;
#pragma unroll 8
        for (int k = 0; k < 64; ++k) {
          float4 a = w4[k], x = h4[k];
          s0 = fmaf(a.x, x.x, s0); s1 = fmaf(a.y, x.y, s1);
          s2 = fmaf(a.z, x.z, s2); s3 = fmaf(a.w, x.w, s3);
        }
      }
      acc += (s0 + s1) + (s2 + s3);
      gl[col_l][gate][nb] = acc;
      __syncthreads();
      if (tid < 64) {
        const int cc = tid >> 5, nb2 = tid & 31;
        const int col2 = 2 * w + cc;
        float gi = gl[cc][0][nb2], gf_ = gl[cc][1][nb2];
        float gg = gl[cc][2][nb2], go = gl[cc][3][nb2];
        const int srow = oblS[nb2] * 8 + (nb2 & 7);
        float cold = cLoad(P.ncb + prevOff + srow * 512 + col2);
        float c2 = sig_(gf_) * cold + sig_(gi) * tanhf(gg);
        float hv = sig_(go) * tanhf(c2);
        cStore(P.nhb + curOff + nb2 * 512 + col2, hv);
        cStore(P.ncb + curOff + nb2 * 512 + col2, c2);
      }
    }
    fbar(P.arr, P.gf, ++ph);

    // ===== B: m' = nh@At.T + u ; vdWo = nh@W2.T + bvo =====
    if (w < 128) {
      const int p = w >> 6, cb = w & 63;
      const int col_l = tid >> 5, nb = tid & 31;
      const int col = cb * 8 + col_l;
      const float* W = (p ? P.W2 : P.At) + (size_t)col * 512;
      float acc = (p ? P.bvo : P.u)[col];
      acc += stage_dot512(P.nhb + curOff, (const float4*)W, hs, nb);
      cStore((p ? P.vbuf : P.mbuf) + nb * 512 + col, acc);
    }
    fbar(P.arr, P.gf, ++ph);

    // ===== C: scores / softmax(3) / out1 combine  (WG 0) =====
    if (w == 0) {
      if (tid < 192) {
        const int dotid = tid >> 1, kh = tid & 1;
        const int nb = dotid / 3, l = dotid - nb * 3, b = nb & 7;
        const ull* xa = (const ull*)(P.nhb + curOff) + nb * 256 + kh * 128;
        const ull* ya = (l < 2)
            ? (const ull*)(P.pvec + l * 4096 + b * 512) + kh * 128
            : (const ull*)(P.mbuf + nb * 512) + kh * 128;
        const float sb0 = (l < 2) ? P.sl0[l * 8 + b] : P.sbb[0];
        float a0 = 0.f, a1 = 0.f;
#pragma unroll 4
        for (int k = 0; k < 128; ++k) {
          float2 x = u2f2(cLoad64(xa + k));
          float2 y = u2f2(cLoad64(ya + k));
          a0 = fmaf(x.x, y.x, a0); a1 = fmaf(x.y, y.y, a1);
        }
        float acc = a0 + a1;
        acc += __shfl_xor(acc, 1);
        if (kh == 0) sl[nb][l] = (acc + sb0) * (1.0f / sqrtf(512.0f));
      }
      __syncthreads();
      if (tid < 32) {
        float a = sl[tid][0], b2 = sl[tid][1], c3 = sl[tid][2];
        float m = fmaxf(a, fmaxf(b2, c3));
        float e0 = expf(a - m), e1 = expf(b2 - m), e2 = expf(c3 - m);
        float inv = 1.0f / (e0 + e1 + e2);
        wsm[tid][0] = e0 * inv; wsm[tid][1] = e1 * inv; wsm[tid][2] = e2 * inv;
      }
      __syncthreads();
      for (int e = tid; e < 16384; e += 256) {
        const int nb = e >> 9, c = e & 511, b = nb & 7;
        float v0 = P.veWo[b * 512 + c];
        float v1 = P.veWo[4096 + b * 512 + c];
        float v2 = cLoad(P.vbuf + nb * 512 + c);
        cStore(P.out1 + e,
               wsm[nb][0] * v0 + wsm[nb][1] * v1 + wsm[nb][2] * v2 + P.bo[c]);
      }
    }
    fbar(P.arr, P.gf, ++ph);

    // ===== E: logits (+bout), bf16 history store, per-WG partial top-4 =====
    {
      const int nb = tid >> 3, cg = tid & 7;
      const int cbase = w * 125;
      float acc[16];
#pragma unroll
      for (int j = 0; j < 16; ++j) acc[j] = 0.0f;
      for (int ck = 0; ck < 2; ++ck) {
        __syncthreads();
        {
          const ull* s8 = (const ull*)P.out1;
          for (int e = tid; e < 4096; e += 256) {
            const int nb2 = e >> 7, k2 = e & 127;
            ull v = cLoad64(s8 + nb2 * 256 + ck * 128 + k2);
            *(ull*)(hs + nb2 * 260 + 2 * k2) = v;
          }
        }
        __syncthreads();
        const float4* h4 = (const float4*)hs + nb * 65;
        const float4* wp[16];
#pragma unroll
        for (int j = 0; j < 16; ++j) {
          int cl2 = cg + 8 * j; if (cl2 > 124) cl2 = 124;
          wp[j] = (const float4*)(P.Wout + (size_t)(cbase + cl2) * 512 + ck * 256);
        }
#pragma unroll 2
        for (int kk = 0; kk < 64; ++kk) {
          float4 x = h4[kk];
          float4 wv[16];
#pragma unroll
          for (int j = 0; j < 16; ++j) wv[j] = wp[j][kk];
#pragma unroll
          for (int j = 0; j < 16; ++j) {
            acc[j] = fmaf(wv[j].x, x.x, acc[j]);
            acc[j] = fmaf(wv[j].y, x.y, acc[j]);
            acc[j] = fmaf(wv[j].z, x.z, acc[j]);
            acc[j] = fmaf(wv[j].w, x.w, acc[j]);
          }
        }
      }
      float v4[4] = {-FLT_MAX, -FLT_MAX, -FLT_MAX, -FLT_MAX};
      int i4[4] = {0x7fffffff, 0x7fffffff, 0x7fffffff, 0x7fffffff};
#pragma unroll
      for (int j = 0; j < 16; ++j) {
        const int cl2 = cg + 8 * j;
        if (cl2 < 125) {
          const int c = cbase + cl2;
          const float v = acc[j] + P.bout[c];
          P.hist[(size_t)t * 1024000 + (size_t)nb * 32000 + c] = __float2bfloat16(v);
          ins4(v4, i4, v, c);
        }
      }
#pragma unroll
      for (int k = 0; k < 4; ++k) { tv[nb][cg][k] = v4[k]; ti_[nb][cg][k] = i4[k]; }
      __syncthreads();
      if (tid < 32) {
        float m4[4] = {-FLT_MAX, -FLT_MAX, -FLT_MAX, -FLT_MAX};
        int mi[4] = {0x7fffffff, 0x7fffffff, 0x7fffffff, 0x7fffffff};
        for (int g2 = 0; g2 < 8; ++g2)
#pragma unroll
          for (int k = 0; k < 4; ++k) ins4(m4, mi, tv[tid][g2][k], ti_[tid][g2][k]);
#pragma unroll
        for (int k = 0; k < 4; ++k) {
          cStore(P.pval + w * 128 + tid * 4 + k, m4[k]);
          cStoreI(P.pidx + w * 128 + tid * 4 + k, mi[k]);
        }
      }
    }
    fbar(P.arr, P.gf, ++ph);

    // ===== F: global top-4/row, beam select, publish obl/tok (WG 0) =====
    if (w == 0) {
      {
        const int r = tid >> 3, ch = tid & 7;
        float m4[4] = {-FLT_MAX, -FLT_MAX, -FLT_MAX, -FLT_MAX};
        int mi[4] = {0x7fffffff, 0x7fffffff, 0x7fffffff, 0x7fffffff};
        for (int wg = ch * 32; wg < ch * 32 + 32; ++wg)
#pragma unroll
          for (int k = 0; k < 4; ++k)
            ins4(m4, mi, cLoad(P.pval + wg * 128 + r * 4 + k),
                 cLoadI(P.pidx + wg * 128 + r * 4 + k));
#pragma unroll
        for (int k = 0; k < 4; ++k) { tv[r][ch][k] = m4[k]; ti_[r][ch][k] = mi[k]; }
      }
      __syncthreads();
      if (tid < 32) {
        float m4[4] = {-FLT_MAX, -FLT_MAX, -FLT_MAX, -FLT_MAX};
        int mi[4] = {0x7fffffff, 0x7fffffff, 0x7fffffff, 0x7fffffff};
        for (int g2 = 0; g2 < 8; ++g2)
#pragma unroll
          for (int k = 0; k < 4; ++k) ins4(m4, mi, tv[tid][g2][k], ti_[tid][g2][k]);
#pragma unroll
        for (int k = 0; k < 4; ++k) { rv[tid][k] = m4[k]; rt[tid][k] = mi[k]; }
      }
      __syncthreads();
      if (tid < 8) {
        const int b2 = tid;
        unsigned used = 0;
#pragma unroll
        for (int sel = 0; sel < 4; ++sel) {
          float bestv = -FLT_MAX; int bestj = -1;
          for (int j = 0; j < 16; ++j) {
            if (used & (1u << j)) continue;
            float vv = rv[(j >> 2) * 8 + b2][j & 3];
            if (vv > bestv) { bestv = vv; bestj = j; }  // tie -> lower j
          }
          used |= 1u << bestj;
          const int obn = bestj >> 2;
          const int tkn = rt[obn * 8 + b2][bestj & 3];
          obl[sel][b2] = obn; tkl[sel][b2] = tkn;
          P.obh[t * 32 + sel * 8 + b2] = obn;
          cStoreI(P.tok + sel * 8 + b2, tkn);
          cStoreI(P.obuf + sel * 8 + b2, obn);
        }
        int tmp[4][13];
        for (int n2 = 0; n2 < 4; ++n2)
          for (int s2 = 0; s2 < 13; ++s2) tmp[n2][s2] = res[obl[n2][b2]][s2][b2];
        for (int n2 = 0; n2 < 4; ++n2)
          for (int s2 = 0; s2 < 13; ++s2) res[n2][s2][b2] = tmp[n2][s2];
        for (int n2 = 0; n2 < 4; ++n2) res[n2][t + 1][b2] = tkl[n2][b2];
      }
      __syncthreads();
      if (t == 11 && tid < 104) {
        P.res0[tid] = res[0][tid >> 3][tid & 7];  // res0[s][b]
      }
    }
    fbar(P.arr, P.gf, ++ph);
  }
}

// ---------------------------------------------------------------------------
// Output assembly: WG = (b, v-block of 1000). Backtrace beam-0 path, stage
// [13][1000] in LDS, write fully-coalesced 13000-float runs.
// ---------------------------------------------------------------------------
__global__ __launch_bounds__(256) void out_kernel(const __hip_bfloat16* hist,
                                                  const int* obh, const int* res0,
                                                  float* out) {
  __shared__ float sh[13 * 1000];
  __shared__ int sbArr[12];
  const int w = blockIdx.x, tid = threadIdx.x;
  const int b = w >> 5, v0 = (w & 31) * 1000;
  if (tid == 0) {
    int beta = 0;
    for (int t = 11; t >= 0; --t) {
      const int sb = obh[t * 32 + beta * 8 + b];
      sbArr[t] = sb;
      beta = sb;
    }
  }
  __syncthreads();
  for (int e = tid; e < 12000; e += 256) {
    const int t = e / 1000, vv = e - t * 1000;
    sh[(t + 1) * 1000 + vv] = __bfloat162float(
        hist[(size_t)(t * 32 + sbArr[t] * 8 + b) * 32000 + v0 + vv]);
  }
  for (int e = tid; e < 1000; e += 256) sh[e] = (v0 + e == 1) ? 1.0f : 0.0f;
  __syncthreads();
  float* base = out + 104 + (size_t)(b * 32000 + v0) * 13;
  for (int o = tid; o < 13000; o += 256) {
    const int v = o / 13, t = o - v * 13;
    base[o] = sh[t * 1000 + v];
  }
  if (w == 0 && tid < 104) {
    out[(tid & 7) * 13 + (tid >> 3)] = (float)res0[tid];
  }
}

// ---------------------------------------------------------------------------
extern "C" void kernel_launch(void* const* d_in, const int* in_sizes, int n_in,
                              void* d_out, int out_size, void* d_ws, size_t ws_size,
                              hipStream_t stream) {
  const int* text  = (const int*)d_in[0];
  const float* embE = (const float*)d_in[1];
  const float* embD = (const float*)d_in[2];
  const float* Wih0 = (const float*)d_in[3];
  const float* Whh0 = (const float*)d_in[4];
  const float* bih0 = (const float*)d_in[5];
  const float* bhh0 = (const float*)d_in[6];
  const float* Wih1 = (const float*)d_in[7];
  const float* Whh1 = (const float*)d_in[8];
  const float* bih1 = (const float*)d_in[9];
  const float* bhh1 = (const float*)d_in[10];
  const float* dWih = (const float*)d_in[11];
  const float* dWhh = (const float*)d_in[12];
  const float* dbih = (const float*)d_in[13];
  const float* dbhh = (const float*)d_in[14];
  const float* Wq = (const float*)d_in[15];
  const float* bq = (const float*)d_in[16];
  const float* Wk = (const float*)d_in[17];
  const float* bk = (const float*)d_in[18];
  const float* Wv = (const float*)d_in[19];
  const float* bv = (const float*)d_in[20];
  const float* Wo = (const float*)d_in[21];
  const float* bo = (const float*)d_in[22];
  const float* Wout = (const float*)d_in[23];
  const float* bout = (const float*)d_in[24];

  char* ws = (char*)d_ws;
  size_t off = 0;
  auto alloc = [&](size_t bytes) -> char* {
    off = (off + 511) & ~(size_t)511;
    char* p = ws + off;
    off += bytes;
    return p;
  };
  int* arrE  = (int*)alloc(8192 * 4);
  int* gfE   = (int*)alloc(32 * 4);
  int* arrD  = (int*)alloc(8192 * 4);
  int* gfD   = (int*)alloc(32 * 4);
  float* h0buf = (float*)alloc(2 * 4096 * 4);
  float* h1buf = (float*)alloc(2 * 4096 * 4);
  float* h0f  = (float*)alloc(4096 * 4);
  float* h1f  = (float*)alloc(4096 * 4);
  float* c1f  = (float*)alloc(4096 * 4);
  float* kenc = (float*)alloc(8192 * 4);
  float* venc = (float*)alloc(8192 * 4);
  float* At   = (float*)alloc((size_t)262144 * 4);
  float* W2   = (float*)alloc((size_t)262144 * 4);
  float* u    = (float*)alloc(512 * 4);
  float* pvec = (float*)alloc(8192 * 4);
  float* veWo = (float*)alloc(8192 * 4);
  float* bvo  = (float*)alloc(512 * 4);
  float* sl0  = (float*)alloc(16 * 4);
  float* sbb  = (float*)alloc(32 * 4);
  float* nhb  = (float*)alloc(2 * 16384 * 4);
  float* ncb  = (float*)alloc(2 * 16384 * 4);
  float* mbuf = (float*)alloc(16384 * 4);
  float* vbuf = (float*)alloc(16384 * 4);
  float* out1 = (float*)alloc(16384 * 4);
  int* tok    = (int*)alloc(32 * 4);
  int* obuf   = (int*)alloc(32 * 4);
  float* pval = (float*)alloc(32768 * 4);
  int* pidx   = (int*)alloc(32768 * 4);
  int* obh    = (int*)alloc(384 * 4);
  int* res0   = (int*)alloc(104 * 4);
  __hip_bfloat16* hist = (__hip_bfloat16*)alloc((size_t)12288000 * 2);
  if (off > ws_size) return;  // ~27.6 MB required

  init_kernel<<<32, 256, 0, stream>>>(h0buf, h1buf, arrE, gfE, arrD, gfD);

  EncP ep{text, embE, Wih0, Whh0, bih0, bhh0, Wih1, Whh1, bih1, bhh1,
          h0buf, h1buf, h0f, h1f, c1f, arrE, gfE};
  enc_kernel<<<256, 256, 0, stream>>>(ep);

  prep_kernel<<<128, 256, 0, stream>>>(Wk, bk, Wv, bv, h0f, h1f, c1f, kenc, venc,
                                       nhb, ncb, tok, obuf);
  prep2_kernel<<<256, 256, 0, stream>>>(Wq, Wk, Wv, Wo, bq, bk, bv, kenc, venc,
                                        At, W2, u, pvec, veWo, bvo, sl0, sbb);

  DecP dp{embD, dWih, dWhh, dbih, dbhh, bo, Wout, bout,
          At, W2, u, bvo, pvec, sl0, sbb, veWo,
          nhb, ncb, mbuf, vbuf, out1, tok, obuf,
          pval, pidx, obh, res0, hist, arrD, gfD};
  dec_kernel<<<256, 256, 0, stream>>>(dp);

  out_kernel<<<256, 256, 0, stream>>>(hist, obh, res0, (float*)d_out);
}

// Round 5
// 8075.999 us; speedup vs baseline: 1.7352x; 1.2002x over previous
//
#include <hip/hip_runtime.h>
#include <hip/hip_bf16.h>
#include <float.h>

// ---------------------------------------------------------------------------
// Beam-search seq2seq (2-layer LSTM encoder S=512, 4-beam decoder MAXLEN=12,
// V=32000). fp32 math; bf16 only for stored logits history.
//
// R5: busy-wait grid barrier (FMA spin raises DVFS clocks; R4 analysis showed
// effective clock ~1.1GHz because the GPU is 85% stalled). Decoder: logits
// algebra folded (E0/E1/bc precompute), R8N2-tiled Wout GEMV with deep load
// batching, packed u64 top-k exchange.
// ---------------------------------------------------------------------------

using ull = unsigned long long;

#define SCOPE_AGENT __HIP_MEMORY_SCOPE_AGENT

__device__ __forceinline__ float cLoad(const float* p) {
  return __hip_atomic_load(p, __ATOMIC_RELAXED, SCOPE_AGENT);
}
__device__ __forceinline__ void cStore(float* p, float v) {
  __hip_atomic_store(p, v, __ATOMIC_RELAXED, SCOPE_AGENT);
}
__device__ __forceinline__ int cLoadI(const int* p) {
  return __hip_atomic_load(p, __ATOMIC_RELAXED, SCOPE_AGENT);
}
__device__ __forceinline__ void cStoreI(int* p, int v) {
  __hip_atomic_store(p, v, __ATOMIC_RELAXED, SCOPE_AGENT);
}
__device__ __forceinline__ ull cLoad64(const ull* p) {
  return __hip_atomic_load(p, __ATOMIC_RELAXED, SCOPE_AGENT);
}
__device__ __forceinline__ void cStore64(ull* p, ull v) {
  __hip_atomic_store(p, v, __ATOMIC_RELAXED, SCOPE_AGENT);
}

__device__ __forceinline__ float2 u2f2(ull u) {
  union { ull u; float2 f; } c; c.u = u; return c.f;
}

// Busy-wait epoch barrier, 256 WGs. arr = 256 lines (stride 32 ints),
// gf = 1 broadcast line, lf = per-WG LDS flag. FMA spin keeps VALU busy so
// the DVFS governor boosts clocks (the whole kernel is barrier-dominated).
__device__ __forceinline__ void fbarB(int* arr, int* gf, int phase,
                                      volatile int* lf) {
  __syncthreads();  // drain vmcnt: all coherent data stores at LLC
  if (threadIdx.x == 0) cStoreI(arr + blockIdx.x * 32, phase);
  if (blockIdx.x == 0) {
    const int* f = arr + threadIdx.x * 32;   // thread t waits for WG t
    float d = 1.0f;
    while (cLoadI(f) < phase) {
#pragma unroll
      for (int z = 0; z < 16; ++z) d = fmaf(d, 1.0000001f, 1e-33f);
    }
    asm volatile("" :: "v"(d));
    __syncthreads();
    if (threadIdx.x == 0) cStoreI(gf, phase);
  } else {
    float d = 1.0f;
    if (threadIdx.x < 64) {          // whole wave0 polls gf (no divergence)
      while (cLoadI(gf) < phase) {
#pragma unroll
        for (int z = 0; z < 16; ++z) d = fmaf(d, 1.0000001f, 1e-33f);
      }
      if (threadIdx.x == 0) *lf = phase;
    } else {                          // waves 1-3 spin on LDS flag
      while (*lf < phase) {
#pragma unroll
        for (int z = 0; z < 16; ++z) d = fmaf(d, 1.0000001f, 1e-33f);
      }
    }
    asm volatile("" :: "v"(d));
    __syncthreads();
  }
}

__device__ __forceinline__ float sig_(float x) { return 1.0f / (1.0f + expf(-x)); }

// top-4 sorted insert; ordering matches lax.top_k (desc value, tie -> lower idx)
__device__ __forceinline__ void ins4(float* v, int* id, float nv, int ni) {
  if (nv > v[3] || (nv == v[3] && ni < id[3])) {
    v[3] = nv; id[3] = ni;
#pragma unroll
    for (int p = 3; p > 0; --p) {
      bool sw = (v[p] > v[p - 1]) || (v[p] == v[p - 1] && id[p] < id[p - 1]);
      if (sw) {
        float t0 = v[p]; v[p] = v[p - 1]; v[p - 1] = t0;
        int t1 = id[p]; id[p] = id[p - 1]; id[p - 1] = t1;
      }
    }
  }
}

// ---------------------------------------------------------------------------
__global__ __launch_bounds__(256) void init_kernel(float* h0buf, float* h1buf,
                                                   int* arrE, int* gfE,
                                                   int* arrD, int* gfD) {
  int g = blockIdx.x * 256 + threadIdx.x;
  if (g < 8192) {
    h0buf[g] = 0.0f; h1buf[g] = 0.0f;
    arrE[g] = 0; arrD[g] = 0;
  }
  if (g < 32) { gfE[g] = 0; gfD[g] = 0; }
}

// ---------------------------------------------------------------------------
// Encoder (unchanged structure from R4; barrier swapped to busy-wait).
// ---------------------------------------------------------------------------
struct EncP {
  const int* text; const float* emb;
  const float* Wih0; const float* Whh0; const float* bih0; const float* bhh0;
  const float* Wih1; const float* Whh1; const float* bih1; const float* bhh1;
  float* h0buf; float* h1buf; float* h0f; float* h1f; float* c1f;
  int* arr; int* gf;
};

template <int KX>
__device__ void enc_run(const EncP& P, float* xcat, int w, int tid,
                        volatile int* lf) {
  constexpr int KTOT = KX + 512;
  constexpr int ST = KTOT + 4;
  constexpr int KSL = KTOT / 8;
  constexpr int Q = KSL / 4;
  constexpr int L = (KX == 512) ? 1 : 0;
  __shared__ float part[16 * 8 * 8];
  __shared__ float gl[128];

  const int c0 = (w & 127) * 4;
  const int kh = tid >> 5, col = (tid >> 3) & 3, b = tid & 7;
  const int kbase = kh * KSL;

  const float* Wih = L ? P.Wih1 : P.Wih0;
  const float* Whh = L ? P.Whh1 : P.Whh0;

  const float4* wih4[4]; const float4* whh4[4];
#pragma unroll
  for (int g = 0; g < 4; ++g) {
    const int row = g * 512 + c0 + col;
    wih4[g] = (const float4*)(Wih + (size_t)row * KX);
    whh4[g] = (const float4*)(Whh + (size_t)row * 512);
  }
  float bsum = 0.f;
  if (tid < 128) {
    const int r = tid >> 3;
    const int row = (r & 3) * 512 + c0 + (r >> 2);
    bsum = (L ? P.bih1[row] + P.bhh1[row] : P.bih0[row] + P.bhh0[row]);
  }
  float creg = 0.f;
  float* myH = L ? P.h1buf : P.h0buf;

  int qx = (KX - kbase) / 4;
  qx = qx < 0 ? 0 : (qx > Q ? Q : qx);

  for (int i = 0; i <= 512; ++i) {
    const bool act = L ? (i >= 1) : (i < 512);
    if (act) {
      const int t = L ? (i - 1) : i;
      if constexpr (KX == 256) {
        for (int e = tid; e < 1024; e += 256) {
          const int b2 = e >> 7, k2 = e & 127;
          const int tokv = P.text[t * 8 + b2];
          float2 v = *(const float2*)(P.emb + (size_t)tokv * 256 + 2 * k2);
          *(float2*)(xcat + b2 * ST + 2 * k2) = v;
        }
      } else {
        const ull* x0 = (const ull*)(P.h0buf + ((i + 1) & 1) * 4096);
        for (int e = tid; e < 2048; e += 256) {
          const int b2 = e >> 8, k2 = e & 255;
          ull u = cLoad64(x0 + b2 * 256 + k2);
          *(ull*)(xcat + b2 * ST + 2 * k2) = u;
        }
      }
      {
        const float* hp = L ? (P.h1buf + (i & 1) * 4096)
                            : (P.h0buf + ((i + 1) & 1) * 4096);
        const ull* hq = (const ull*)hp;
        for (int e = tid; e < 2048; e += 256) {
          const int b2 = e >> 8, k2 = e & 255;
          ull u = cLoad64(hq + b2 * 256 + k2);
          *(ull*)(xcat + b2 * ST + KX + 2 * k2) = u;
        }
      }
      __syncthreads();
      float a0 = 0.f, a1 = 0.f, a2 = 0.f, a3 = 0.f;
      const float4* xq = (const float4*)(xcat + b * ST + kbase);
      const int iw = kbase >> 2, ih = (kbase - KX) >> 2;
#pragma unroll 4
      for (int q = 0; q < qx; ++q) {
        float4 x = xq[q];
        float4 w0 = wih4[0][iw + q], w1 = wih4[1][iw + q];
        float4 w2 = wih4[2][iw + q], w3 = wih4[3][iw + q];
        a0 = fmaf(w0.x, x.x, a0); a0 = fmaf(w0.y, x.y, a0);
        a0 = fmaf(w0.z, x.z, a0); a0 = fmaf(w0.w, x.w, a0);
        a1 = fmaf(w1.x, x.x, a1); a1 = fmaf(w1.y, x.y, a1);
        a1 = fmaf(w1.z, x.z, a1); a1 = fmaf(w1.w, x.w, a1);
        a2 = fmaf(w2.x, x.x, a2); a2 = fmaf(w2.y, x.y, a2);
        a2 = fmaf(w2.z, x.z, a2); a2 = fmaf(w2.w, x.w, a2);
        a3 = fmaf(w3.x, x.x, a3); a3 = fmaf(w3.y, x.y, a3);
        a3 = fmaf(w3.z, x.z, a3); a3 = fmaf(w3.w, x.w, a3);
      }
#pragma unroll 4
      for (int q = qx; q < Q; ++q) {
        float4 x = xq[q];
        float4 w0 = whh4[0][ih + q], w1 = whh4[1][ih + q];
        float4 w2 = whh4[2][ih + q], w3 = whh4[3][ih + q];
        a0 = fmaf(w0.x, x.x, a0); a0 = fmaf(w0.y, x.y, a0);
        a0 = fmaf(w0.z, x.z, a0); a0 = fmaf(w0.w, x.w, a0);
        a1 = fmaf(w1.x, x.x, a1); a1 = fmaf(w1.y, x.y, a1);
        a1 = fmaf(w1.z, x.z, a1); a1 = fmaf(w1.w, x.w, a1);
        a2 = fmaf(w2.x, x.x, a2); a2 = fmaf(w2.y, x.y, a2);
        a2 = fmaf(w2.z, x.z, a2); a2 = fmaf(w2.w, x.w, a2);
        a3 = fmaf(w3.x, x.x, a3); a3 = fmaf(w3.y, x.y, a3);
        a3 = fmaf(w3.z, x.z, a3); a3 = fmaf(w3.w, x.w, a3);
      }
      part[((col * 4 + 0) * 8 + b) * 8 + kh] = a0;
      part[((col * 4 + 1) * 8 + b) * 8 + kh] = a1;
      part[((col * 4 + 2) * 8 + b) * 8 + kh] = a2;
      part[((col * 4 + 3) * 8 + b) * 8 + kh] = a3;
      __syncthreads();
      if (tid < 128) {
        const int r = tid >> 3, b2 = tid & 7;
        const float4* pp = (const float4*)(part + (r * 8 + b2) * 8);
        float4 p0 = pp[0], p1 = pp[1];
        gl[r * 8 + b2] =
            bsum + (((p0.x + p0.y) + (p0.z + p0.w)) + ((p1.x + p1.y) + (p1.z + p1.w)));
      }
      __syncthreads();
      if (tid < 32) {
        const int cc = tid >> 3, b2 = tid & 7;
        float gi = gl[(cc * 4 + 0) * 8 + b2], gf_ = gl[(cc * 4 + 1) * 8 + b2];
        float gg = gl[(cc * 4 + 2) * 8 + b2], go = gl[(cc * 4 + 3) * 8 + b2];
        float c2 = sig_(gf_) * creg + sig_(gi) * tanhf(gg);
        float hv = sig_(go) * tanhf(c2);
        creg = c2;
        cStore(myH + (t & 1) * 4096 + b2 * 512 + c0 + cc, hv);
        if (t == 511) {
          (L ? P.h1f : P.h0f)[b2 * 512 + c0 + cc] = hv;
          if (L) P.c1f[b2 * 512 + c0 + cc] = c2;
        }
      }
    }
    if (i < 512) fbarB(P.arr, P.gf, i + 1, lf);
  }
}

__global__ __launch_bounds__(256, 1) void enc_kernel(EncP P) {
  __shared__ float xcat0[8 * 772];
  __shared__ float xcat1[8 * 1028];
  __shared__ int lflag;
  if (threadIdx.x == 0) lflag = 0;
  __syncthreads();
  if (blockIdx.x >> 7) enc_run<512>(P, xcat1, blockIdx.x, threadIdx.x, &lflag);
  else enc_run<256>(P, xcat0, blockIdx.x, threadIdx.x, &lflag);
}

// ---------------------------------------------------------------------------
// prep: k_enc/v_enc projections, decoder state init
// ---------------------------------------------------------------------------
__global__ __launch_bounds__(256) void prep_kernel(
    const float* Wk, const float* bk, const float* Wv, const float* bv,
    const float* h0f, const float* h1f, const float* c1f,
    float* kenc, float* venc, float* nhb, float* ncb, int* tok, int* obuf) {
  const int w = blockIdx.x, tid = threadIdx.x;
  if (w < 64) {
    const int o = w * 256 + tid;
    const int kv = o >> 13, l = (o >> 12) & 1, b = (o >> 9) & 7, c = o & 511;
    const float4* h4 = (const float4*)((l ? h1f : h0f) + b * 512);
    const float4* w4 = (const float4*)((kv ? Wv : Wk) + (size_t)c * 512);
    float s0 = 0.f, s1 = 0.f, s2 = 0.f, s3 = 0.f;
#pragma unroll 8
    for (int k = 0; k < 128; ++k) {
      float4 a = w4[k], x = h4[k];
      s0 = fmaf(a.x, x.x, s0); s1 = fmaf(a.y, x.y, s1);
      s2 = fmaf(a.z, x.z, s2); s3 = fmaf(a.w, x.w, s3);
    }
    (kv ? venc : kenc)[l * 4096 + b * 512 + c] =
        (kv ? bv : bk)[c] + ((s0 + s1) + (s2 + s3));
  } else {
    const int o = (w - 64) * 256 + tid;
    nhb[16384 + o] = h1f[o & 4095];
    ncb[16384 + o] = c1f[o & 4095];
    if (o < 32) { tok[o] = 1; obuf[o] = o >> 3; }
  }
}

// ---------------------------------------------------------------------------
// prep2: attention algebra folds (R3-verified).
// ---------------------------------------------------------------------------
__global__ __launch_bounds__(256) void prep2_kernel(
    const float* Wq, const float* Wk, const float* Wv, const float* Wo,
    const float* bq, const float* bk, const float* bv,
    const float* kenc, const float* venc,
    float* At, float* W2, float* u, float* pvec, float* veWo, float* bvo,
    float* sl0, float* sbb) {
  const int w = blockIdx.x, tid = threadIdx.x;
#pragma unroll 1
  for (int sub = 0; sub < 2; ++sub) {
    const int d = 2 * w + sub;
    for (int cc = 0; cc < 2; ++cc) {
      const int c = tid + cc * 256;
      float s0 = 0.f, s1 = 0.f, s2 = 0.f, s3 = 0.f;
      for (int i = 0; i < 512; i += 4) {
        s0 = fmaf(Wk[(i + 0) * 512 + d], Wq[(i + 0) * 512 + c], s0);
        s1 = fmaf(Wk[(i + 1) * 512 + d], Wq[(i + 1) * 512 + c], s1);
        s2 = fmaf(Wk[(i + 2) * 512 + d], Wq[(i + 2) * 512 + c], s2);
        s3 = fmaf(Wk[(i + 3) * 512 + d], Wq[(i + 3) * 512 + c], s3);
      }
      At[(size_t)d * 512 + c] = (s0 + s1) + (s2 + s3);
    }
    for (int cc = 0; cc < 2; ++cc) {
      const int dc = tid + cc * 256;
      float s0 = 0.f, s1 = 0.f, s2 = 0.f, s3 = 0.f;
      const float* wor = Wo + (size_t)d * 512;
      for (int c2 = 0; c2 < 512; c2 += 4) {
        s0 = fmaf(wor[c2 + 0], Wv[(size_t)(c2 + 0) * 512 + dc], s0);
        s1 = fmaf(wor[c2 + 1], Wv[(size_t)(c2 + 1) * 512 + dc], s1);
        s2 = fmaf(wor[c2 + 2], Wv[(size_t)(c2 + 2) * 512 + dc], s2);
        s3 = fmaf(wor[c2 + 3], Wv[(size_t)(c2 + 3) * 512 + dc], s3);
      }
      W2[(size_t)d * 512 + dc] = (s0 + s1) + (s2 + s3);
    }
  }
  if (w == 0) {
    for (int cc = 0; cc < 2; ++cc) {
      const int c = tid + cc * 256;
      float a = 0.f;
      for (int i = 0; i < 512; ++i)
        a += Wq[i * 512 + c] * bk[i] + Wk[i * 512 + c] * bq[i];
      u[c] = a;
    }
  } else if (w <= 32) {
    const int idx = (w - 1) * 256 + tid;
    const int l = idx >> 12, b = (idx >> 9) & 7, c = idx & 511;
    const float* ke = kenc + l * 4096 + b * 512;
    float a = 0.f;
    for (int i = 0; i < 512; ++i) a = fmaf(Wq[i * 512 + c], ke[i], a);
    pvec[idx] = a;
  } else if (w <= 64) {
    const int idx = (w - 33) * 256 + tid;
    const int l = idx >> 12, b = (idx >> 9) & 7, j = idx & 511;
    const float* ve = venc + l * 4096 + b * 512;
    const float* wo = Wo + (size_t)j * 512;
    float a = 0.f;
    for (int c = 0; c < 512; ++c) a = fmaf(wo[c], ve[c], a);
    veWo[idx] = a;
  } else if (w == 65) {
    for (int cc = 0; cc < 2; ++cc) {
      const int j = tid + cc * 256;
      const float* wo = Wo + (size_t)j * 512;
      float a = 0.f;
      for (int c = 0; c < 512; ++c) a = fmaf(wo[c], bv[c], a);
      bvo[j] = a;
    }
  } else if (w == 66) {
    if (tid < 16) {
      const int l = tid >> 3, b = tid & 7;
      const float* ke = kenc + l * 4096 + b * 512;
      float a = 0.f;
      for (int i = 0; i < 512; ++i) a = fmaf(bq[i], ke[i], a);
      sl0[tid] = a;
    } else if (tid == 16) {
      float a = 0.f;
      for (int i = 0; i < 512; ++i) a = fmaf(bq[i], bk[i], a);
      sbb[0] = a;
    }
  }
}

// ---------------------------------------------------------------------------
// prep3: fold the static attention terms through Wout.
//   E0[b][v] = veWo[0][b] . Wout[v];  E1[b][v] = veWo[1][b] . Wout[v]
//   bc[v]    = bo . Wout[v] + bout[v]
// ---------------------------------------------------------------------------
__global__ __launch_bounds__(256) void prep3_kernel(
    const float* Wout, const float* bout, const float* bo, const float* veWo,
    float* E0g, float* E1g, float* bcg) {
  __shared__ float sv[8704];   // veWo[2][8][512] ; bo[512]
  const int w = blockIdx.x, tid = threadIdx.x;
  for (int e = tid; e < 8704; e += 256)
    sv[e] = (e < 8192) ? veWo[e] : bo[e - 8192];
  __syncthreads();
  const int cbase = w * 125;
  for (int jj = 0; jj < 9; ++jj) {
    const int idx = jj * 256 + tid;
    if (idx < 2125) {
      const int row = cbase + idx / 17, sel = idx % 17;
      const float4* wr = (const float4*)(Wout + (size_t)row * 512);
      const float4* xv = (const float4*)(sv + (sel < 16 ? sel * 512 : 8192));
      float s0 = 0.f, s1 = 0.f, s2 = 0.f, s3 = 0.f;
#pragma unroll 8
      for (int k = 0; k < 128; ++k) {
        float4 a = wr[k], x = xv[k];
        s0 = fmaf(a.x, x.x, s0); s1 = fmaf(a.y, x.y, s1);
        s2 = fmaf(a.z, x.z, s2); s3 = fmaf(a.w, x.w, s3);
      }
      const float s = (s0 + s1) + (s2 + s3);
      if (sel < 16) (sel < 8 ? E0g : E1g)[(size_t)(sel & 7) * 32000 + row] = s;
      else bcg[row] = s + bout[row];
    }
  }
}

// ---------------------------------------------------------------------------
// Decoder: 256 WGs x 256 thr, 12 steps x 5 busy-wait barrier phases.
// ---------------------------------------------------------------------------
struct DecP {
  const float* emb;
  const float* Wih; const float* Whh; const float* bih; const float* bhh;
  const float* Wout;
  const float* At; const float* W2; const float* u; const float* bvo;
  const float* pvec; const float* sl0; const float* sbb;
  const float* E0g; const float* E1g; const float* bcg;
  float* nhb; float* ncb;  // [2][32][512]
  float* mbuf;   // [32][512]
  float* vbuf;   // [32][512]
  float* wsmG;   // [32][3]
  int* tok;      // [32]
  int* obuf;     // [32]
  ull* pvp;      // [256][32][4] packed (val,idx)
  int* obh;      // [12][4][8]
  int* res0;     // [13][8]
  __hip_bfloat16* hist;    // [12][32][32000]
  int* arr; int* gf;
};

// stage [32][512] coherent source into LDS (2 chunks, 8B loads) and dot with
// one weight row; all 256 threads of a WG must call uniformly.
__device__ float stage_dot512(const float* src, const float4* w4row, float* hs,
                              int nb) {
  const int tid = threadIdx.x;
  float s0 = 0.f, s1 = 0.f, s2 = 0.f, s3 = 0.f;
  for (int ck = 0; ck < 2; ++ck) {
    __syncthreads();
    const ull* s8 = (const ull*)src;
    for (int e = tid; e < 4096; e += 256) {
      const int nb2 = e >> 7, k2 = e & 127;
      ull v = cLoad64(s8 + nb2 * 256 + ck * 128 + k2);
      *(ull*)(hs + nb2 * 260 + 2 * k2) = v;
    }
    __syncthreads();
    const float4* h4 = (const float4*)hs + nb * 65;
    const float4* w4 = w4row + ck * 64;
#pragma unroll 8
    for (int k = 0; k < 64; ++k) {
      float4 a = w4[k], x = h4[k];
      s0 = fmaf(a.x, x.x, s0); s1 = fmaf(a.y, x.y, s1);
      s2 = fmaf(a.z, x.z, s2); s3 = fmaf(a.w, x.w, s3);
    }
  }
  return (s0 + s1) + (s2 + s3);
}

__global__ __launch_bounds__(256, 1) void dec_kernel(DecP P) {
  __shared__ float hs[32 * 260];
  __shared__ float gl[2][4][32];
  __shared__ float sl[32][3];
  __shared__ float wsl[96];
  __shared__ float tv[32][16][4];
  __shared__ int ti_[32][16][4];
  __shared__ float rv[32][4];
  __shared__ int rt[32][4];
  __shared__ int res[4][13][8];
  __shared__ int obl[4][8];
  __shared__ int tkl[4][8];
  __shared__ int oblS[32];
  __shared__ int tokS[32];
  __shared__ int lflag;

  const int w = blockIdx.x, tid = threadIdx.x;
  int ph = 0;
  if (tid == 0) lflag = 0;

  if (tid < 104) {
    for (int n = 0; n < 4; ++n) res[n][tid >> 3][tid & 7] = 1;
  }
  __syncthreads();

  for (int t = 0; t < 12; ++t) {
    const int curOff = (t & 1) * 16384, prevOff = ((t + 1) & 1) * 16384;
    // ===== A: LSTM gates + cell; h/c gathered by backpointer =====
    {
      const int col_l = tid >> 7, gate = (tid >> 5) & 3, nb = tid & 31;
      const int col = 2 * w + col_l;
      const int row = gate * 512 + col;
      if (tid < 32) {
        oblS[tid] = cLoadI(P.obuf + tid);
        tokS[tid] = cLoadI(P.tok + tid);
      }
      __syncthreads();
      for (int e = tid; e < 2048; e += 256) {
        const int nb2 = e >> 6, kf = e & 63;
        float4 v = *((const float4*)(P.emb + (size_t)tokS[nb2] * 256) + kf);
        *((float4*)hs + nb2 * 65 + kf) = v;
      }
      __syncthreads();
      float s0 = 0.f, s1 = 0.f, s2 = 0.f, s3 = 0.f;
      {
        const float4* a4 = (const float4*)(P.Wih + (size_t)row * 256);
        const float4* x4 = (const float4*)hs + nb * 65;
#pragma unroll 8
        for (int k = 0; k < 64; ++k) {
          float4 a = a4[k], x = x4[k];
          s0 = fmaf(a.x, x.x, s0); s1 = fmaf(a.y, x.y, s1);
          s2 = fmaf(a.z, x.z, s2); s3 = fmaf(a.w, x.w, s3);
        }
      }
      float acc = P.bih[row] + P.bhh[row];
      const ull* hsrc = (const ull*)(P.nhb + prevOff);
      const float4* w4row = (const float4*)(P.Whh + (size_t)row * 512);
      for (int ck = 0; ck < 2; ++ck) {
        __syncthreads();
        for (int e = tid; e < 4096; e += 256) {
          const int nb2 = e >> 7, k2 = e & 127;
          const int srow = oblS[nb2] * 8 + (nb2 & 7);
          ull v = cLoad64(hsrc + srow * 256 + ck * 128 + k2);
          *(ull*)(hs + nb2 * 260 + 2 * k2) = v;
        }
        __syncthreads();
        const float4* h4 = (const float4*)hs + nb * 65;
        const float4* w4 = w4row + ck * 64;
#pragma unroll 8
        for (int k = 0; k < 64; ++k) {
          float4 a = w4[k], x = h4[k];
          s0 = fmaf(a.x, x.x, s0); s1 = fmaf(a.y, x.y, s1);
          s2 = fmaf(a.z, x.z, s2); s3 = fmaf(a.w, x.w, s3);
        }
      }
      acc += (s0 + s1) + (s2 + s3);
      gl[col_l][gate][nb] = acc;
      __syncthreads();
      if (tid < 64) {
        const int cc = tid >> 5, nb2 = tid & 31;
        const int col2 = 2 * w + cc;
        float gi = gl[cc][0][nb2], gf_ = gl[cc][1][nb2];
        float gg = gl[cc][2][nb2], go = gl[cc][3][nb2];
        const int srow = oblS[nb2] * 8 + (nb2 & 7);
        float cold = cLoad(P.ncb + prevOff + srow * 512 + col2);
        float c2 = sig_(gf_) * cold + sig_(gi) * tanhf(gg);
        float hv = sig_(go) * tanhf(c2);
        cStore(P.nhb + curOff + nb2 * 512 + col2, hv);
        cStore(P.ncb + curOff + nb2 * 512 + col2, c2);
      }
    }
    fbarB(P.arr, P.gf, ++ph, &lflag);

    // ===== B: mbuf = At@nh + u ; vbuf = W2@nh + bvo  (128 WGs) =====
    if (w < 128) {
      const int p = w >> 6, cb = w & 63;
      const int col_l = tid >> 5, nb = tid & 31;
      const int col = cb * 8 + col_l;
      const float* W = (p ? P.W2 : P.At) + (size_t)col * 512;
      float acc = (p ? P.bvo : P.u)[col];
      acc += stage_dot512(P.nhb + curOff, (const float4*)W, hs, nb);
      cStore((p ? P.vbuf : P.mbuf) + nb * 512 + col, acc);
    }
    fbarB(P.arr, P.gf, ++ph, &lflag);

    // ===== C: scores (batched) / softmax / publish wsm  (WG 0) =====
    if (w == 0) {
      if (tid < 192) {
        const int dotid = tid >> 1, kh = tid & 1;
        const int nb = dotid / 3, l = dotid - nb * 3, b = nb & 7;
        const ull* xa = (const ull*)(P.nhb + curOff) + nb * 256 + kh * 128;
        const float sb0 = (l < 2) ? P.sl0[l * 8 + b] : P.sbb[0];
        float a0 = 0.f, a1 = 0.f;
        if (l < 2) {
          const ull* ya = (const ull*)(P.pvec + l * 4096 + b * 512) + kh * 128;
          for (int chk = 0; chk < 8; ++chk) {
            ull xr[16], yr[16];
#pragma unroll
            for (int z = 0; z < 16; ++z) {
              xr[z] = cLoad64(xa + chk * 16 + z);
              yr[z] = ya[chk * 16 + z];
            }
#pragma unroll
            for (int z = 0; z < 16; ++z) {
              float2 x = u2f2(xr[z]), y = u2f2(yr[z]);
              a0 = fmaf(x.x, y.x, a0); a1 = fmaf(x.y, y.y, a1);
            }
          }
        } else {
          const ull* ya = (const ull*)P.mbuf + nb * 256 + kh * 128;
          for (int chk = 0; chk < 8; ++chk) {
            ull xr[16], yr[16];
#pragma unroll
            for (int z = 0; z < 16; ++z) {
              xr[z] = cLoad64(xa + chk * 16 + z);
              yr[z] = cLoad64(ya + chk * 16 + z);
            }
#pragma unroll
            for (int z = 0; z < 16; ++z) {
              float2 x = u2f2(xr[z]), y = u2f2(yr[z]);
              a0 = fmaf(x.x, y.x, a0); a1 = fmaf(x.y, y.y, a1);
            }
          }
        }
        float acc = a0 + a1;
        acc += __shfl_xor(acc, 1);
        if (kh == 0) sl[nb][l] = (acc + sb0) * (1.0f / sqrtf(512.0f));
      }
      __syncthreads();
      if (tid < 32) {
        float a = sl[tid][0], b2 = sl[tid][1], c3 = sl[tid][2];
        float m = fmaxf(a, fmaxf(b2, c3));
        float e0 = expf(a - m), e1 = expf(b2 - m), e2 = expf(c3 - m);
        float inv = 1.0f / (e0 + e1 + e2);
        cStore(P.wsmG + tid * 3 + 0, e0 * inv);
        cStore(P.wsmG + tid * 3 + 1, e1 * inv);
        cStore(P.wsmG + tid * 3 + 2, e2 * inv);
      }
    }
    fbarB(P.arr, P.gf, ++ph, &lflag);

    // ===== E: logits = w0*E0 + w1*E1 + w2*(vbuf.Wout) + bc ; hist ; top-4 ==
    {
      const int pp = tid >> 4, cg = tid & 15;
      const int nb0 = pp, nb1 = pp + 16, b = pp & 7;
      const int cbase = w * 125;
      if (tid < 96) wsl[tid] = cLoad(P.wsmG + tid);
      float acc0[8], acc1[8];
#pragma unroll
      for (int j = 0; j < 8; ++j) { acc0[j] = 0.f; acc1[j] = 0.f; }
      const float4* wp[8];
#pragma unroll
      for (int j = 0; j < 8; ++j) {
        int cl = cg + 16 * j; if (cl > 124) cl = 124;
        wp[j] = (const float4*)(P.Wout + (size_t)(cbase + cl) * 512);
      }
      for (int ck = 0; ck < 2; ++ck) {
        __syncthreads();
        {
          const ull* s8 = (const ull*)P.vbuf;
          for (int e = tid; e < 4096; e += 256) {
            const int nb2 = e >> 7, k2 = e & 127;
            ull v = cLoad64(s8 + nb2 * 256 + ck * 128 + k2);
            *(ull*)(hs + nb2 * 260 + 2 * k2) = v;
          }
        }
        __syncthreads();
        const float4* x0p = (const float4*)hs + nb0 * 65;
        const float4* x1p = (const float4*)hs + nb1 * 65;
        const int kofs = ck * 64;
        for (int k = 0; k < 64; k += 2) {
          float4 xa0 = x0p[k], xa1 = x0p[k + 1];
          float4 xb0 = x1p[k], xb1 = x1p[k + 1];
          float4 wv0[8], wv1[8];
#pragma unroll
          for (int j = 0; j < 8; ++j) {
            wv0[j] = wp[j][kofs + k];
            wv1[j] = wp[j][kofs + k + 1];
          }
#pragma unroll
          for (int j = 0; j < 8; ++j) {
            float4 wa = wv0[j], wb = wv1[j];
            float a = acc0[j];
            a = fmaf(wa.x, xa0.x, a); a = fmaf(wa.y, xa0.y, a);
            a = fmaf(wa.z, xa0.z, a); a = fmaf(wa.w, xa0.w, a);
            a = fmaf(wb.x, xa1.x, a); a = fmaf(wb.y, xa1.y, a);
            a = fmaf(wb.z, xa1.z, a); a = fmaf(wb.w, xa1.w, a);
            acc0[j] = a;
            float c = acc1[j];
            c = fmaf(wa.x, xb0.x, c); c = fmaf(wa.y, xb0.y, c);
            c = fmaf(wa.z, xb0.z, c); c = fmaf(wa.w, xb0.w, c);
            c = fmaf(wb.x, xb1.x, c); c = fmaf(wb.y, xb1.y, c);
            c = fmaf(wb.z, xb1.z, c); c = fmaf(wb.w, xb1.w, c);
            acc1[j] = c;
          }
        }
      }
      const float w00 = wsl[nb0 * 3], w01 = wsl[nb0 * 3 + 1], w02 = wsl[nb0 * 3 + 2];
      const float w10 = wsl[nb1 * 3], w11 = wsl[nb1 * 3 + 1], w12 = wsl[nb1 * 3 + 2];
      float v4a[4] = {-FLT_MAX, -FLT_MAX, -FLT_MAX, -FLT_MAX};
      float v4b[4] = {-FLT_MAX, -FLT_MAX, -FLT_MAX, -FLT_MAX};
      int i4a[4] = {0x7fffffff, 0x7fffffff, 0x7fffffff, 0x7fffffff};
      int i4b[4] = {0x7fffffff, 0x7fffffff, 0x7fffffff, 0x7fffffff};
#pragma unroll
      for (int j = 0; j < 8; ++j) {
        const int cl = cg + 16 * j;
        if (cl < 125) {
          const int c = cbase + cl;
          const float e0 = P.E0g[(size_t)b * 32000 + c];
          const float e1 = P.E1g[(size_t)b * 32000 + c];
          const float bcv = P.bcg[c];
          const float L0 = fmaf(w02, acc0[j], fmaf(w00, e0, fmaf(w01, e1, bcv)));
          const float L1 = fmaf(w12, acc1[j], fmaf(w10, e0, fmaf(w11, e1, bcv)));
          P.hist[(size_t)t * 1024000 + (size_t)nb0 * 32000 + c] = __float2bfloat16(L0);
          P.hist[(size_t)t * 1024000 + (size_t)nb1 * 32000 + c] = __float2bfloat16(L1);
          ins4(v4a, i4a, L0, c);
          ins4(v4b, i4b, L1, c);
        }
      }
#pragma unroll
      for (int k = 0; k < 4; ++k) {
        tv[nb0][cg][k] = v4a[k]; ti_[nb0][cg][k] = i4a[k];
        tv[nb1][cg][k] = v4b[k]; ti_[nb1][cg][k] = i4b[k];
      }
      __syncthreads();
      if (tid < 32) {
        float m4[4] = {-FLT_MAX, -FLT_MAX, -FLT_MAX, -FLT_MAX};
        int mi[4] = {0x7fffffff, 0x7fffffff, 0x7fffffff, 0x7fffffff};
        for (int g2 = 0; g2 < 16; ++g2)
#pragma unroll
          for (int k = 0; k < 4; ++k) ins4(m4, mi, tv[tid][g2][k], ti_[tid][g2][k]);
#pragma unroll
        for (int k = 0; k < 4; ++k) {
          ull pk = ((ull)__float_as_uint(m4[k]) << 32) | (unsigned)mi[k];
          cStore64(P.pvp + w * 128 + tid * 4 + k, pk);
        }
      }
    }
    fbarB(P.arr, P.gf, ++ph, &lflag);

    // ===== F: global top-4/row (packed u64, batched), beam select (WG 0) ===
    if (w == 0) {
      {
        const int r = tid >> 3, ch = tid & 7;
        float m4[4] = {-FLT_MAX, -FLT_MAX, -FLT_MAX, -FLT_MAX};
        int mi[4] = {0x7fffffff, 0x7fffffff, 0x7fffffff, 0x7fffffff};
        for (int g = 0; g < 4; ++g) {
          ull pk[32];
#pragma unroll
          for (int z = 0; z < 32; ++z) {
            const int wg = ch * 32 + g * 8 + (z >> 2);
            pk[z] = cLoad64(P.pvp + wg * 128 + r * 4 + (z & 3));
          }
#pragma unroll
          for (int z = 0; z < 32; ++z) {
            const float vv = __uint_as_float((unsigned)(pk[z] >> 32));
            const int ii = (int)(unsigned)(pk[z] & 0xffffffffu);
            ins4(m4, mi, vv, ii);
          }
        }
#pragma unroll
        for (int k = 0; k < 4; ++k) { tv[r][ch][k] = m4[k]; ti_[r][ch][k] = mi[k]; }
      }
      __syncthreads();
      if (tid < 32) {
        float m4[4] = {-FLT_MAX, -FLT_MAX, -FLT_MAX, -FLT_MAX};
        int mi[4] = {0x7fffffff, 0x7fffffff, 0x7fffffff, 0x7fffffff};
        for (int g2 = 0; g2 < 8; ++g2)
#pragma unroll
          for (int k = 0; k < 4; ++k) ins4(m4, mi, tv[tid][g2][k], ti_[tid][g2][k]);
#pragma unroll
        for (int k = 0; k < 4; ++k) { rv[tid][k] = m4[k]; rt[tid][k] = mi[k]; }
      }
      __syncthreads();
      if (tid < 8) {
        const int b2 = tid;
        unsigned used = 0;
#pragma unroll
        for (int sel = 0; sel < 4; ++sel) {
          float bestv = -FLT_MAX; int bestj = -1;
          for (int j = 0; j < 16; ++j) {
            if (used & (1u << j)) continue;
            float vv = rv[(j >> 2) * 8 + b2][j & 3];
            if (vv > bestv) { bestv = vv; bestj = j; }
          }
          used |= 1u << bestj;
          const int obn = bestj >> 2;
          const int tkn = rt[obn * 8 + b2][bestj & 3];
          obl[sel][b2] = obn; tkl[sel][b2] = tkn;
          P.obh[t * 32 + sel * 8 + b2] = obn;
          cStoreI(P.tok + sel * 8 + b2, tkn);
          cStoreI(P.obuf + sel * 8 + b2, obn);
        }
        int tmp[4][13];
        for (int n2 = 0; n2 < 4; ++n2)
          for (int s2 = 0; s2 < 13; ++s2) tmp[n2][s2] = res[obl[n2][b2]][s2][b2];
        for (int n2 = 0; n2 < 4; ++n2)
          for (int s2 = 0; s2 < 13; ++s2) res[n2][s2][b2] = tmp[n2][s2];
        for (int n2 = 0; n2 < 4; ++n2) res[n2][t + 1][b2] = tkl[n2][b2];
      }
      __syncthreads();
      if (t == 11 && tid < 104) {
        P.res0[tid] = res[0][tid >> 3][tid & 7];
      }
    }
    fbarB(P.arr, P.gf, ++ph, &lflag);
  }
}

// ---------------------------------------------------------------------------
// Output assembly (unchanged from R4).
// ---------------------------------------------------------------------------
__global__ __launch_bounds__(256) void out_kernel(const __hip_bfloat16* hist,
                                                  const int* obh, const int* res0,
                                                  float* out) {
  __shared__ float sh[13 * 1000];
  __shared__ int sbArr[12];
  const int w = blockIdx.x, tid = threadIdx.x;
  const int b = w >> 5, v0 = (w & 31) * 1000;
  if (tid == 0) {
    int beta = 0;
    for (int t = 11; t >= 0; --t) {
      const int sb = obh[t * 32 + beta * 8 + b];
      sbArr[t] = sb;
      beta = sb;
    }
  }
  __syncthreads();
  for (int e = tid; e < 12000; e += 256) {
    const int t = e / 1000, vv = e - t * 1000;
    sh[(t + 1) * 1000 + vv] = __bfloat162float(
        hist[(size_t)(t * 32 + sbArr[t] * 8 + b) * 32000 + v0 + vv]);
  }
  for (int e = tid; e < 1000; e += 256) sh[e] = (v0 + e == 1) ? 1.0f : 0.0f;
  __syncthreads();
  float* base = out + 104 + (size_t)(b * 32000 + v0) * 13;
  for (int o = tid; o < 13000; o += 256) {
    const int v = o / 13, t = o - v * 13;
    base[o] = sh[t * 1000 + v];
  }
  if (w == 0 && tid < 104) {
    out[(tid & 7) * 13 + (tid >> 3)] = (float)res0[tid];
  }
}

// ---------------------------------------------------------------------------
extern "C" void kernel_launch(void* const* d_in, const int* in_sizes, int n_in,
                              void* d_out, int out_size, void* d_ws, size_t ws_size,
                              hipStream_t stream) {
  const int* text  = (const int*)d_in[0];
  const float* embE = (const float*)d_in[1];
  const float* embD = (const float*)d_in[2];
  const float* Wih0 = (const float*)d_in[3];
  const float* Whh0 = (const float*)d_in[4];
  const float* bih0 = (const float*)d_in[5];
  const float* bhh0 = (const float*)d_in[6];
  const float* Wih1 = (const float*)d_in[7];
  const float* Whh1 = (const float*)d_in[8];
  const float* bih1 = (const float*)d_in[9];
  const float* bhh1 = (const float*)d_in[10];
  const float* dWih = (const float*)d_in[11];
  const float* dWhh = (const float*)d_in[12];
  const float* dbih = (const float*)d_in[13];
  const float* dbhh = (const float*)d_in[14];
  const float* Wq = (const float*)d_in[15];
  const float* bq = (const float*)d_in[16];
  const float* Wk = (const float*)d_in[17];
  const float* bk = (const float*)d_in[18];
  const float* Wv = (const float*)d_in[19];
  const float* bv = (const float*)d_in[20];
  const float* Wo = (const float*)d_in[21];
  const float* bo = (const float*)d_in[22];
  const float* Wout = (const float*)d_in[23];
  const float* bout = (const float*)d_in[24];

  char* ws = (char*)d_ws;
  size_t off = 0;
  auto alloc = [&](size_t bytes) -> char* {
    off = (off + 511) & ~(size_t)511;
    char* p = ws + off;
    off += bytes;
    return p;
  };
  int* arrE  = (int*)alloc(8192 * 4);
  int* gfE   = (int*)alloc(32 * 4);
  int* arrD  = (int*)alloc(8192 * 4);
  int* gfD   = (int*)alloc(32 * 4);
  float* h0buf = (float*)alloc(2 * 4096 * 4);
  float* h1buf = (float*)alloc(2 * 4096 * 4);
  float* h0f  = (float*)alloc(4096 * 4);
  float* h1f  = (float*)alloc(4096 * 4);
  float* c1f  = (float*)alloc(4096 * 4);
  float* kenc = (float*)alloc(8192 * 4);
  float* venc = (float*)alloc(8192 * 4);
  float* At   = (float*)alloc((size_t)262144 * 4);
  float* W2   = (float*)alloc((size_t)262144 * 4);
  float* u    = (float*)alloc(512 * 4);
  float* pvec = (float*)alloc(8192 * 4);
  float* veWo = (float*)alloc(8192 * 4);
  float* bvo  = (float*)alloc(512 * 4);
  float* sl0  = (float*)alloc(16 * 4);
  float* sbb  = (float*)alloc(32 * 4);
  float* E0g  = (float*)alloc((size_t)256000 * 4);
  float* E1g  = (float*)alloc((size_t)256000 * 4);
  float* bcg  = (float*)alloc(32000 * 4);
  float* nhb  = (float*)alloc(2 * 16384 * 4);
  float* ncb  = (float*)alloc(2 * 16384 * 4);
  float* mbuf = (float*)alloc(16384 * 4);
  float* vbuf = (float*)alloc(16384 * 4);
  float* wsmG = (float*)alloc(96 * 4);
  int* tok    = (int*)alloc(32 * 4);
  int* obuf   = (int*)alloc(32 * 4);
  ull* pvp    = (ull*)alloc((size_t)32768 * 8);
  int* obh    = (int*)alloc(384 * 4);
  int* res0   = (int*)alloc(104 * 4);
  __hip_bfloat16* hist = (__hip_bfloat16*)alloc((size_t)12288000 * 2);
  if (off > ws_size) return;  // ~30 MB required

  init_kernel<<<32, 256, 0, stream>>>(h0buf, h1buf, arrE, gfE, arrD, gfD);

  EncP ep{text, embE, Wih0, Whh0, bih0, bhh0, Wih1, Whh1, bih1, bhh1,
          h0buf, h1buf, h0f, h1f, c1f, arrE, gfE};
  enc_kernel<<<256, 256, 0, stream>>>(ep);

  prep_kernel<<<128, 256, 0, stream>>>(Wk, bk, Wv, bv, h0f, h1f, c1f, kenc, venc,
                                       nhb, ncb, tok, obuf);
  prep2_kernel<<<256, 256, 0, stream>>>(Wq, Wk, Wv, Wo, bq, bk, bv, kenc, venc,
                                        At, W2, u, pvec, veWo, bvo, sl0, sbb);
  prep3_kernel<<<256, 256, 0, stream>>>(Wout, bout, bo, veWo, E0g, E1g, bcg);

  DecP dp{embD, dWih, dWhh, dbih, dbhh, Wout,
          At, W2, u, bvo, pvec, sl0, sbb, E0g, E1g, bcg,
          nhb, ncb, mbuf, vbuf, wsmG, tok, obuf,
          pvp, obh, res0, hist, arrD, gfD};
  dec_kernel<<<256, 256, 0, stream>>>(dp);

  out_kernel<<<256, 256, 0, stream>>>(hist, obh, res0, (float*)d_out);
}

// Round 6
// 7085.130 us; speedup vs baseline: 1.9779x; 1.1399x over previous
//
#include <hip/hip_runtime.h>
#include <hip/hip_bf16.h>
#include <float.h>

// ---------------------------------------------------------------------------
// Beam-search seq2seq (2-layer LSTM encoder S=512, 4-beam decoder MAXLEN=12,
// V=32000). fp32 math; bf16 only for stored logits history.
//
// R6: low-contention 2-level barrier (<=8 readers per LLC line: R1-R5 all had
// ~256 readers on some line -> ~8us detection). Decoder: 3 barriers/step
// (softmax via per-WG partial scores from B; beam-select replicated in A),
// phase E reads Wout through LDS tiles with fully-coalesced staging.
// ---------------------------------------------------------------------------

using ull = unsigned long long;

#define SCOPE_AGENT __HIP_MEMORY_SCOPE_AGENT

__device__ __forceinline__ float cLoad(const float* p) {
  return __hip_atomic_load(p, __ATOMIC_RELAXED, SCOPE_AGENT);
}
__device__ __forceinline__ void cStore(float* p, float v) {
  __hip_atomic_store(p, v, __ATOMIC_RELAXED, SCOPE_AGENT);
}
__device__ __forceinline__ int cLoadI(const int* p) {
  return __hip_atomic_load(p, __ATOMIC_RELAXED, SCOPE_AGENT);
}
__device__ __forceinline__ void cStoreI(int* p, int v) {
  __hip_atomic_store(p, v, __ATOMIC_RELAXED, SCOPE_AGENT);
}
__device__ __forceinline__ ull cLoad64(const ull* p) {
  return __hip_atomic_load(p, __ATOMIC_RELAXED, SCOPE_AGENT);
}
__device__ __forceinline__ void cStore64(ull* p, ull v) {
  __hip_atomic_store(p, v, __ATOMIC_RELAXED, SCOPE_AGENT);
}

__device__ __forceinline__ float2 u2f2(ull u) {
  union { ull u; float2 f; } c; c.u = u; return c.f;
}

// Two-level epoch barrier, 256 WGs. arr = 256 lines (1 reader each),
// bc = 32 lines (8 readers each). phase monotonic from 1.
__device__ __forceinline__ void fbar2(int* arr, int* bc, int phase) {
  __syncthreads();  // drain vmcnt: all coherent data stores at LLC
  if (threadIdx.x == 0) cStoreI(arr + blockIdx.x * 32, phase);
  if (blockIdx.x == 0) {
    const int* f = arr + threadIdx.x * 32;   // thread t polls WG t: 1 reader/line
    while (cLoadI(f) < phase) {}
    __syncthreads();
    if (threadIdx.x < 32) cStoreI(bc + threadIdx.x * 32, phase);
  } else {
    if (threadIdx.x == 0) {
      const int* f = bc + (blockIdx.x >> 3) * 32;  // 8 readers/line
      while (cLoadI(f) < phase) {}
    }
    __syncthreads();
  }
}

__device__ __forceinline__ float sig_(float x) { return 1.0f / (1.0f + expf(-x)); }

// top-4 sorted insert; ordering matches lax.top_k (desc value, tie -> lower idx)
__device__ __forceinline__ void ins4(float* v, int* id, float nv, int ni) {
  if (nv > v[3] || (nv == v[3] && ni < id[3])) {
    v[3] = nv; id[3] = ni;
#pragma unroll
    for (int p = 3; p > 0; --p) {
      bool sw = (v[p] > v[p - 1]) || (v[p] == v[p - 1] && id[p] < id[p - 1]);
      if (sw) {
        float t0 = v[p]; v[p] = v[p - 1]; v[p - 1] = t0;
        int t1 = id[p]; id[p] = id[p - 1]; id[p - 1] = t1;
      }
    }
  }
}

// ---------------------------------------------------------------------------
__global__ __launch_bounds__(256) void init_kernel(float* h0buf, float* h1buf,
                                                   int* arrE, int* bcE,
                                                   int* arrD, int* bcD) {
  int g = blockIdx.x * 256 + threadIdx.x;
  if (g < 8192) {
    h0buf[g] = 0.0f; h1buf[g] = 0.0f;
    arrE[g] = 0; arrD[g] = 0;
  }
  if (g < 1024) { bcE[g] = 0; bcD[g] = 0; }
}

// ---------------------------------------------------------------------------
// Encoder (R5 compute; fbar2 barrier).
// ---------------------------------------------------------------------------
struct EncP {
  const int* text; const float* emb;
  const float* Wih0; const float* Whh0; const float* bih0; const float* bhh0;
  const float* Wih1; const float* Whh1; const float* bih1; const float* bhh1;
  float* h0buf; float* h1buf; float* h0f; float* h1f; float* c1f;
  int* arr; int* bc;
};

template <int KX>
__device__ void enc_run(const EncP& P, float* xcat, int w, int tid) {
  constexpr int KTOT = KX + 512;
  constexpr int ST = KTOT + 4;
  constexpr int KSL = KTOT / 8;
  constexpr int Q = KSL / 4;
  constexpr int L = (KX == 512) ? 1 : 0;
  __shared__ float part[16 * 8 * 8];
  __shared__ float gl[128];

  const int c0 = (w & 127) * 4;
  const int kh = tid >> 5, col = (tid >> 3) & 3, b = tid & 7;
  const int kbase = kh * KSL;

  const float* Wih = L ? P.Wih1 : P.Wih0;
  const float* Whh = L ? P.Whh1 : P.Whh0;

  const float4* wih4[4]; const float4* whh4[4];
#pragma unroll
  for (int g = 0; g < 4; ++g) {
    const int row = g * 512 + c0 + col;
    wih4[g] = (const float4*)(Wih + (size_t)row * KX);
    whh4[g] = (const float4*)(Whh + (size_t)row * 512);
  }
  float bsum = 0.f;
  if (tid < 128) {
    const int r = tid >> 3;
    const int row = (r & 3) * 512 + c0 + (r >> 2);
    bsum = (L ? P.bih1[row] + P.bhh1[row] : P.bih0[row] + P.bhh0[row]);
  }
  float creg = 0.f;
  float* myH = L ? P.h1buf : P.h0buf;

  int qx = (KX - kbase) / 4;
  qx = qx < 0 ? 0 : (qx > Q ? Q : qx);

  for (int i = 0; i <= 512; ++i) {
    const bool act = L ? (i >= 1) : (i < 512);
    if (act) {
      const int t = L ? (i - 1) : i;
      if constexpr (KX == 256) {
        for (int e = tid; e < 1024; e += 256) {
          const int b2 = e >> 7, k2 = e & 127;
          const int tokv = P.text[t * 8 + b2];
          float2 v = *(const float2*)(P.emb + (size_t)tokv * 256 + 2 * k2);
          *(float2*)(xcat + b2 * ST + 2 * k2) = v;
        }
      } else {
        const ull* x0 = (const ull*)(P.h0buf + ((i + 1) & 1) * 4096);
        for (int e = tid; e < 2048; e += 256) {
          const int b2 = e >> 8, k2 = e & 255;
          ull u = cLoad64(x0 + b2 * 256 + k2);
          *(ull*)(xcat + b2 * ST + 2 * k2) = u;
        }
      }
      {
        const float* hp = L ? (P.h1buf + (i & 1) * 4096)
                            : (P.h0buf + ((i + 1) & 1) * 4096);
        const ull* hq = (const ull*)hp;
        for (int e = tid; e < 2048; e += 256) {
          const int b2 = e >> 8, k2 = e & 255;
          ull u = cLoad64(hq + b2 * 256 + k2);
          *(ull*)(xcat + b2 * ST + KX + 2 * k2) = u;
        }
      }
      __syncthreads();
      float a0 = 0.f, a1 = 0.f, a2 = 0.f, a3 = 0.f;
      const float4* xq = (const float4*)(xcat + b * ST + kbase);
      const int iw = kbase >> 2, ih = (kbase - KX) >> 2;
#pragma unroll 4
      for (int q = 0; q < qx; ++q) {
        float4 x = xq[q];
        float4 w0 = wih4[0][iw + q], w1 = wih4[1][iw + q];
        float4 w2 = wih4[2][iw + q], w3 = wih4[3][iw + q];
        a0 = fmaf(w0.x, x.x, a0); a0 = fmaf(w0.y, x.y, a0);
        a0 = fmaf(w0.z, x.z, a0); a0 = fmaf(w0.w, x.w, a0);
        a1 = fmaf(w1.x, x.x, a1); a1 = fmaf(w1.y, x.y, a1);
        a1 = fmaf(w1.z, x.z, a1); a1 = fmaf(w1.w, x.w, a1);
        a2 = fmaf(w2.x, x.x, a2); a2 = fmaf(w2.y, x.y, a2);
        a2 = fmaf(w2.z, x.z, a2); a2 = fmaf(w2.w, x.w, a2);
        a3 = fmaf(w3.x, x.x, a3); a3 = fmaf(w3.y, x.y, a3);
        a3 = fmaf(w3.z, x.z, a3); a3 = fmaf(w3.w, x.w, a3);
      }
#pragma unroll 4
      for (int q = qx; q < Q; ++q) {
        float4 x = xq[q];
        float4 w0 = whh4[0][ih + q], w1 = whh4[1][ih + q];
        float4 w2 = whh4[2][ih + q], w3 = whh4[3][ih + q];
        a0 = fmaf(w0.x, x.x, a0); a0 = fmaf(w0.y, x.y, a0);
        a0 = fmaf(w0.z, x.z, a0); a0 = fmaf(w0.w, x.w, a0);
        a1 = fmaf(w1.x, x.x, a1); a1 = fmaf(w1.y, x.y, a1);
        a1 = fmaf(w1.z, x.z, a1); a1 = fmaf(w1.w, x.w, a1);
        a2 = fmaf(w2.x, x.x, a2); a2 = fmaf(w2.y, x.y, a2);
        a2 = fmaf(w2.z, x.z, a2); a2 = fmaf(w2.w, x.w, a2);
        a3 = fmaf(w3.x, x.x, a3); a3 = fmaf(w3.y, x.y, a3);
        a3 = fmaf(w3.z, x.z, a3); a3 = fmaf(w3.w, x.w, a3);
      }
      part[((col * 4 + 0) * 8 + b) * 8 + kh] = a0;
      part[((col * 4 + 1) * 8 + b) * 8 + kh] = a1;
      part[((col * 4 + 2) * 8 + b) * 8 + kh] = a2;
      part[((col * 4 + 3) * 8 + b) * 8 + kh] = a3;
      __syncthreads();
      if (tid < 128) {
        const int r = tid >> 3, b2 = tid & 7;
        const float4* pp = (const float4*)(part + (r * 8 + b2) * 8);
        float4 p0 = pp[0], p1 = pp[1];
        gl[r * 8 + b2] =
            bsum + (((p0.x + p0.y) + (p0.z + p0.w)) + ((p1.x + p1.y) + (p1.z + p1.w)));
      }
      __syncthreads();
      if (tid < 32) {
        const int cc = tid >> 3, b2 = tid & 7;
        float gi = gl[(cc * 4 + 0) * 8 + b2], gf_ = gl[(cc * 4 + 1) * 8 + b2];
        float gg = gl[(cc * 4 + 2) * 8 + b2], go = gl[(cc * 4 + 3) * 8 + b2];
        float c2 = sig_(gf_) * creg + sig_(gi) * tanhf(gg);
        float hv = sig_(go) * tanhf(c2);
        creg = c2;
        cStore(myH + (t & 1) * 4096 + b2 * 512 + c0 + cc, hv);
        if (t == 511) {
          (L ? P.h1f : P.h0f)[b2 * 512 + c0 + cc] = hv;
          if (L) P.c1f[b2 * 512 + c0 + cc] = c2;
        }
      }
    }
    if (i < 512) fbar2(P.arr, P.bc, i + 1);
  }
}

__global__ __launch_bounds__(256, 1) void enc_kernel(EncP P) {
  __shared__ float xcat0[8 * 772];
  __shared__ float xcat1[8 * 1028];
  if (blockIdx.x >> 7) enc_run<512>(P, xcat1, blockIdx.x, threadIdx.x);
  else enc_run<256>(P, xcat0, blockIdx.x, threadIdx.x);
}

// ---------------------------------------------------------------------------
// prep: k_enc/v_enc projections, decoder state init
// ---------------------------------------------------------------------------
__global__ __launch_bounds__(256) void prep_kernel(
    const float* Wk, const float* bk, const float* Wv, const float* bv,
    const float* h0f, const float* h1f, const float* c1f,
    float* kenc, float* venc, float* nhb, float* ncb) {
  const int w = blockIdx.x, tid = threadIdx.x;
  if (w < 64) {
    const int o = w * 256 + tid;
    const int kv = o >> 13, l = (o >> 12) & 1, b = (o >> 9) & 7, c = o & 511;
    const float4* h4 = (const float4*)((l ? h1f : h0f) + b * 512);
    const float4* w4 = (const float4*)((kv ? Wv : Wk) + (size_t)c * 512);
    float s0 = 0.f, s1 = 0.f, s2 = 0.f, s3 = 0.f;
#pragma unroll 8
    for (int k = 0; k < 128; ++k) {
      float4 a = w4[k], x = h4[k];
      s0 = fmaf(a.x, x.x, s0); s1 = fmaf(a.y, x.y, s1);
      s2 = fmaf(a.z, x.z, s2); s3 = fmaf(a.w, x.w, s3);
    }
    (kv ? venc : kenc)[l * 4096 + b * 512 + c] =
        (kv ? bv : bk)[c] + ((s0 + s1) + (s2 + s3));
  } else {
    const int o = (w - 64) * 256 + tid;
    nhb[16384 + o] = h1f[o & 4095];
    ncb[16384 + o] = c1f[o & 4095];
  }
}

// ---------------------------------------------------------------------------
// prep2: attention algebra folds (R3-verified).
// ---------------------------------------------------------------------------
__global__ __launch_bounds__(256) void prep2_kernel(
    const float* Wq, const float* Wk, const float* Wv, const float* Wo,
    const float* bq, const float* bk, const float* bv,
    const float* kenc, const float* venc,
    float* At, float* W2, float* u, float* pvec, float* veWo, float* bvo,
    float* sl0, float* sbb) {
  const int w = blockIdx.x, tid = threadIdx.x;
#pragma unroll 1
  for (int sub = 0; sub < 2; ++sub) {
    const int d = 2 * w + sub;
    for (int cc = 0; cc < 2; ++cc) {
      const int c = tid + cc * 256;
      float s0 = 0.f, s1 = 0.f, s2 = 0.f, s3 = 0.f;
      for (int i = 0; i < 512; i += 4) {
        s0 = fmaf(Wk[(i + 0) * 512 + d], Wq[(i + 0) * 512 + c], s0);
        s1 = fmaf(Wk[(i + 1) * 512 + d], Wq[(i + 1) * 512 + c], s1);
        s2 = fmaf(Wk[(i + 2) * 512 + d], Wq[(i + 2) * 512 + c], s2);
        s3 = fmaf(Wk[(i + 3) * 512 + d], Wq[(i + 3) * 512 + c], s3);
      }
      At[(size_t)d * 512 + c] = (s0 + s1) + (s2 + s3);
    }
    for (int cc = 0; cc < 2; ++cc) {
      const int dc = tid + cc * 256;
      float s0 = 0.f, s1 = 0.f, s2 = 0.f, s3 = 0.f;
      const float* wor = Wo + (size_t)d * 512;
      for (int c2 = 0; c2 < 512; c2 += 4) {
        s0 = fmaf(wor[c2 + 0], Wv[(size_t)(c2 + 0) * 512 + dc], s0);
        s1 = fmaf(wor[c2 + 1], Wv[(size_t)(c2 + 1) * 512 + dc], s1);
        s2 = fmaf(wor[c2 + 2], Wv[(size_t)(c2 + 2) * 512 + dc], s2);
        s3 = fmaf(wor[c2 + 3], Wv[(size_t)(c2 + 3) * 512 + dc], s3);
      }
      W2[(size_t)d * 512 + dc] = (s0 + s1) + (s2 + s3);
    }
  }
  if (w == 0) {
    for (int cc = 0; cc < 2; ++cc) {
      const int c = tid + cc * 256;
      float a = 0.f;
      for (int i = 0; i < 512; ++i)
        a += Wq[i * 512 + c] * bk[i] + Wk[i * 512 + c] * bq[i];
      u[c] = a;
    }
  } else if (w <= 32) {
    const int idx = (w - 1) * 256 + tid;
    const int l = idx >> 12, b = (idx >> 9) & 7, c = idx & 511;
    const float* ke = kenc + l * 4096 + b * 512;
    float a = 0.f;
    for (int i = 0; i < 512; ++i) a = fmaf(Wq[i * 512 + c], ke[i], a);
    pvec[idx] = a;
  } else if (w <= 64) {
    const int idx = (w - 33) * 256 + tid;
    const int l = idx >> 12, b = (idx >> 9) & 7, j = idx & 511;
    const float* ve = venc + l * 4096 + b * 512;
    const float* wo = Wo + (size_t)j * 512;
    float a = 0.f;
    for (int c = 0; c < 512; ++c) a = fmaf(wo[c], ve[c], a);
    veWo[idx] = a;
  } else if (w == 65) {
    for (int cc = 0; cc < 2; ++cc) {
      const int j = tid + cc * 256;
      const float* wo = Wo + (size_t)j * 512;
      float a = 0.f;
      for (int c = 0; c < 512; ++c) a = fmaf(wo[c], bv[c], a);
      bvo[j] = a;
    }
  } else if (w == 66) {
    if (tid < 16) {
      const int l = tid >> 3, b = tid & 7;
      const float* ke = kenc + l * 4096 + b * 512;
      float a = 0.f;
      for (int i = 0; i < 512; ++i) a = fmaf(bq[i], ke[i], a);
      sl0[tid] = a;
    } else if (tid == 16) {
      float a = 0.f;
      for (int i = 0; i < 512; ++i) a = fmaf(bq[i], bk[i], a);
      sbb[0] = a;
    }
  }
}

// ---------------------------------------------------------------------------
// prep3: fold static attention terms through Wout (E0/E1/bc).
// ---------------------------------------------------------------------------
__global__ __launch_bounds__(256) void prep3_kernel(
    const float* Wout, const float* bout, const float* bo, const float* veWo,
    float* E0g, float* E1g, float* bcg) {
  __shared__ float sv[8704];
  const int w = blockIdx.x, tid = threadIdx.x;
  for (int e = tid; e < 8704; e += 256)
    sv[e] = (e < 8192) ? veWo[e] : bo[e - 8192];
  __syncthreads();
  const int cbase = w * 125;
  for (int jj = 0; jj < 9; ++jj) {
    const int idx = jj * 256 + tid;
    if (idx < 2125) {
      const int row = cbase + idx / 17, sel = idx % 17;
      const float4* wr = (const float4*)(Wout + (size_t)row * 512);
      const float4* xv = (const float4*)(sv + (sel < 16 ? sel * 512 : 8192));
      float s0 = 0.f, s1 = 0.f, s2 = 0.f, s3 = 0.f;
#pragma unroll 8
      for (int k = 0; k < 128; ++k) {
        float4 a = wr[k], x = xv[k];
        s0 = fmaf(a.x, x.x, s0); s1 = fmaf(a.y, x.y, s1);
        s2 = fmaf(a.z, x.z, s2); s3 = fmaf(a.w, x.w, s3);
      }
      const float s = (s0 + s1) + (s2 + s3);
      if (sel < 16) (sel < 8 ? E0g : E1g)[(size_t)(sel & 7) * 32000 + row] = s;
      else bcg[row] = s + bout[row];
    }
  }
}

// ---------------------------------------------------------------------------
// Decoder: 256 WGs x 256 thr, 12 steps x 3 barriers.
// ---------------------------------------------------------------------------
struct DecP {
  const float* emb;
  const float* Wih; const float* Whh; const float* bih; const float* bhh;
  const float* Wout;
  const float* At; const float* W2; const float* u; const float* bvo;
  const float* pvec; const float* sl0; const float* sbb;
  const float* E0g; const float* E1g; const float* bcg;
  float* nhb; float* ncb;  // [2][32][512]
  float* vbuf;             // [32][512]
  float* part_s;           // [3][32][64]
  ull* pvp;                // [256][32][4] packed (val,idx)
  int* obh;                // [12][4][8]
  int* res0;               // [13][8]
  __hip_bfloat16* hist;    // [12][32][32000]
  int* arr; int* bc;
};

__global__ __launch_bounds__(256, 1) void dec_kernel(DecP P) {
  __shared__ float SM[29312];        // phase-aliased pool (117 KB)
  __shared__ float gl[2][4][32];
  __shared__ float slS[32][3];
  __shared__ float wslS[96];
  __shared__ float svv[32][8][4];
  __shared__ int sii[32][8][4];
  __shared__ float rvS[32][4];
  __shared__ int rtS[32][4];
  __shared__ int resS[4][13][8];
  __shared__ int oblS[32];
  __shared__ int tokS[32];
  __shared__ float pscS[32][8];
  __shared__ float nhsS[32][8];

  const int w = blockIdx.x, tid = threadIdx.x;
  float* hs = SM;                    // [32][260] in A/B
  float* tileS = SM;                 // [4][32][132] in E
  float* vqS = SM + 16896;           // [4][8][132] in E
  float* tvE = SM + 21120;           // [32][130]
  int* tiE = (int*)(SM + 25280);     // [32][130]
  int ph = 0;

  if (tid < 104) {
    for (int n = 0; n < 4; ++n) resS[n][tid >> 3][tid & 7] = 1;
  }

  // replicated beam-select for step tt (reads pvp; all 256 threads)
  auto do_select = [&](int tt) {
    {
      const int r = tid >> 3, ch = tid & 7;
      float m4[4] = {-FLT_MAX, -FLT_MAX, -FLT_MAX, -FLT_MAX};
      int mi[4] = {0x7fffffff, 0x7fffffff, 0x7fffffff, 0x7fffffff};
      for (int g = 0; g < 4; ++g) {
        ull pk[32];
#pragma unroll
        for (int z = 0; z < 32; ++z) {
          const int wg = ch * 32 + g * 8 + (z >> 2);
          pk[z] = cLoad64(P.pvp + wg * 128 + r * 4 + (z & 3));
        }
#pragma unroll
        for (int z = 0; z < 32; ++z)
          ins4(m4, mi, __uint_as_float((unsigned)(pk[z] >> 32)),
               (int)(unsigned)(pk[z] & 0xffffffffu));
      }
#pragma unroll
      for (int k = 0; k < 4; ++k) { svv[r][ch][k] = m4[k]; sii[r][ch][k] = mi[k]; }
    }
    __syncthreads();
    if (tid < 32) {
      float m4[4] = {-FLT_MAX, -FLT_MAX, -FLT_MAX, -FLT_MAX};
      int mi[4] = {0x7fffffff, 0x7fffffff, 0x7fffffff, 0x7fffffff};
      for (int g2 = 0; g2 < 8; ++g2)
#pragma unroll
        for (int k = 0; k < 4; ++k) ins4(m4, mi, svv[tid][g2][k], sii[tid][g2][k]);
#pragma unroll
      for (int k = 0; k < 4; ++k) { rvS[tid][k] = m4[k]; rtS[tid][k] = mi[k]; }
    }
    __syncthreads();
    if (tid < 8) {
      const int b2 = tid;
      unsigned used = 0;
      int obl_[4], tkl_[4];
#pragma unroll
      for (int sel = 0; sel < 4; ++sel) {
        float bestv = -FLT_MAX; int bestj = -1;
        for (int j = 0; j < 16; ++j) {
          if (used & (1u << j)) continue;
          float vv = rvS[(j >> 2) * 8 + b2][j & 3];
          if (vv > bestv) { bestv = vv; bestj = j; }
        }
        used |= 1u << bestj;
        const int obn = bestj >> 2;
        obl_[sel] = obn;
        tkl_[sel] = rtS[obn * 8 + b2][bestj & 3];
        oblS[sel * 8 + b2] = obn;
        tokS[sel * 8 + b2] = tkl_[sel];
        if (w == 0) P.obh[tt * 32 + sel * 8 + b2] = obn;
      }
      if (w == 0) {
        int tmp[4][13];
        for (int n2 = 0; n2 < 4; ++n2)
          for (int s2 = 0; s2 < 13; ++s2) tmp[n2][s2] = resS[obl_[n2]][s2][b2];
        for (int n2 = 0; n2 < 4; ++n2)
          for (int s2 = 0; s2 < 13; ++s2) resS[n2][s2][b2] = tmp[n2][s2];
        for (int n2 = 0; n2 < 4; ++n2) resS[n2][tt + 1][b2] = tkl_[n2];
      }
    }
    __syncthreads();
    if (tt == 11 && w == 0 && tid < 104)
      P.res0[tid] = resS[0][tid >> 3][tid & 7];
  };

  for (int t = 0; t < 12; ++t) {
    const int curOff = (t & 1) * 16384, prevOff = ((t + 1) & 1) * 16384;

    // ===== A: [select(t-1)] + LSTM gates/cell with backpointer gather =====
    if (t == 0) {
      __syncthreads();
      if (tid < 32) { oblS[tid] = tid >> 3; tokS[tid] = 1; }
      __syncthreads();
    } else {
      do_select(t - 1);
    }
    {
      const int col_l = tid >> 7, gate = (tid >> 5) & 3, nb = tid & 31;
      const int col = 2 * w + col_l;
      const int row = gate * 512 + col;
      for (int e = tid; e < 2048; e += 256) {
        const int nb2 = e >> 6, kf = e & 63;
        float4 v = *((const float4*)(P.emb + (size_t)tokS[nb2] * 256) + kf);
        *((float4*)hs + nb2 * 65 + kf) = v;
      }
      __syncthreads();
      float s0 = 0.f, s1 = 0.f, s2 = 0.f, s3 = 0.f;
      {
        const float4* a4 = (const float4*)(P.Wih + (size_t)row * 256);
        const float4* x4 = (const float4*)hs + nb * 65;
#pragma unroll 8
        for (int k = 0; k < 64; ++k) {
          float4 a = a4[k], x = x4[k];
          s0 = fmaf(a.x, x.x, s0); s1 = fmaf(a.y, x.y, s1);
          s2 = fmaf(a.z, x.z, s2); s3 = fmaf(a.w, x.w, s3);
        }
      }
      float acc = P.bih[row] + P.bhh[row];
      const ull* hsrc = (const ull*)(P.nhb + prevOff);
      const float4* w4row = (const float4*)(P.Whh + (size_t)row * 512);
      for (int ck = 0; ck < 2; ++ck) {
        __syncthreads();
        for (int e = tid; e < 4096; e += 256) {
          const int nb2 = e >> 7, k2 = e & 127;
          const int srow = oblS[nb2] * 8 + (nb2 & 7);
          ull v = cLoad64(hsrc + srow * 256 + ck * 128 + k2);
          *(ull*)(hs + nb2 * 260 + 2 * k2) = v;
        }
        __syncthreads();
        const float4* h4 = (const float4*)hs + nb * 65;
        const float4* w4 = w4row + ck * 64;
#pragma unroll 8
        for (int k = 0; k < 64; ++k) {
          float4 a = w4[k], x = h4[k];
          s0 = fmaf(a.x, x.x, s0); s1 = fmaf(a.y, x.y, s1);
          s2 = fmaf(a.z, x.z, s2); s3 = fmaf(a.w, x.w, s3);
        }
      }
      acc += (s0 + s1) + (s2 + s3);
      gl[col_l][gate][nb] = acc;
      __syncthreads();
      if (tid < 64) {
        const int cc = tid >> 5, nb2 = tid & 31;
        const int col2 = 2 * w + cc;
        float gi = gl[cc][0][nb2], gf_ = gl[cc][1][nb2];
        float gg = gl[cc][2][nb2], go = gl[cc][3][nb2];
        const int srow = oblS[nb2] * 8 + (nb2 & 7);
        float cold = cLoad(P.ncb + prevOff + srow * 512 + col2);
        float c2 = sig_(gf_) * cold + sig_(gi) * tanhf(gg);
        float hv = sig_(go) * tanhf(c2);
        cStore(P.nhb + curOff + nb2 * 512 + col2, hv);
        cStore(P.ncb + curOff + nb2 * 512 + col2, c2);
      }
    }
    fbar2(P.arr, P.bc, ++ph);

    // ===== B: p=0 -> score partials (At fold); p=1 -> vbuf (W2 fold) =====
    if (w < 128) {
      const int p = w >> 6, cb = w & 63;
      const int col_l = tid >> 5, nb = tid & 31;
      const int col = cb * 8 + col_l;
      const float* W = (p ? P.W2 : P.At) + (size_t)col * 512;
      float acc = (p ? P.bvo : P.u)[col];
      {
        const float4* w4row = (const float4*)W;
        float s0 = 0.f, s1 = 0.f, s2 = 0.f, s3 = 0.f;
        for (int ck = 0; ck < 2; ++ck) {
          __syncthreads();
          const ull* s8 = (const ull*)(P.nhb + curOff);
          for (int e = tid; e < 4096; e += 256) {
            const int nb2 = e >> 7, k2 = e & 127;
            ull v = cLoad64(s8 + nb2 * 256 + ck * 128 + k2);
            *(ull*)(hs + nb2 * 260 + 2 * k2) = v;
          }
          __syncthreads();
          const float4* h4 = (const float4*)hs + nb * 65;
          const float4* w4 = w4row + ck * 64;
#pragma unroll 8
          for (int k = 0; k < 64; ++k) {
            float4 a = w4[k], x = h4[k];
            s0 = fmaf(a.x, x.x, s0); s1 = fmaf(a.y, x.y, s1);
            s2 = fmaf(a.z, x.z, s2); s3 = fmaf(a.w, x.w, s3);
          }
        }
        acc += (s0 + s1) + (s2 + s3);
      }
      if (p) {
        cStore(P.vbuf + nb * 512 + col, acc);
      } else {
        // score partials over this WG's 8 cols
        const float nhv = cLoad(P.nhb + curOff + nb * 512 + col);
        pscS[nb][col_l] = nhv * acc;
        nhsS[nb][col_l] = nhv;
        __syncthreads();
        if (tid < 32) {
          const int nb2 = tid, b = nb2 & 7;
          float s2a = 0.f, l0 = 0.f, l1 = 0.f;
#pragma unroll
          for (int i2 = 0; i2 < 8; ++i2) {
            s2a += pscS[nb2][i2];
            const float nv = nhsS[nb2][i2];
            l0 = fmaf(nv, P.pvec[b * 512 + cb * 8 + i2], l0);
            l1 = fmaf(nv, P.pvec[4096 + b * 512 + cb * 8 + i2], l1);
          }
          cStore(P.part_s + (0 * 32 + nb2) * 64 + cb, l0);
          cStore(P.part_s + (1 * 32 + nb2) * 64 + cb, l1);
          cStore(P.part_s + (2 * 32 + nb2) * 64 + cb, s2a);
        }
      }
    }
    fbar2(P.arr, P.bc, ++ph);

    // ===== E: softmax (from partials) + logits via LDS-tiled Wout + top-4 ==
    {
      const int cbase = w * 125;
      // inline softmax
      if (tid < 96) {
        const int nb = tid / 3, l = tid - (tid / 3) * 3, b = nb & 7;
        const ull* ps = (const ull*)(P.part_s + (l * 32 + nb) * 64);
        ull pk[32];
#pragma unroll
        for (int z = 0; z < 32; ++z) pk[z] = cLoad64(ps + z);
        float s = 0.f;
#pragma unroll
        for (int z = 0; z < 32; ++z) { float2 f = u2f2(pk[z]); s += f.x + f.y; }
        const float bias = (l < 2) ? P.sl0[l * 8 + b] : P.sbb[0];
        slS[nb][l] = (s + bias) * (1.0f / sqrtf(512.0f));
      }
      __syncthreads();
      if (tid < 32) {
        float a = slS[tid][0], b2 = slS[tid][1], c3 = slS[tid][2];
        float m = fmaxf(a, fmaxf(b2, c3));
        float e0 = expf(a - m), e1 = expf(b2 - m), e2 = expf(c3 - m);
        float inv = 1.0f / (e0 + e1 + e2);
        wslS[tid * 3 + 0] = e0 * inv;
        wslS[tid * 3 + 1] = e1 * inv;
        wslS[tid * 3 + 2] = e2 * inv;
      }
      // GEMV: rows rg*4+i (128 rows, 125 valid), nbs ng*4+j
      const int rg = tid >> 3, ng = tid & 7;
      float acc[4][4];
#pragma unroll
      for (int i = 0; i < 4; ++i)
#pragma unroll
        for (int j = 0; j < 4; ++j) acc[i][j] = 0.f;
      for (int q = 0; q < 4; ++q) {
        __syncthreads();
        for (int e = tid; e < 1024; e += 256) {
          const int nb = e >> 5, kf = e & 31;
          ull u0 = cLoad64((const ull*)(P.vbuf + nb * 512 + q * 128 + kf * 4));
          ull u1 = cLoad64((const ull*)(P.vbuf + nb * 512 + q * 128 + kf * 4 + 2));
          float2 a = u2f2(u0), b2 = u2f2(u1);
          float4 v = {a.x, a.y, b2.x, b2.y};
          *(float4*)(vqS + (nb & 3) * 1056 + (nb >> 2) * 132 + kf * 4) = v;
        }
        for (int it = 0; it < 16; ++it) {
          const int idx = it * 256 + tid;
          if (idx < 4000) {
            const int r = idx >> 5, kf = idx & 31;
            float4 v = *(const float4*)(P.Wout + (size_t)(cbase + r) * 512 +
                                        q * 128 + kf * 4);
            *(float4*)(tileS + (r & 3) * 4224 + (r >> 2) * 132 + kf * 4) = v;
          }
        }
        __syncthreads();
        for (int kf = 0; kf < 32; ++kf) {
          float4 xv[4], wv[4];
#pragma unroll
          for (int j = 0; j < 4; ++j)
            xv[j] = *(const float4*)(vqS + j * 1056 + ng * 132 + kf * 4);
#pragma unroll
          for (int i = 0; i < 4; ++i)
            wv[i] = *(const float4*)(tileS + i * 4224 + rg * 132 + kf * 4);
#pragma unroll
          for (int i = 0; i < 4; ++i)
#pragma unroll
            for (int j = 0; j < 4; ++j) {
              float a = acc[i][j];
              a = fmaf(wv[i].x, xv[j].x, a); a = fmaf(wv[i].y, xv[j].y, a);
              a = fmaf(wv[i].z, xv[j].z, a); a = fmaf(wv[i].w, xv[j].w, a);
              acc[i][j] = a;
            }
        }
      }
      __syncthreads();
      // combine + hist + per-thread top4 per nb
      float w0w[4], w1w[4], w2w[4];
#pragma unroll
      for (int j = 0; j < 4; ++j) {
        const int nb = ng * 4 + j;
        w0w[j] = wslS[nb * 3 + 0]; w1w[j] = wslS[nb * 3 + 1]; w2w[j] = wslS[nb * 3 + 2];
      }
      float v4[4][4]; int i4[4][4];
#pragma unroll
      for (int j = 0; j < 4; ++j)
#pragma unroll
        for (int k = 0; k < 4; ++k) { v4[j][k] = -FLT_MAX; i4[j][k] = 0x7fffffff; }
#pragma unroll
      for (int i = 0; i < 4; ++i) {
        const int r = rg * 4 + i;
        if (r < 125) {
          const int c = cbase + r;
          const float bcv = P.bcg[c];
#pragma unroll
          for (int j = 0; j < 4; ++j) {
            const int nb = ng * 4 + j, b = nb & 7;
            const float e0 = P.E0g[(size_t)b * 32000 + c];
            const float e1 = P.E1g[(size_t)b * 32000 + c];
            const float L = fmaf(w2w[j], acc[i][j],
                                 fmaf(w0w[j], e0, fmaf(w1w[j], e1, bcv)));
            P.hist[(size_t)t * 1024000 + (size_t)nb * 32000 + c] = __float2bfloat16(L);
            ins4(v4[j], i4[j], L, c);
          }
        }
      }
#pragma unroll
      for (int j = 0; j < 4; ++j)
#pragma unroll
        for (int k = 0; k < 4; ++k) {
          tvE[(ng * 4 + j) * 130 + rg * 4 + k] = v4[j][k];
          tiE[(ng * 4 + j) * 130 + rg * 4 + k] = i4[j][k];
        }
      __syncthreads();
      if (tid < 32) {
        float m4[4] = {-FLT_MAX, -FLT_MAX, -FLT_MAX, -FLT_MAX};
        int mi[4] = {0x7fffffff, 0x7fffffff, 0x7fffffff, 0x7fffffff};
        for (int e = 0; e < 128; ++e)
          ins4(m4, mi, tvE[tid * 130 + e], tiE[tid * 130 + e]);
#pragma unroll
        for (int k = 0; k < 4; ++k) {
          ull pk = ((ull)__float_as_uint(m4[k]) << 32) | (unsigned)mi[k];
          cStore64(P.pvp + w * 128 + tid * 4 + k, pk);
        }
      }
    }
    fbar2(P.arr, P.bc, ++ph);
  }
  if (w == 0) do_select(11);
}

// ---------------------------------------------------------------------------
// Output assembly (unchanged).
// ---------------------------------------------------------------------------
__global__ __launch_bounds__(256) void out_kernel(const __hip_bfloat16* hist,
                                                  const int* obh, const int* res0,
                                                  float* out) {
  __shared__ float sh[13 * 1000];
  __shared__ int sbArr[12];
  const int w = blockIdx.x, tid = threadIdx.x;
  const int b = w >> 5, v0 = (w & 31) * 1000;
  if (tid == 0) {
    int beta = 0;
    for (int t = 11; t >= 0; --t) {
      const int sb = obh[t * 32 + beta * 8 + b];
      sbArr[t] = sb;
      beta = sb;
    }
  }
  __syncthreads();
  for (int e = tid; e < 12000; e += 256) {
    const int t = e / 1000, vv = e - t * 1000;
    sh[(t + 1) * 1000 + vv] = __bfloat162float(
        hist[(size_t)(t * 32 + sbArr[t] * 8 + b) * 32000 + v0 + vv]);
  }
  for (int e = tid; e < 1000; e += 256) sh[e] = (v0 + e == 1) ? 1.0f : 0.0f;
  __syncthreads();
  float* base = out + 104 + (size_t)(b * 32000 + v0) * 13;
  for (int o = tid; o < 13000; o += 256) {
    const int v = o / 13, t = o - v * 13;
    base[o] = sh[t * 1000 + v];
  }
  if (w == 0 && tid < 104) {
    out[(tid & 7) * 13 + (tid >> 3)] = (float)res0[tid];
  }
}

// ---------------------------------------------------------------------------
extern "C" void kernel_launch(void* const* d_in, const int* in_sizes, int n_in,
                              void* d_out, int out_size, void* d_ws, size_t ws_size,
                              hipStream_t stream) {
  const int* text  = (const int*)d_in[0];
  const float* embE = (const float*)d_in[1];
  const float* embD = (const float*)d_in[2];
  const float* Wih0 = (const float*)d_in[3];
  const float* Whh0 = (const float*)d_in[4];
  const float* bih0 = (const float*)d_in[5];
  const float* bhh0 = (const float*)d_in[6];
  const float* Wih1 = (const float*)d_in[7];
  const float* Whh1 = (const float*)d_in[8];
  const float* bih1 = (const float*)d_in[9];
  const float* bhh1 = (const float*)d_in[10];
  const float* dWih = (const float*)d_in[11];
  const float* dWhh = (const float*)d_in[12];
  const float* dbih = (const float*)d_in[13];
  const float* dbhh = (const float*)d_in[14];
  const float* Wq = (const float*)d_in[15];
  const float* bq = (const float*)d_in[16];
  const float* Wk = (const float*)d_in[17];
  const float* bk = (const float*)d_in[18];
  const float* Wv = (const float*)d_in[19];
  const float* bv = (const float*)d_in[20];
  const float* Wo = (const float*)d_in[21];
  const float* bo = (const float*)d_in[22];
  const float* Wout = (const float*)d_in[23];
  const float* bout = (const float*)d_in[24];

  char* ws = (char*)d_ws;
  size_t off = 0;
  auto alloc = [&](size_t bytes) -> char* {
    off = (off + 511) & ~(size_t)511;
    char* p = ws + off;
    off += bytes;
    return p;
  };
  int* arrE  = (int*)alloc(8192 * 4);
  int* bcE   = (int*)alloc(1024 * 4);
  int* arrD  = (int*)alloc(8192 * 4);
  int* bcD   = (int*)alloc(1024 * 4);
  float* h0buf = (float*)alloc(2 * 4096 * 4);
  float* h1buf = (float*)alloc(2 * 4096 * 4);
  float* h0f  = (float*)alloc(4096 * 4);
  float* h1f  = (float*)alloc(4096 * 4);
  float* c1f  = (float*)alloc(4096 * 4);
  float* kenc = (float*)alloc(8192 * 4);
  float* venc = (float*)alloc(8192 * 4);
  float* At   = (float*)alloc((size_t)262144 * 4);
  float* W2   = (float*)alloc((size_t)262144 * 4);
  float* u    = (float*)alloc(512 * 4);
  float* pvec = (float*)alloc(8192 * 4);
  float* veWo = (float*)alloc(8192 * 4);
  float* bvo  = (float*)alloc(512 * 4);
  float* sl0  = (float*)alloc(16 * 4);
  float* sbb  = (float*)alloc(32 * 4);
  float* E0g  = (float*)alloc((size_t)256000 * 4);
  float* E1g  = (float*)alloc((size_t)256000 * 4);
  float* bcg  = (float*)alloc(32000 * 4);
  float* nhb  = (float*)alloc(2 * 16384 * 4);
  float* ncb  = (float*)alloc(2 * 16384 * 4);
  float* vbuf = (float*)alloc(16384 * 4);
  float* part_s = (float*)alloc(6144 * 4);
  ull* pvp    = (ull*)alloc((size_t)32768 * 8);
  int* obh    = (int*)alloc(384 * 4);
  int* res0   = (int*)alloc(104 * 4);
  __hip_bfloat16* hist = (__hip_bfloat16*)alloc((size_t)12288000 * 2);
  if (off > ws_size) return;  // ~30 MB required

  init_kernel<<<32, 256, 0, stream>>>(h0buf, h1buf, arrE, bcE, arrD, bcD);

  EncP ep{text, embE, Wih0, Whh0, bih0, bhh0, Wih1, Whh1, bih1, bhh1,
          h0buf, h1buf, h0f, h1f, c1f, arrE, bcE};
  enc_kernel<<<256, 256, 0, stream>>>(ep);

  prep_kernel<<<128, 256, 0, stream>>>(Wk, bk, Wv, bv, h0f, h1f, c1f, kenc, venc,
                                       nhb, ncb);
  prep2_kernel<<<256, 256, 0, stream>>>(Wq, Wk, Wv, Wo, bq, bk, bv, kenc, venc,
                                        At, W2, u, pvec, veWo, bvo, sl0, sbb);
  prep3_kernel<<<256, 256, 0, stream>>>(Wout, bout, bo, veWo, E0g, E1g, bcg);

  DecP dp{embD, dWih, dWhh, dbih, dbhh, Wout,
          At, W2, u, bvo, pvec, sl0, sbb, E0g, E1g, bcg,
          nhb, ncb, vbuf, part_s, pvp, obh, res0, hist, arrD, bcD};
  dec_kernel<<<256, 256, 0, stream>>>(dp);

  out_kernel<<<256, 256, 0, stream>>>(hist, obh, res0, (float*)d_out);
}